// Round 1
// baseline (1896.167 us; speedup 1.0000x reference)
//
#include <hip/hip_runtime.h>
#include <math.h>

// Problem constants: B=2,T=8,D=64,H=64,W=64,D2=128,E=4,HID=256
// token index = ((bt)*64 + h)*64 + w ; bt = b*8+t ; NTOK = 65536

// -------- workspace layout (float offsets) --------
#define W_XCL_RE 0u
#define W_XCL_IM 4194304u
#define W_C      8388608u     // xn (conv input) -> later tok (post-LN2)
#define W_EIG_RE 16777216u    // x_eigen -> u_out -> x_out (in place)
#define W_EIG_IM 20971520u
#define W_D      16777216u    // final_tok (reuses eig region after it dies)
#define W_SMALL  25165824u
#define W_TE     (W_SMALL+0u)
#define W_MOMRE  (W_SMALL+1024u)
#define W_MOMIM  (W_SMALL+2048u)
#define W_MTRE   (W_SMALL+3072u)
#define W_MTIM   (W_SMALL+4096u)
#define W_GATE   (W_SMALL+5120u)
#define W_SRCRE  (W_SMALL+6144u)
#define W_SRCIM  (W_SMALL+7168u)
#define W_OPFRE  (W_SMALL+8192u)
#define W_OPFIM  (W_SMALL+9216u)
#define W_OPDRE  (W_SMALL+10240u)
#define W_OPDIM  (W_SMALL+11264u)
#define W_SCALE  (W_SMALL+12288u)
#define W_EPART  (W_SMALL+13312u)
#define W_XPR    (W_SMALL+17408u)
#define W_XPI    (W_SMALL+21504u)

// K1: per (bt,d): target_energy, momentum (mean over H*W)
__global__ void k1_reduce_in(const float* __restrict__ xre, const float* __restrict__ xim, float* ws) {
  int bi = blockIdx.x; // bt*64 + d
  const float* pr = xre + (size_t)bi * 4096;
  const float* pi = xim + (size_t)bi * 4096;
  float sr = 0.f, si = 0.f, se = 0.f;
  for (int i = threadIdx.x; i < 4096; i += 256) {
    float r = pr[i], m = pi[i];
    sr += r; si += m; se += r * r + m * m;
  }
  for (int o = 32; o > 0; o >>= 1) {
    sr += __shfl_down(sr, o);
    si += __shfl_down(si, o);
    se += __shfl_down(se, o);
  }
  __shared__ float red[3][4];
  int wid = threadIdx.x >> 6, lane = threadIdx.x & 63;
  if (lane == 0) { red[0][wid] = sr; red[1][wid] = si; red[2][wid] = se; }
  __syncthreads();
  if (threadIdx.x == 0) {
    float a = 0.f, b = 0.f, c = 0.f;
    for (int q = 0; q < 4; q++) { a += red[0][q]; b += red[1][q]; c += red[2][q]; }
    ws[W_MOMRE + bi] = a / 4096.f;
    ws[W_MOMIM + bi] = b / 4096.f;
    ws[W_TE + bi]    = c / 4096.f;
  }
}

// K2: transpose (B,T,D,H,W)->(token,d) xcl; layernorm -> xn (token,c)
__global__ __launch_bounds__(256) void k2_transpose_ln(
    const float* __restrict__ xre, const float* __restrict__ xim,
    const float* __restrict__ g, const float* __restrict__ bb_, float* ws) {
  int blk = blockIdx.x; int bt = blk >> 6, h = blk & 63;
  __shared__ float tre[64][65], tim[64][65];
  __shared__ float ps[4][64], pq[4][64];
  __shared__ float mean_l[64], rstd_l[64];
  size_t inbase = (size_t)bt * 262144 + (size_t)h * 64; // + d*4096 + w
  for (int i = threadIdx.x; i < 4096; i += 256) {
    int d = i >> 6, w = i & 63;
    tre[d][w] = xre[inbase + (size_t)d * 4096 + w];
    tim[d][w] = xim[inbase + (size_t)d * 4096 + w];
  }
  __syncthreads();
  {
    int w = threadIdx.x & 63, part = threadIdx.x >> 6;
    float s = 0.f, sq = 0.f;
    for (int dd = part * 16; dd < part * 16 + 16; dd++) {
      float vr = tre[dd][w], vi = tim[dd][w];
      s += vr + vi; sq += vr * vr + vi * vi;
    }
    ps[part][w] = s; pq[part][w] = sq;
  }
  __syncthreads();
  if (threadIdx.x < 64) {
    int w = threadIdx.x;
    float s  = ps[0][w] + ps[1][w] + ps[2][w] + ps[3][w];
    float sq = pq[0][w] + pq[1][w] + pq[2][w] + pq[3][w];
    float m = s / 128.f;
    float v = sq / 128.f - m * m;
    mean_l[w] = m; rstd_l[w] = rsqrtf(v + 1e-5f);
  }
  __syncthreads();
  size_t tokbase = (size_t)blk * 64;
  for (int i = threadIdx.x; i < 4096; i += 256) {
    int w = i >> 6, d = i & 63;
    ws[W_XCL_RE + tokbase * 64 + (size_t)w * 64 + d] = tre[d][w];
    ws[W_XCL_IM + tokbase * 64 + (size_t)w * 64 + d] = tim[d][w];
  }
  int c = threadIdx.x & 127, wh = threadIdx.x >> 7;
  float gc = g[c], bc = bb_[c];
  for (int pass = 0; pass < 32; pass++) {
    int w = pass * 2 + wh;
    float val = (c < 64) ? tre[c][w] : tim[c - 64][w];
    ws[W_C + tokbase * 128 + (size_t)w * 128 + c] = (val - mean_l[w]) * rstd_l[w] * gc + bc;
  }
}

// K2b: mom_cat @ mom_w + mom_b -> momentum advection term per (bt,d)
__global__ void k2b_mom(const float* __restrict__ mom_w, const float* __restrict__ mom_b,
                        const float* __restrict__ adv_w, const float* __restrict__ dt, float* ws) {
  int bt = blockIdx.x; int t = bt & 7;
  __shared__ float mc[128], outl[128];
  int tid = threadIdx.x; // 128 threads
  mc[tid] = (tid < 64) ? ws[W_MOMRE + bt * 64 + tid] : ws[W_MOMIM + bt * 64 + tid - 64];
  __syncthreads();
  float acc = mom_b[tid];
  for (int k = 0; k < 128; k++) acc += mc[k] * mom_w[k * 128 + tid];
  outl[tid] = acc;
  __syncthreads();
  if (tid < 64) {
    float f = adv_w[0] * dt[t];
    ws[W_MTRE + bt * 64 + tid] = outl[tid] * f;
    ws[W_MTIM + bt * 64 + tid] = outl[64 + tid] * f;
  }
}

// K3: 3x3 SAME conv on xn; xcl += conv_y + conv_b + mom_term
__global__ __launch_bounds__(256) void k3_conv(const float* __restrict__ cw,
                                               const float* __restrict__ cb, float* ws) {
  int blk = blockIdx.x; int bt = blk >> 6, h = blk & 63;
  __shared__ __align__(16) float cf[9 * 8 * 128];
  __shared__ float tin[3][66][8];
  int tid = threadIdx.x;
  int c4 = tid & 31, wg = tid >> 5;
  float4 acc[8];
  #pragma unroll
  for (int k = 0; k < 8; k++) acc[k] = make_float4(0.f, 0.f, 0.f, 0.f);
  const float* xn = ws + W_C;
  size_t rowtok = (size_t)blk * 64;
  for (int chunk = 0; chunk < 16; chunk++) {
    int ci0 = chunk * 8;
    __syncthreads();
    for (int i = tid; i < 9216; i += 256) {
      int c = i & 127, r = i >> 7, cc = r & 7, kk = r >> 3;
      cf[i] = cw[((size_t)kk * 128 + ci0 + cc) * 128 + c];
    }
    for (int i = tid; i < 1584; i += 256) {
      int cc = i & 7, wp = (i >> 3) % 66, r3 = i / 528;
      int w_in = wp - 1, hh = h + r3 - 1;
      float v = 0.f;
      if (hh >= 0 && hh < 64 && w_in >= 0 && w_in < 64)
        v = xn[((size_t)bt * 4096 + hh * 64 + w_in) * 128 + ci0 + cc];
      tin[r3][wp][cc] = v;
    }
    __syncthreads();
    for (int cc = 0; cc < 8; cc++) {
      for (int kh = 0; kh < 3; kh++) {
        float r[10];
        #pragma unroll
        for (int j = 0; j < 10; j++) r[j] = tin[kh][wg * 8 + j][cc];
        #pragma unroll
        for (int kw = 0; kw < 3; kw++) {
          const float4 cfv = *(const float4*)&cf[((kh * 3 + kw) * 8 + cc) * 128 + c4 * 4];
          #pragma unroll
          for (int k = 0; k < 8; k++) {
            float in = r[k + kw];
            acc[k].x += in * cfv.x; acc[k].y += in * cfv.y;
            acc[k].z += in * cfv.z; acc[k].w += in * cfv.w;
          }
        }
      }
    }
  }
  int cbase = c4 * 4;
  float4 cbv = *(const float4*)&cb[cbase];
  bool isre = (c4 < 16);
  int d = isre ? cbase : (cbase - 64);
  float* xcl = ws + (isre ? W_XCL_RE : W_XCL_IM);
  float4 mtv = *(const float4*)(ws + (isre ? W_MTRE : W_MTIM) + bt * 64 + d);
  for (int k = 0; k < 8; k++) {
    int w = wg * 8 + k;
    float4* p = (float4*)&xcl[(rowtok + w) * 64 + d];
    float4 old = *p;
    old.x += acc[k].x + cbv.x + mtv.x;
    old.y += acc[k].y + cbv.y + mtv.y;
    old.z += acc[k].z + cbv.z + mtv.z;
    old.w += acc[k].w + cbv.w + mtv.w;
    *p = old;
  }
}

// generic per-token complex matmul (64x64), block = one (bt,h) row; in-place safe
__global__ __launch_bounds__(256) void k_cmatmul(const float* __restrict__ wre,
                                                 const float* __restrict__ wim, float* ws,
                                                 long ire_off, long iim_off,
                                                 long ore_off, long oim_off) {
  int blk = blockIdx.x;
  __shared__ float sre[64][64], sim[64][64];
  size_t tokbase = (size_t)blk * 64;
  for (int i = threadIdx.x; i < 4096; i += 256) {
    sre[i >> 6][i & 63] = ws[ire_off + tokbase * 64 + i];
    sim[i >> 6][i & 63] = ws[iim_off + tokbase * 64 + i];
  }
  __syncthreads();
  int j = threadIdx.x & 63, wg = threadIdx.x >> 6;
  float ar[16], ai[16];
  #pragma unroll
  for (int kk = 0; kk < 16; kk++) { ar[kk] = 0.f; ai[kk] = 0.f; }
  for (int d = 0; d < 64; d++) {
    float wr = wre[d * 64 + j], wi = wim[d * 64 + j];
    #pragma unroll
    for (int kk = 0; kk < 16; kk++) {
      float xr = sre[wg * 16 + kk][d], xi = sim[wg * 16 + kk][d];
      ar[kk] += xr * wr - xi * wi;
      ai[kk] += xr * wi + xi * wr;
    }
  }
  for (int kk = 0; kk < 16; kk++) {
    int w = wg * 16 + kk;
    ws[ore_off + (tokbase + w) * 64 + j] = ar[kk];
    ws[oim_off + (tokbase + w) * 64 + j] = ai[kk];
  }
}

// partial spatial reductions over eig buffer. mode 0: sum re/im (x_mean); mode 1: sum |.|^2
__global__ void k_partial(float* ws, int mode) {
  int blk = blockIdx.x; int bt = blk >> 2, q = blk & 3;
  __shared__ float pr[4][64], pi[4][64];
  int j = threadIdx.x & 63, sub = threadIdx.x >> 6;
  float sr = 0.f, si = 0.f;
  size_t base = (size_t)bt * 4096;
  int tk0 = q * 1024 + sub * 256;
  for (int tk = tk0; tk < tk0 + 256; tk++) {
    float r = ws[W_EIG_RE + (base + tk) * 64 + j];
    float m = ws[W_EIG_IM + (base + tk) * 64 + j];
    if (mode == 0) { sr += r; si += m; }
    else { sr += r * r + m * m; }
  }
  pr[sub][j] = sr; pi[sub][j] = si;
  __syncthreads();
  if (threadIdx.x < 64) {
    float a = pr[0][j] + pr[1][j] + pr[2][j] + pr[3][j];
    if (mode == 0) {
      ws[W_XPR + blk * 64 + j] = a;
      ws[W_XPI + blk * 64 + j] = pi[0][j] + pi[1][j] + pi[2][j] + pi[3][j];
    } else {
      ws[W_EPART + blk * 64 + j] = a;
    }
  }
}

__device__ __forceinline__ float softplusf(float x) {
  return (x > 20.f) ? x : log1pf(expf(x));
}

// K6: X_flux, flux scan, source, gate, op_decay/op_forcing — all tiny (B,T,D) work
__global__ void k6_seq(const float* __restrict__ fin_re, const float* __restrict__ fin_im,
                       const float* __restrict__ fproj_re, const float* __restrict__ fproj_im,
                       const float* __restrict__ flux_a_re, const float* __restrict__ flux_a_im,
                       const float* __restrict__ gate_w, const float* __restrict__ gate_b,
                       const float* __restrict__ lam_re, const float* __restrict__ lam_im,
                       const float* __restrict__ dt, float* ws) {
  __shared__ float xmr[1024], xmi[1024], Xfr[1024], Xfi[1024], flr[1024], fli[1024];
  int tid = threadIdx.x;
  for (int i = tid; i < 1024; i += 256) {
    int bt = i >> 6, j = i & 63;
    float sr = 0.f, si = 0.f;
    for (int q = 0; q < 4; q++) {
      sr += ws[W_XPR + (bt * 4 + q) * 64 + j];
      si += ws[W_XPI + (bt * 4 + q) * 64 + j];
    }
    xmr[i] = sr / 4096.f; xmi[i] = si / 4096.f;
  }
  __syncthreads();
  for (int i = tid; i < 1024; i += 256) {
    int bt = i >> 6, j = i & 63;
    float ar = 0.f, ai = 0.f;
    for (int d = 0; d < 64; d++) {
      float xr = xmr[bt * 64 + d], xi = xmi[bt * 64 + d];
      float wr = fin_re[d * 64 + j], wi = fin_im[d * 64 + j];
      ar += xr * wr - xi * wi; ai += xr * wi + xi * wr;
    }
    Xfr[i] = ar; Xfi[i] = ai;
  }
  __syncthreads();
  if (tid < 128) {
    int b = tid >> 6, j = tid & 63;
    float mag = expf(-softplusf(flux_a_re[j]));
    float aar = mag * cosf(flux_a_im[j]), aai = mag * sinf(flux_a_im[j]);
    float sr = 0.f, si = 0.f;
    for (int t = 0; t < 8; t++) {
      int idx = (b * 8 + t) * 64 + j;
      float nr = aar * sr - aai * si + Xfr[idx];
      float ni = aar * si + aai * sr + Xfi[idx];
      sr = nr; si = ni;
      flr[idx] = sr; fli[idx] = si;
    }
  }
  __syncthreads();
  for (int i = tid; i < 1024; i += 256) {
    int bt = i >> 6, j = i & 63;
    float ar = 0.f, ai = 0.f, lg = 0.f;
    for (int d = 0; d < 64; d++) {
      float fr = flr[bt * 64 + d], fi = fli[bt * 64 + d];
      float wr = fproj_re[d * 64 + j], wi = fproj_im[d * 64 + j];
      ar += fr * wr - fi * wi; ai += fr * wi + fi * wr;
      lg += fr * gate_w[d * 64 + j] + fi * gate_w[(64 + d) * 64 + j];
    }
    ws[W_SRCRE + i] = ar; ws[W_SRCIM + i] = ai;
    ws[W_GATE + i] = 1.f / (1.f + expf(-(lg + gate_b[j])));
  }
  for (int i = tid; i < 1024; i += 256) {
    int bt = i >> 6, d = i & 63, t = bt & 7;
    float lr = -softplusf(lam_re[d]), li = lam_im[d];
    float dtv = dt[t];
    float mag = expf(lr * dtv);
    float dr = mag * cosf(li * dtv), di = mag * sinf(li * dtv);
    ws[W_OPDRE + i] = dr; ws[W_OPDIM + i] = di;
    float omr = dr - 1.f, omi = di;
    float den = lr * lr + li * li;
    ws[W_OPFRE + i] = (omr * lr + omi * li) / den;
    ws[W_OPFIM + i] = (omi * lr - omr * li) / den;
  }
}

// K7: forcing -> u_t -> time scan (T=8) -> + noise, in place over eig buffer
__global__ __launch_bounds__(256) void k7_scan(const float* __restrict__ nre,
                                               const float* __restrict__ nim,
                                               const float* __restrict__ dt, float* ws) {
  int blk = blockIdx.x; int b = blk >> 6, h = blk & 63;
  __shared__ float gl[8][64], srl[8][64], sil[8][64], ofr[8][64], ofi[8][64], odr[8][64], odi[8][64];
  int tid = threadIdx.x;
  for (int i = tid; i < 512; i += 256) {
    int t = i >> 6, d = i & 63, idx = (b * 8 + t) * 64 + d;
    gl[t][d]  = ws[W_GATE + idx];
    srl[t][d] = ws[W_SRCRE + idx]; sil[t][d] = ws[W_SRCIM + idx];
    ofr[t][d] = ws[W_OPFRE + idx]; ofi[t][d] = ws[W_OPFIM + idx];
    odr[t][d] = ws[W_OPDRE + idx]; odi[t][d] = ws[W_OPDIM + idx];
  }
  __syncthreads();
  float ur[16], ui[16];
  #pragma unroll
  for (int k = 0; k < 16; k++) { ur[k] = 0.f; ui[k] = 0.f; }
  for (int t = 0; t < 8; t++) {
    float ns = 0.01f * sqrtf(dt[t]);
    size_t tokbase = ((size_t)(b * 8 + t) * 64 + h) * 64;
    for (int k = 0; k < 16; k++) {
      int idx = tid + 256 * k;
      int w = idx >> 6, d = idx & 63;
      size_t off = (tokbase + w) * 64 + d;
      float er_ = ws[W_EIG_RE + off], ei_ = ws[W_EIG_IM + off];
      float gg = gl[t][d];
      float fre = er_ * gg + srl[t][d] * (1.f - gg);
      float fim = ei_ * gg + sil[t][d] * (1.f - gg);
      float utr = fre * ofr[t][d] - fim * ofi[t][d];
      float uti = fre * ofi[t][d] + fim * ofr[t][d];
      float nur = odr[t][d] * ur[k] - odi[t][d] * ui[k] + utr;
      float nui = odr[t][d] * ui[k] + odi[t][d] * ur[k] + uti;
      ur[k] = nur; ui[k] = nui;
      ws[W_EIG_RE + off] = nur + ns * nre[off];
      ws[W_EIG_IM + off] = nui + ns * nim[off];
    }
  }
}

// K9b: combine |x_out|^2 partials -> energy rescale factor per (bt,d)
__global__ void k9b_scale(const float* __restrict__ escale, float* ws) {
  int bt = blockIdx.x; int j = threadIdx.x; // 64 threads
  float s = ws[W_EPART + (bt * 4 + 0) * 64 + j] + ws[W_EPART + (bt * 4 + 1) * 64 + j]
          + ws[W_EPART + (bt * 4 + 2) * 64 + j] + ws[W_EPART + (bt * 4 + 3) * 64 + j];
  float cur = s / 4096.f;
  float te = ws[W_TE + bt * 64 + j];
  float ratio = te / (cur + 1e-8f);
  ratio = fminf(fmaxf(ratio, 0.5f), 2.0f);
  ws[W_SCALE + bt * 64 + j] = 1.f + escale[0] * (sqrtf(ratio) - 1.f);
}

// K10: scale x_out by sf, layernorm(ln_t) -> tok (token,c) into W_C
__global__ __launch_bounds__(256) void k10_scale_ln(const float* __restrict__ g2,
                                                    const float* __restrict__ b2_, float* ws) {
  int blk = blockIdx.x; int bt = blk >> 6;
  __shared__ float lv[64][129];
  __shared__ float ps[4][64], pq[4][64], mean_l[64], rstd_l[64];
  size_t tokbase = (size_t)blk * 64;
  int tid = threadIdx.x;
  for (int i = tid; i < 4096; i += 256) {
    int w = i >> 6, d = i & 63;
    float s = ws[W_SCALE + bt * 64 + d];
    lv[w][d]      = ws[W_EIG_RE + (tokbase + w) * 64 + d] * s;
    lv[w][64 + d] = ws[W_EIG_IM + (tokbase + w) * 64 + d] * s;
  }
  __syncthreads();
  {
    int w = tid & 63, part = tid >> 6;
    float s = 0.f, sq = 0.f;
    for (int c = part * 32; c < part * 32 + 32; c++) {
      float v = lv[w][c]; s += v; sq += v * v;
    }
    ps[part][w] = s; pq[part][w] = sq;
  }
  __syncthreads();
  if (tid < 64) {
    int w = tid;
    float s  = ps[0][w] + ps[1][w] + ps[2][w] + ps[3][w];
    float sq = pq[0][w] + pq[1][w] + pq[2][w] + pq[3][w];
    float m = s / 128.f, v = sq / 128.f - m * m;
    mean_l[w] = m; rstd_l[w] = rsqrtf(v + 1e-5f);
  }
  __syncthreads();
  int c = tid & 127, wh = tid >> 7;
  float gc = g2[c], bc = b2_[c];
  for (int pass = 0; pass < 32; pass++) {
    int w = pass * 2 + wh;
    ws[W_C + tokbase * 128 + (size_t)w * 128 + c] = (lv[w][c] - mean_l[w]) * rstd_l[w] * gc + bc;
  }
}

// K11: dense MoE (router softmax, 2-layer gelu experts) + residuals -> final_tok in W_D
__global__ __launch_bounds__(256) void k11_moe(const float* __restrict__ rw, const float* __restrict__ rb,
                                               const float* __restrict__ w1, const float* __restrict__ b1,
                                               const float* __restrict__ w2, const float* __restrict__ b2,
                                               float* ws) {
  int blk = blockIdx.x;
  __shared__ __align__(16) float ltok[64][132];
  __shared__ __align__(16) float hbuf[64][68];
  __shared__ float pl[64][4];
  size_t tokbase = (size_t)blk * 64;
  const float* tokp = ws + W_C + tokbase * 128;
  int tid = threadIdx.x;
  for (int i = tid; i < 8192; i += 256) ltok[i >> 7][i & 127] = tokp[i];
  __syncthreads();
  {
    int l = tid >> 2, e = tid & 3;
    float acc = rb[e];
    for (int d = 0; d < 128; d++) acc += ltok[l][d] * rw[d * 4 + e];
    pl[l][e] = acc;
  }
  __syncthreads();
  if (tid < 64) {
    float m = fmaxf(fmaxf(pl[tid][0], pl[tid][1]), fmaxf(pl[tid][2], pl[tid][3]));
    float e0 = expf(pl[tid][0] - m), e1 = expf(pl[tid][1] - m);
    float e2 = expf(pl[tid][2] - m), e3 = expf(pl[tid][3] - m);
    float s = e0 + e1 + e2 + e3;
    pl[tid][0] = e0 / s; pl[tid][1] = e1 / s; pl[tid][2] = e2 / s; pl[tid][3] = e3 / s;
  }
  __syncthreads();
  int k = tid & 63, tg = tid >> 6;     // layer-1 mapping: hid k0+k, tokens tg*16..+16
  int d2 = tid & 127, tg2 = tid >> 7;  // layer-2 mapping: out d2, tokens tg2*32..+32
  float out_acc[32];
  #pragma unroll
  for (int i = 0; i < 32; i++) out_acc[i] = 0.f;
  for (int e = 0; e < 4; e++) {
    float acc2[32];
    #pragma unroll
    for (int i = 0; i < 32; i++) acc2[i] = 0.f;
    for (int hc = 0; hc < 4; hc++) {
      int k0 = hc * 64;
      float a1[16];
      #pragma unroll
      for (int i = 0; i < 16; i++) a1[i] = 0.f;
      const float* w1p = w1 + ((size_t)e * 128) * 256 + k0 + k;
      for (int dd4 = 0; dd4 < 128; dd4 += 4) {
        float wv0 = w1p[(size_t)(dd4 + 0) * 256];
        float wv1 = w1p[(size_t)(dd4 + 1) * 256];
        float wv2 = w1p[(size_t)(dd4 + 2) * 256];
        float wv3 = w1p[(size_t)(dd4 + 3) * 256];
        #pragma unroll
        for (int tt = 0; tt < 16; tt++) {
          const float4 tv = *(const float4*)&ltok[tg * 16 + tt][dd4];
          a1[tt] += tv.x * wv0 + tv.y * wv1 + tv.z * wv2 + tv.w * wv3;
        }
      }
      float bv = b1[e * 256 + k0 + k];
      __syncthreads(); // previous chunk's layer-2 reads of hbuf done
      #pragma unroll
      for (int tt = 0; tt < 16; tt++) {
        float hv = a1[tt] + bv;
        float inner = 0.7978845608028654f * (hv + 0.044715f * hv * hv * hv);
        hbuf[tg * 16 + tt][k] = 0.5f * hv * (1.f + tanhf(inner));
      }
      __syncthreads();
      const float* w2p = w2 + ((size_t)e * 256 + k0) * 128 + d2;
      for (int kk4 = 0; kk4 < 64; kk4 += 4) {
        float u0 = w2p[(size_t)(kk4 + 0) * 128];
        float u1 = w2p[(size_t)(kk4 + 1) * 128];
        float u2 = w2p[(size_t)(kk4 + 2) * 128];
        float u3 = w2p[(size_t)(kk4 + 3) * 128];
        #pragma unroll
        for (int tt = 0; tt < 32; tt++) {
          const float4 hv = *(const float4*)&hbuf[tg2 * 32 + tt][kk4];
          acc2[tt] += hv.x * u0 + hv.y * u1 + hv.z * u2 + hv.w * u3;
        }
      }
    }
    float bv2 = b2[e * 128 + d2];
    #pragma unroll
    for (int tt = 0; tt < 32; tt++)
      out_acc[tt] += pl[tg2 * 32 + tt][e] * (acc2[tt] + bv2);
  }
  __syncthreads();
  for (int tt = 0; tt < 32; tt++) {
    int l = tg2 * 32 + tt;
    size_t gtok = tokbase + l;
    float val = ltok[l][d2] + out_acc[tt];
    if (d2 < 64) val += ws[W_XCL_RE + gtok * 64 + d2];
    else         val += ws[W_XCL_IM + gtok * 64 + d2 - 64];
    ws[W_D + gtok * 128 + d2] = val;
  }
}

// K12: transpose final_tok (token,c) -> output (2,B,T,D,H,W)
__global__ void k12_out(float* __restrict__ out, const float* ws) {
  int blk = blockIdx.x; int bt = blk >> 6, h = blk & 63;
  __shared__ float t[64][65];
  size_t tokbase = (size_t)blk * 64;
  int tid = threadIdx.x;
  for (int half = 0; half < 2; half++) {
    __syncthreads();
    for (int i = tid; i < 4096; i += 256) {
      int w = i >> 6, c = i & 63;
      t[w][c] = ws[W_D + (tokbase + w) * 128 + half * 64 + c];
    }
    __syncthreads();
    float* o = out + (size_t)half * 4194304 + (size_t)bt * 262144 + (size_t)h * 64;
    for (int i = tid; i < 4096; i += 256) {
      int d = i >> 6, w = i & 63;
      o[(size_t)d * 4096 + w] = t[w][d];
    }
  }
}

extern "C" void kernel_launch(void* const* d_in, const int* in_sizes, int n_in,
                              void* d_out, int out_size, void* d_ws, size_t ws_size,
                              hipStream_t stream) {
  const float* x_re      = (const float*)d_in[0];
  const float* x_im      = (const float*)d_in[1];
  const float* dt        = (const float*)d_in[2];
  const float* ln_s_g    = (const float*)d_in[3];
  const float* ln_s_b    = (const float*)d_in[4];
  const float* conv_w    = (const float*)d_in[5];
  const float* conv_b    = (const float*)d_in[6];
  const float* mom_w     = (const float*)d_in[7];
  const float* mom_b     = (const float*)d_in[8];
  const float* adv_w     = (const float*)d_in[9];
  const float* enc_re    = (const float*)d_in[10];
  const float* enc_im    = (const float*)d_in[11];
  const float* dec_re    = (const float*)d_in[12];
  const float* dec_im    = (const float*)d_in[13];
  const float* flux_a_re = (const float*)d_in[14];
  const float* flux_a_im = (const float*)d_in[15];
  const float* fin_re    = (const float*)d_in[16];
  const float* fin_im    = (const float*)d_in[17];
  const float* fproj_re  = (const float*)d_in[18];
  const float* fproj_im  = (const float*)d_in[19];
  const float* gate_w    = (const float*)d_in[20];
  const float* gate_b    = (const float*)d_in[21];
  const float* lam_re    = (const float*)d_in[22];
  const float* lam_im    = (const float*)d_in[23];
  const float* noise_re  = (const float*)d_in[24];
  const float* noise_im  = (const float*)d_in[25];
  const float* e_scale   = (const float*)d_in[26];
  const float* ln_t_g    = (const float*)d_in[27];
  const float* ln_t_b    = (const float*)d_in[28];
  const float* router_w  = (const float*)d_in[29];
  const float* router_b  = (const float*)d_in[30];
  const float* w1        = (const float*)d_in[31];
  const float* b1        = (const float*)d_in[32];
  const float* w2        = (const float*)d_in[33];
  const float* b2        = (const float*)d_in[34];
  float* ws  = (float*)d_ws;
  float* out = (float*)d_out;

  k1_reduce_in<<<1024, 256, 0, stream>>>(x_re, x_im, ws);
  k2_transpose_ln<<<1024, 256, 0, stream>>>(x_re, x_im, ln_s_g, ln_s_b, ws);
  k2b_mom<<<16, 128, 0, stream>>>(mom_w, mom_b, adv_w, dt, ws);
  k3_conv<<<1024, 256, 0, stream>>>(conv_w, conv_b, ws);
  k_cmatmul<<<1024, 256, 0, stream>>>(enc_re, enc_im, ws,
      (long)W_XCL_RE, (long)W_XCL_IM, (long)W_EIG_RE, (long)W_EIG_IM);
  k_partial<<<64, 256, 0, stream>>>(ws, 0);
  k6_seq<<<1, 256, 0, stream>>>(fin_re, fin_im, fproj_re, fproj_im, flux_a_re, flux_a_im,
                                gate_w, gate_b, lam_re, lam_im, dt, ws);
  k7_scan<<<128, 256, 0, stream>>>(noise_re, noise_im, dt, ws);
  k_cmatmul<<<1024, 256, 0, stream>>>(dec_re, dec_im, ws,
      (long)W_EIG_RE, (long)W_EIG_IM, (long)W_EIG_RE, (long)W_EIG_IM);
  k_partial<<<64, 256, 0, stream>>>(ws, 1);
  k9b_scale<<<16, 64, 0, stream>>>(e_scale, ws);
  k10_scale_ln<<<1024, 256, 0, stream>>>(ln_t_g, ln_t_b, ws);
  k11_moe<<<1024, 256, 0, stream>>>(router_w, router_b, w1, b1, w2, b2, ws);
  k12_out<<<1024, 256, 0, stream>>>(out, ws);
}

// Round 2
// 786.869 us; speedup vs baseline: 2.4098x; 2.4098x over previous
//
#include <hip/hip_runtime.h>
#include <hip/hip_bf16.h>
#include <math.h>

// Problem constants: B=2,T=8,D=64,H=64,W=64,D2=128,E=4,HID=256
// token index = ((bt)*64 + h)*64 + w ; bt = b*8+t ; NTOK = 65536

// -------- workspace layout (float offsets) --------
#define W_XCL_RE 0u
#define W_XCL_IM 4194304u
#define W_C      8388608u     // xn fp32 (conv input) -> later tok bf16 (post-LN2, 4.19M float-slots)
#define W_W1T    14680064u    // bf16 w1 transposed [4][256][128] (dead xn space, written after k3)
#define W_W2T    14745600u    // bf16 w2 transposed [4][128][256]
#define W_EIG_RE 16777216u    // x_eigen -> u_out -> x_out (in place)
#define W_EIG_IM 20971520u
#define W_SMALL  25165824u
#define W_TE     (W_SMALL+0u)
#define W_MOMRE  (W_SMALL+1024u)
#define W_MOMIM  (W_SMALL+2048u)
#define W_MTRE   (W_SMALL+3072u)
#define W_MTIM   (W_SMALL+4096u)
#define W_GATE   (W_SMALL+5120u)
#define W_SRCRE  (W_SMALL+6144u)
#define W_SRCIM  (W_SMALL+7168u)
#define W_OPFRE  (W_SMALL+8192u)
#define W_OPFIM  (W_SMALL+9216u)
#define W_OPDRE  (W_SMALL+10240u)
#define W_OPDIM  (W_SMALL+11264u)
#define W_SCALE  (W_SMALL+12288u)
#define W_EPART  (W_SMALL+13312u)
#define W_XPR    (W_SMALL+17408u)
#define W_XPI    (W_SMALL+21504u)

typedef __attribute__((ext_vector_type(8))) short bf16x8;
typedef __attribute__((ext_vector_type(4))) float f32x4;

// K1: per (bt,d): target_energy, momentum (mean over H*W)
__global__ void k1_reduce_in(const float* __restrict__ xre, const float* __restrict__ xim, float* ws) {
  int bi = blockIdx.x; // bt*64 + d
  const float* pr = xre + (size_t)bi * 4096;
  const float* pi = xim + (size_t)bi * 4096;
  float sr = 0.f, si = 0.f, se = 0.f;
  for (int i = threadIdx.x; i < 4096; i += 256) {
    float r = pr[i], m = pi[i];
    sr += r; si += m; se += r * r + m * m;
  }
  for (int o = 32; o > 0; o >>= 1) {
    sr += __shfl_down(sr, o);
    si += __shfl_down(si, o);
    se += __shfl_down(se, o);
  }
  __shared__ float red[3][4];
  int wid = threadIdx.x >> 6, lane = threadIdx.x & 63;
  if (lane == 0) { red[0][wid] = sr; red[1][wid] = si; red[2][wid] = se; }
  __syncthreads();
  if (threadIdx.x == 0) {
    float a = 0.f, b = 0.f, c = 0.f;
    for (int q = 0; q < 4; q++) { a += red[0][q]; b += red[1][q]; c += red[2][q]; }
    ws[W_MOMRE + bi] = a / 4096.f;
    ws[W_MOMIM + bi] = b / 4096.f;
    ws[W_TE + bi]    = c / 4096.f;
  }
}

// K2: transpose (B,T,D,H,W)->(token,d) xcl; layernorm -> xn (token,c)
__global__ __launch_bounds__(256) void k2_transpose_ln(
    const float* __restrict__ xre, const float* __restrict__ xim,
    const float* __restrict__ g, const float* __restrict__ bb_, float* ws) {
  int blk = blockIdx.x; int bt = blk >> 6, h = blk & 63;
  __shared__ float tre[64][65], tim[64][65];
  __shared__ float ps[4][64], pq[4][64];
  __shared__ float mean_l[64], rstd_l[64];
  size_t inbase = (size_t)bt * 262144 + (size_t)h * 64; // + d*4096 + w
  for (int i = threadIdx.x; i < 4096; i += 256) {
    int d = i >> 6, w = i & 63;
    tre[d][w] = xre[inbase + (size_t)d * 4096 + w];
    tim[d][w] = xim[inbase + (size_t)d * 4096 + w];
  }
  __syncthreads();
  {
    int w = threadIdx.x & 63, part = threadIdx.x >> 6;
    float s = 0.f, sq = 0.f;
    for (int dd = part * 16; dd < part * 16 + 16; dd++) {
      float vr = tre[dd][w], vi = tim[dd][w];
      s += vr + vi; sq += vr * vr + vi * vi;
    }
    ps[part][w] = s; pq[part][w] = sq;
  }
  __syncthreads();
  if (threadIdx.x < 64) {
    int w = threadIdx.x;
    float s  = ps[0][w] + ps[1][w] + ps[2][w] + ps[3][w];
    float sq = pq[0][w] + pq[1][w] + pq[2][w] + pq[3][w];
    float m = s / 128.f;
    float v = sq / 128.f - m * m;
    mean_l[w] = m; rstd_l[w] = rsqrtf(v + 1e-5f);
  }
  __syncthreads();
  size_t tokbase = (size_t)blk * 64;
  for (int i = threadIdx.x; i < 4096; i += 256) {
    int w = i >> 6, d = i & 63;
    ws[W_XCL_RE + tokbase * 64 + (size_t)w * 64 + d] = tre[d][w];
    ws[W_XCL_IM + tokbase * 64 + (size_t)w * 64 + d] = tim[d][w];
  }
  int c = threadIdx.x & 127, wh = threadIdx.x >> 7;
  float gc = g[c], bc = bb_[c];
  for (int pass = 0; pass < 32; pass++) {
    int w = pass * 2 + wh;
    float val = (c < 64) ? tre[c][w] : tim[c - 64][w];
    ws[W_C + tokbase * 128 + (size_t)w * 128 + c] = (val - mean_l[w]) * rstd_l[w] * gc + bc;
  }
}

// K2b: mom_cat @ mom_w + mom_b -> momentum advection term per (bt,d)
__global__ void k2b_mom(const float* __restrict__ mom_w, const float* __restrict__ mom_b,
                        const float* __restrict__ adv_w, const float* __restrict__ dt, float* ws) {
  int bt = blockIdx.x; int t = bt & 7;
  __shared__ float mc[128], outl[128];
  int tid = threadIdx.x; // 128 threads
  mc[tid] = (tid < 64) ? ws[W_MOMRE + bt * 64 + tid] : ws[W_MOMIM + bt * 64 + tid - 64];
  __syncthreads();
  float acc = mom_b[tid];
  for (int k = 0; k < 128; k++) acc += mc[k] * mom_w[k * 128 + tid];
  outl[tid] = acc;
  __syncthreads();
  if (tid < 64) {
    float f = adv_w[0] * dt[t];
    ws[W_MTRE + bt * 64 + tid] = outl[tid] * f;
    ws[W_MTIM + bt * 64 + tid] = outl[64 + tid] * f;
  }
}

// K3: 3x3 SAME conv on xn; xcl += conv_y + conv_b + mom_term
__global__ __launch_bounds__(256) void k3_conv(const float* __restrict__ cw,
                                               const float* __restrict__ cb, float* ws) {
  int blk = blockIdx.x; int bt = blk >> 6, h = blk & 63;
  __shared__ __align__(16) float cf[9 * 8 * 128];
  __shared__ float tin[3][66][8];
  int tid = threadIdx.x;
  int c4 = tid & 31, wg = tid >> 5;
  float4 acc[8];
  #pragma unroll
  for (int k = 0; k < 8; k++) acc[k] = make_float4(0.f, 0.f, 0.f, 0.f);
  const float* xn = ws + W_C;
  size_t rowtok = (size_t)blk * 64;
  for (int chunk = 0; chunk < 16; chunk++) {
    int ci0 = chunk * 8;
    __syncthreads();
    for (int i = tid; i < 9216; i += 256) {
      int c = i & 127, r = i >> 7, cc = r & 7, kk = r >> 3;
      cf[i] = cw[((size_t)kk * 128 + ci0 + cc) * 128 + c];
    }
    for (int i = tid; i < 1584; i += 256) {
      int cc = i & 7, wp = (i >> 3) % 66, r3 = i / 528;
      int w_in = wp - 1, hh = h + r3 - 1;
      float v = 0.f;
      if (hh >= 0 && hh < 64 && w_in >= 0 && w_in < 64)
        v = xn[((size_t)bt * 4096 + hh * 64 + w_in) * 128 + ci0 + cc];
      tin[r3][wp][cc] = v;
    }
    __syncthreads();
    for (int cc = 0; cc < 8; cc++) {
      for (int kh = 0; kh < 3; kh++) {
        float r[10];
        #pragma unroll
        for (int j = 0; j < 10; j++) r[j] = tin[kh][wg * 8 + j][cc];
        #pragma unroll
        for (int kw = 0; kw < 3; kw++) {
          const float4 cfv = *(const float4*)&cf[((kh * 3 + kw) * 8 + cc) * 128 + c4 * 4];
          #pragma unroll
          for (int k = 0; k < 8; k++) {
            float in = r[k + kw];
            acc[k].x += in * cfv.x; acc[k].y += in * cfv.y;
            acc[k].z += in * cfv.z; acc[k].w += in * cfv.w;
          }
        }
      }
    }
  }
  int cbase = c4 * 4;
  float4 cbv = *(const float4*)&cb[cbase];
  bool isre = (c4 < 16);
  int d = isre ? cbase : (cbase - 64);
  float* xcl = ws + (isre ? W_XCL_RE : W_XCL_IM);
  float4 mtv = *(const float4*)(ws + (isre ? W_MTRE : W_MTIM) + bt * 64 + d);
  for (int k = 0; k < 8; k++) {
    int w = wg * 8 + k;
    float4* p = (float4*)&xcl[(rowtok + w) * 64 + d];
    float4 old = *p;
    old.x += acc[k].x + cbv.x + mtv.x;
    old.y += acc[k].y + cbv.y + mtv.y;
    old.z += acc[k].z + cbv.z + mtv.z;
    old.w += acc[k].w + cbv.w + mtv.w;
    *p = old;
  }
}

// K0w: convert + transpose MoE weights to bf16 (runs after k3; uses dead xn space)
__global__ void k0_wprep(const float* __restrict__ w1, const float* __restrict__ w2, float* ws) {
  __hip_bfloat16* w1t = (__hip_bfloat16*)(ws + W_W1T);
  __hip_bfloat16* w2t = (__hip_bfloat16*)(ws + W_W2T);
  int idx = blockIdx.x * 256 + threadIdx.x; // 0..131071
  {
    // w1t[(e*256+h)*128+d] = w1[(e*128+d)*256+h]
    int d = idx & 127, r = idx >> 7;
    int hh = r & 255, e = r >> 8;
    w1t[idx] = __float2bfloat16(w1[((size_t)(e * 128 + d)) * 256 + hh]);
  }
  {
    // w2t[(e*128+dout)*256+h] = w2[(e*256+h)*128+dout]
    int hh = idx & 255, r = idx >> 8;
    int dout = r & 127, e = r >> 7;
    w2t[idx] = __float2bfloat16(w2[((size_t)(e * 256 + hh)) * 128 + dout]);
  }
}

// generic per-token complex matmul (64x64), block = one (bt,h) row; in-place safe
__global__ __launch_bounds__(256) void k_cmatmul(const float* __restrict__ wre,
                                                 const float* __restrict__ wim, float* ws,
                                                 long ire_off, long iim_off,
                                                 long ore_off, long oim_off) {
  int blk = blockIdx.x;
  __shared__ float sre[64][64], sim[64][64];
  size_t tokbase = (size_t)blk * 64;
  for (int i = threadIdx.x; i < 4096; i += 256) {
    sre[i >> 6][i & 63] = ws[ire_off + tokbase * 64 + i];
    sim[i >> 6][i & 63] = ws[iim_off + tokbase * 64 + i];
  }
  __syncthreads();
  int j = threadIdx.x & 63, wg = threadIdx.x >> 6;
  float ar[16], ai[16];
  #pragma unroll
  for (int kk = 0; kk < 16; kk++) { ar[kk] = 0.f; ai[kk] = 0.f; }
  for (int d = 0; d < 64; d++) {
    float wr = wre[d * 64 + j], wi = wim[d * 64 + j];
    #pragma unroll
    for (int kk = 0; kk < 16; kk++) {
      float xr = sre[wg * 16 + kk][d], xi = sim[wg * 16 + kk][d];
      ar[kk] += xr * wr - xi * wi;
      ai[kk] += xr * wi + xi * wr;
    }
  }
  for (int kk = 0; kk < 16; kk++) {
    int w = wg * 16 + kk;
    ws[ore_off + (tokbase + w) * 64 + j] = ar[kk];
    ws[oim_off + (tokbase + w) * 64 + j] = ai[kk];
  }
}

// partial spatial reductions over eig buffer. mode 0: sum re/im (x_mean); mode 1: sum |.|^2
__global__ void k_partial(float* ws, int mode) {
  int blk = blockIdx.x; int bt = blk >> 2, q = blk & 3;
  __shared__ float pr[4][64], pi[4][64];
  int j = threadIdx.x & 63, sub = threadIdx.x >> 6;
  float sr = 0.f, si = 0.f;
  size_t base = (size_t)bt * 4096;
  int tk0 = q * 1024 + sub * 256;
  for (int tk = tk0; tk < tk0 + 256; tk++) {
    float r = ws[W_EIG_RE + (base + tk) * 64 + j];
    float m = ws[W_EIG_IM + (base + tk) * 64 + j];
    if (mode == 0) { sr += r; si += m; }
    else { sr += r * r + m * m; }
  }
  pr[sub][j] = sr; pi[sub][j] = si;
  __syncthreads();
  if (threadIdx.x < 64) {
    float a = pr[0][j] + pr[1][j] + pr[2][j] + pr[3][j];
    if (mode == 0) {
      ws[W_XPR + blk * 64 + j] = a;
      ws[W_XPI + blk * 64 + j] = pi[0][j] + pi[1][j] + pi[2][j] + pi[3][j];
    } else {
      ws[W_EPART + blk * 64 + j] = a;
    }
  }
}

__device__ __forceinline__ float softplusf(float x) {
  return (x > 20.f) ? x : log1pf(expf(x));
}

// K6: X_flux, flux scan, source, gate, op_decay/op_forcing — all tiny (B,T,D) work
__global__ void k6_seq(const float* __restrict__ fin_re, const float* __restrict__ fin_im,
                       const float* __restrict__ fproj_re, const float* __restrict__ fproj_im,
                       const float* __restrict__ flux_a_re, const float* __restrict__ flux_a_im,
                       const float* __restrict__ gate_w, const float* __restrict__ gate_b,
                       const float* __restrict__ lam_re, const float* __restrict__ lam_im,
                       const float* __restrict__ dt, float* ws) {
  __shared__ float xmr[1024], xmi[1024], Xfr[1024], Xfi[1024], flr[1024], fli[1024];
  int tid = threadIdx.x;
  for (int i = tid; i < 1024; i += 256) {
    int bt = i >> 6, j = i & 63;
    float sr = 0.f, si = 0.f;
    for (int q = 0; q < 4; q++) {
      sr += ws[W_XPR + (bt * 4 + q) * 64 + j];
      si += ws[W_XPI + (bt * 4 + q) * 64 + j];
    }
    xmr[i] = sr / 4096.f; xmi[i] = si / 4096.f;
  }
  __syncthreads();
  for (int i = tid; i < 1024; i += 256) {
    int bt = i >> 6, j = i & 63;
    float ar = 0.f, ai = 0.f;
    for (int d = 0; d < 64; d++) {
      float xr = xmr[bt * 64 + d], xi = xmi[bt * 64 + d];
      float wr = fin_re[d * 64 + j], wi = fin_im[d * 64 + j];
      ar += xr * wr - xi * wi; ai += xr * wi + xi * wr;
    }
    Xfr[i] = ar; Xfi[i] = ai;
  }
  __syncthreads();
  if (tid < 128) {
    int b = tid >> 6, j = tid & 63;
    float mag = expf(-softplusf(flux_a_re[j]));
    float aar = mag * cosf(flux_a_im[j]), aai = mag * sinf(flux_a_im[j]);
    float sr = 0.f, si = 0.f;
    for (int t = 0; t < 8; t++) {
      int idx = (b * 8 + t) * 64 + j;
      float nr = aar * sr - aai * si + Xfr[idx];
      float ni = aar * si + aai * sr + Xfi[idx];
      sr = nr; si = ni;
      flr[idx] = sr; fli[idx] = si;
    }
  }
  __syncthreads();
  for (int i = tid; i < 1024; i += 256) {
    int bt = i >> 6, j = i & 63;
    float ar = 0.f, ai = 0.f, lg = 0.f;
    for (int d = 0; d < 64; d++) {
      float fr = flr[bt * 64 + d], fi = fli[bt * 64 + d];
      float wr = fproj_re[d * 64 + j], wi = fproj_im[d * 64 + j];
      ar += fr * wr - fi * wi; ai += fr * wi + fi * wr;
      lg += fr * gate_w[d * 64 + j] + fi * gate_w[(64 + d) * 64 + j];
    }
    ws[W_SRCRE + i] = ar; ws[W_SRCIM + i] = ai;
    ws[W_GATE + i] = 1.f / (1.f + expf(-(lg + gate_b[j])));
  }
  for (int i = tid; i < 1024; i += 256) {
    int bt = i >> 6, d = i & 63, t = bt & 7;
    float lr = -softplusf(lam_re[d]), li = lam_im[d];
    float dtv = dt[t];
    float mag = expf(lr * dtv);
    float dr = mag * cosf(li * dtv), di = mag * sinf(li * dtv);
    ws[W_OPDRE + i] = dr; ws[W_OPDIM + i] = di;
    float omr = dr - 1.f, omi = di;
    float den = lr * lr + li * li;
    ws[W_OPFRE + i] = (omr * lr + omi * li) / den;
    ws[W_OPFIM + i] = (omi * lr - omr * li) / den;
  }
}

// K7: forcing -> u_t -> time scan (T=8) -> + noise, in place over eig buffer
__global__ __launch_bounds__(256) void k7_scan(const float* __restrict__ nre,
                                               const float* __restrict__ nim,
                                               const float* __restrict__ dt, float* ws) {
  int blk = blockIdx.x; int b = blk >> 6, h = blk & 63;
  __shared__ float gl[8][64], srl[8][64], sil[8][64], ofr[8][64], ofi[8][64], odr[8][64], odi[8][64];
  int tid = threadIdx.x;
  for (int i = tid; i < 512; i += 256) {
    int t = i >> 6, d = i & 63, idx = (b * 8 + t) * 64 + d;
    gl[t][d]  = ws[W_GATE + idx];
    srl[t][d] = ws[W_SRCRE + idx]; sil[t][d] = ws[W_SRCIM + idx];
    ofr[t][d] = ws[W_OPFRE + idx]; ofi[t][d] = ws[W_OPFIM + idx];
    odr[t][d] = ws[W_OPDRE + idx]; odi[t][d] = ws[W_OPDIM + idx];
  }
  __syncthreads();
  float ur[16], ui[16];
  #pragma unroll
  for (int k = 0; k < 16; k++) { ur[k] = 0.f; ui[k] = 0.f; }
  for (int t = 0; t < 8; t++) {
    float ns = 0.01f * sqrtf(dt[t]);
    size_t tokbase = ((size_t)(b * 8 + t) * 64 + h) * 64;
    for (int k = 0; k < 16; k++) {
      int idx = tid + 256 * k;
      int w = idx >> 6, d = idx & 63;
      size_t off = (tokbase + w) * 64 + d;
      float er_ = ws[W_EIG_RE + off], ei_ = ws[W_EIG_IM + off];
      float gg = gl[t][d];
      float fre = er_ * gg + srl[t][d] * (1.f - gg);
      float fim = ei_ * gg + sil[t][d] * (1.f - gg);
      float utr = fre * ofr[t][d] - fim * ofi[t][d];
      float uti = fre * ofi[t][d] + fim * ofr[t][d];
      float nur = odr[t][d] * ur[k] - odi[t][d] * ui[k] + utr;
      float nui = odr[t][d] * ui[k] + odi[t][d] * ur[k] + uti;
      ur[k] = nur; ui[k] = nui;
      ws[W_EIG_RE + off] = nur + ns * nre[off];
      ws[W_EIG_IM + off] = nui + ns * nim[off];
    }
  }
}

// K9b: combine |x_out|^2 partials -> energy rescale factor per (bt,d)
__global__ void k9b_scale(const float* __restrict__ escale, float* ws) {
  int bt = blockIdx.x; int j = threadIdx.x; // 64 threads
  float s = ws[W_EPART + (bt * 4 + 0) * 64 + j] + ws[W_EPART + (bt * 4 + 1) * 64 + j]
          + ws[W_EPART + (bt * 4 + 2) * 64 + j] + ws[W_EPART + (bt * 4 + 3) * 64 + j];
  float cur = s / 4096.f;
  float te = ws[W_TE + bt * 64 + j];
  float ratio = te / (cur + 1e-8f);
  ratio = fminf(fmaxf(ratio, 0.5f), 2.0f);
  ws[W_SCALE + bt * 64 + j] = 1.f + escale[0] * (sqrtf(ratio) - 1.f);
}

// K10: scale x_out by sf, layernorm(ln_t) -> tok (token,c) BF16 into W_C
__global__ __launch_bounds__(256) void k10_scale_ln(const float* __restrict__ g2,
                                                    const float* __restrict__ b2_, float* ws) {
  int blk = blockIdx.x; int bt = blk >> 6;
  __shared__ float lv[64][129];
  __shared__ float ps[4][64], pq[4][64], mean_l[64], rstd_l[64];
  size_t tokbase = (size_t)blk * 64;
  int tid = threadIdx.x;
  for (int i = tid; i < 4096; i += 256) {
    int w = i >> 6, d = i & 63;
    float s = ws[W_SCALE + bt * 64 + d];
    lv[w][d]      = ws[W_EIG_RE + (tokbase + w) * 64 + d] * s;
    lv[w][64 + d] = ws[W_EIG_IM + (tokbase + w) * 64 + d] * s;
  }
  __syncthreads();
  {
    int w = tid & 63, part = tid >> 6;
    float s = 0.f, sq = 0.f;
    for (int c = part * 32; c < part * 32 + 32; c++) {
      float v = lv[w][c]; s += v; sq += v * v;
    }
    ps[part][w] = s; pq[part][w] = sq;
  }
  __syncthreads();
  if (tid < 64) {
    int w = tid;
    float s  = ps[0][w] + ps[1][w] + ps[2][w] + ps[3][w];
    float sq = pq[0][w] + pq[1][w] + pq[2][w] + pq[3][w];
    float m = s / 128.f, v = sq / 128.f - m * m;
    mean_l[w] = m; rstd_l[w] = rsqrtf(v + 1e-5f);
  }
  __syncthreads();
  __hip_bfloat16* tokb = (__hip_bfloat16*)(ws + W_C);
  int c = tid & 127, wh = tid >> 7;
  float gc = g2[c], bc = b2_[c];
  for (int pass = 0; pass < 32; pass++) {
    int w = pass * 2 + wh;
    tokb[tokbase * 128 + (size_t)w * 128 + c] =
        __float2bfloat16((lv[w][c] - mean_l[w]) * rstd_l[w] * gc + bc);
  }
}

// K11: MFMA bf16 MoE + residuals + fused output transpose.
// 4 waves; layer1 tiles: wave owns hid-cols [wv*64, wv*64+64) (4 n-tiles) x 4 m-tiles.
// layer2 tiles: wave owns out-cols [wv*32, wv*32+32) (2 n-tiles) x 4 m-tiles.
__global__ __launch_bounds__(256) void k11_moe(
    const float* __restrict__ rw, const float* __restrict__ rb,
    const float* __restrict__ b1, const float* __restrict__ b2,
    float* __restrict__ ws, float* __restrict__ out) {
  int blk = blockIdx.x; int bt = blk >> 6, h = blk & 63;
  const __hip_bfloat16* tokg = (const __hip_bfloat16*)(ws + W_C);
  const __hip_bfloat16* w1t  = (const __hip_bfloat16*)(ws + W_W1T);
  const __hip_bfloat16* w2t  = (const __hip_bfloat16*)(ws + W_W2T);
  __shared__ __align__(16) __hip_bfloat16 ltok[64][136];
  __shared__ __align__(16) char hmem[64 * 264 * 2]; // hbuf bf16[64][264] / obuf f32[64][129]
  __shared__ float pl[64][4];
  __hip_bfloat16 (*hbuf)[264] = (__hip_bfloat16(*)[264])hmem;
  float (*obuf)[129] = (float(*)[129])hmem;
  int tid = threadIdx.x, lane = tid & 63, wv = tid >> 6;
  int arow = lane & 15, kgrp = (lane >> 4) * 8, rbase = (lane >> 4) * 4;
  size_t tokbase = (size_t)blk * 64;

  // load ltok (bf16, 2 elems per 4B)
  {
    const unsigned int* tg32 = (const unsigned int*)(tokg + tokbase * 128);
    for (int i = tid; i < 4096; i += 256)
      *(unsigned int*)&ltok[i >> 6][(i & 63) * 2] = tg32[i];
  }
  __syncthreads();

  // router logits (fp32 from bf16 tok)
  {
    int l = tid >> 2, e = tid & 3;
    float acc = rb[e];
    const float* rwe = rw + e;
    for (int dd = 0; dd < 128; dd += 2) {
      unsigned int u = *(const unsigned int*)&ltok[l][dd];
      float x0 = __uint_as_float(u << 16);
      float x1 = __uint_as_float(u & 0xffff0000u);
      acc += x0 * rwe[dd * 4] + x1 * rwe[dd * 4 + 4];
    }
    pl[l][e] = acc;
  }
  __syncthreads();
  if (tid < 64) {
    float m = fmaxf(fmaxf(pl[tid][0], pl[tid][1]), fmaxf(pl[tid][2], pl[tid][3]));
    float e0 = expf(pl[tid][0] - m), e1 = expf(pl[tid][1] - m);
    float e2 = expf(pl[tid][2] - m), e3 = expf(pl[tid][3] - m);
    float s = e0 + e1 + e2 + e3;
    pl[tid][0] = e0 / s; pl[tid][1] = e1 / s; pl[tid][2] = e2 / s; pl[tid][3] = e3 / s;
  }

  // out accumulator init = tok residual (frag layout: row=m*16+rbase+r, col=(wv*2+n2)*16+arow)
  f32x4 oacc[4][2];
  #pragma unroll
  for (int m = 0; m < 4; m++)
    #pragma unroll
    for (int n2 = 0; n2 < 2; n2++) {
      int col = (wv * 2 + n2) * 16 + arow;
      #pragma unroll
      for (int r = 0; r < 4; r++)
        oacc[m][n2][r] = __bfloat162float(ltok[m * 16 + rbase + r][col]);
    }
  __syncthreads();

  for (int e = 0; e < 4; e++) {
    // ---- layer1: h = tok @ w1[e], tiles 4m x 4n per wave ----
    f32x4 acc1[4][4];
    #pragma unroll
    for (int m = 0; m < 4; m++)
      #pragma unroll
      for (int n = 0; n < 4; n++) acc1[m][n] = (f32x4){0.f, 0.f, 0.f, 0.f};
    const __hip_bfloat16* w1e = w1t + (size_t)e * 32768;
    for (int kt = 0; kt < 4; kt++) {
      bf16x8 a[4], b[4];
      #pragma unroll
      for (int m = 0; m < 4; m++)
        a[m] = *(const bf16x8*)&ltok[m * 16 + arow][kt * 32 + kgrp];
      #pragma unroll
      for (int n = 0; n < 4; n++)
        b[n] = *(const bf16x8*)&w1e[((size_t)((wv * 4 + n) * 16 + arow)) * 128 + kt * 32 + kgrp];
      #pragma unroll
      for (int m = 0; m < 4; m++)
        #pragma unroll
        for (int n = 0; n < 4; n++)
          acc1[m][n] = __builtin_amdgcn_mfma_f32_16x16x32_bf16(a[m], b[n], acc1[m][n], 0, 0, 0);
    }
    __syncthreads(); // hbuf free (previous expert's layer2 reads done)
    // bias + fast gelu (x*sigmoid(2z)) -> bf16 hbuf
    #pragma unroll
    for (int n = 0; n < 4; n++) {
      int col = (wv * 4 + n) * 16 + arow;
      float bv = b1[e * 256 + col];
      #pragma unroll
      for (int m = 0; m < 4; m++)
        #pragma unroll
        for (int r = 0; r < 4; r++) {
          float hv = acc1[m][n][r] + bv;
          float z = 1.5957691216f * hv + 0.0713548162f * hv * hv * hv;
          float gelu = hv / (1.f + __expf(-z));
          hbuf[m * 16 + rbase + r][col] = __float2bfloat16(gelu);
        }
    }
    __syncthreads();
    // ---- layer2: eout = h @ w2[e], tiles 4m x 2n per wave ----
    f32x4 acc2[4][2];
    #pragma unroll
    for (int m = 0; m < 4; m++)
      #pragma unroll
      for (int n = 0; n < 2; n++) acc2[m][n] = (f32x4){0.f, 0.f, 0.f, 0.f};
    const __hip_bfloat16* w2e = w2t + (size_t)e * 32768;
    for (int kt = 0; kt < 8; kt++) {
      bf16x8 a2[4], bb[2];
      #pragma unroll
      for (int m = 0; m < 4; m++)
        a2[m] = *(const bf16x8*)&hbuf[m * 16 + arow][kt * 32 + kgrp];
      #pragma unroll
      for (int n = 0; n < 2; n++)
        bb[n] = *(const bf16x8*)&w2e[((size_t)((wv * 2 + n) * 16 + arow)) * 256 + kt * 32 + kgrp];
      #pragma unroll
      for (int m = 0; m < 4; m++)
        #pragma unroll
        for (int n = 0; n < 2; n++)
          acc2[m][n] = __builtin_amdgcn_mfma_f32_16x16x32_bf16(a2[m], bb[n], acc2[m][n], 0, 0, 0);
    }
    // combine with router prob (pl stable since softmax barrier)
    #pragma unroll
    for (int n = 0; n < 2; n++) {
      int col = (wv * 2 + n) * 16 + arow;
      float bv2 = b2[e * 128 + col];
      #pragma unroll
      for (int m = 0; m < 4; m++)
        #pragma unroll
        for (int r = 0; r < 4; r++)
          oacc[m][n][r] += pl[m * 16 + rbase + r][e] * (acc2[m][n][r] + bv2);
    }
  }

  __syncthreads(); // last layer2 hbuf reads done -> reuse as obuf
  #pragma unroll
  for (int m = 0; m < 4; m++)
    #pragma unroll
    for (int n2 = 0; n2 < 2; n2++) {
      int col = (wv * 2 + n2) * 16 + arow;
      #pragma unroll
      for (int r = 0; r < 4; r++)
        obuf[m * 16 + rbase + r][col] = oacc[m][n2][r];
    }
  __syncthreads();

  // epilogue: + xcl residual, transpose to out[half][bt][d][h][w]
  const float* xre = ws + W_XCL_RE;
  const float* xim = ws + W_XCL_IM;
  for (int i = tid; i < 8192; i += 256) {
    int d2 = i >> 6, w = i & 63;
    int dd = d2 & 63;
    float res = (d2 < 64) ? xre[(tokbase + w) * 64 + dd] : xim[(tokbase + w) * 64 + dd];
    out[(size_t)(d2 >> 6) * 4194304 + (size_t)bt * 262144 + (size_t)dd * 4096
        + (size_t)h * 64 + w] = obuf[w][d2] + res;
  }
}

extern "C" void kernel_launch(void* const* d_in, const int* in_sizes, int n_in,
                              void* d_out, int out_size, void* d_ws, size_t ws_size,
                              hipStream_t stream) {
  const float* x_re      = (const float*)d_in[0];
  const float* x_im      = (const float*)d_in[1];
  const float* dt        = (const float*)d_in[2];
  const float* ln_s_g    = (const float*)d_in[3];
  const float* ln_s_b    = (const float*)d_in[4];
  const float* conv_w    = (const float*)d_in[5];
  const float* conv_b    = (const float*)d_in[6];
  const float* mom_w     = (const float*)d_in[7];
  const float* mom_b     = (const float*)d_in[8];
  const float* adv_w     = (const float*)d_in[9];
  const float* enc_re    = (const float*)d_in[10];
  const float* enc_im    = (const float*)d_in[11];
  const float* dec_re    = (const float*)d_in[12];
  const float* dec_im    = (const float*)d_in[13];
  const float* flux_a_re = (const float*)d_in[14];
  const float* flux_a_im = (const float*)d_in[15];
  const float* fin_re    = (const float*)d_in[16];
  const float* fin_im    = (const float*)d_in[17];
  const float* fproj_re  = (const float*)d_in[18];
  const float* fproj_im  = (const float*)d_in[19];
  const float* gate_w    = (const float*)d_in[20];
  const float* gate_b    = (const float*)d_in[21];
  const float* lam_re    = (const float*)d_in[22];
  const float* lam_im    = (const float*)d_in[23];
  const float* noise_re  = (const float*)d_in[24];
  const float* noise_im  = (const float*)d_in[25];
  const float* e_scale   = (const float*)d_in[26];
  const float* ln_t_g    = (const float*)d_in[27];
  const float* ln_t_b    = (const float*)d_in[28];
  const float* router_w  = (const float*)d_in[29];
  const float* router_b  = (const float*)d_in[30];
  const float* w1        = (const float*)d_in[31];
  const float* b1        = (const float*)d_in[32];
  const float* w2        = (const float*)d_in[33];
  const float* b2        = (const float*)d_in[34];
  float* ws  = (float*)d_ws;
  float* out = (float*)d_out;

  k1_reduce_in<<<1024, 256, 0, stream>>>(x_re, x_im, ws);
  k2_transpose_ln<<<1024, 256, 0, stream>>>(x_re, x_im, ln_s_g, ln_s_b, ws);
  k2b_mom<<<16, 128, 0, stream>>>(mom_w, mom_b, adv_w, dt, ws);
  k3_conv<<<1024, 256, 0, stream>>>(conv_w, conv_b, ws);
  k0_wprep<<<512, 256, 0, stream>>>(w1, w2, ws);
  k_cmatmul<<<1024, 256, 0, stream>>>(enc_re, enc_im, ws,
      (long)W_XCL_RE, (long)W_XCL_IM, (long)W_EIG_RE, (long)W_EIG_IM);
  k_partial<<<64, 256, 0, stream>>>(ws, 0);
  k6_seq<<<1, 256, 0, stream>>>(fin_re, fin_im, fproj_re, fproj_im, flux_a_re, flux_a_im,
                                gate_w, gate_b, lam_re, lam_im, dt, ws);
  k7_scan<<<128, 256, 0, stream>>>(noise_re, noise_im, dt, ws);
  k_cmatmul<<<1024, 256, 0, stream>>>(dec_re, dec_im, ws,
      (long)W_EIG_RE, (long)W_EIG_IM, (long)W_EIG_RE, (long)W_EIG_IM);
  k_partial<<<64, 256, 0, stream>>>(ws, 1);
  k9b_scale<<<16, 64, 0, stream>>>(e_scale, ws);
  k10_scale_ln<<<1024, 256, 0, stream>>>(ln_t_g, ln_t_b, ws);
  k11_moe<<<1024, 256, 0, stream>>>(router_w, router_b, b1, b2, ws, out);
}

// Round 3
// 544.675 us; speedup vs baseline: 3.4813x; 1.4447x over previous
//
#include <hip/hip_runtime.h>
#include <hip/hip_bf16.h>
#include <math.h>

// Problem constants: B=2,T=8,D=64,H=64,W=64,D2=128,E=4,HID=256
// token index = ((bt)*64 + h)*64 + w ; bt = b*8+t ; NTOK = 65536

// -------- workspace layout (float offsets) --------
#define W_XCL_RE 0u
#define W_XCL_IM 4194304u
#define W_C      8388608u     // xn BF16 [tok][128] (conv input) -> later tok bf16 (post-LN2)
#define W_CWT    12582912u    // bf16 conv weights, fragment order [9][8][4][64][8] (147456 elems)
#define W_W1T    14680064u    // bf16 w1 transposed [4][256][128]
#define W_W2T    14745600u    // bf16 w2 transposed [4][128][256]
#define W_EIG_RE 16777216u    // x_eigen -> u_out -> x_out (in place)
#define W_EIG_IM 20971520u
#define W_SMALL  25165824u
#define W_TE     (W_SMALL+0u)
#define W_MOMRE  (W_SMALL+1024u)
#define W_MOMIM  (W_SMALL+2048u)
#define W_MTRE   (W_SMALL+3072u)
#define W_MTIM   (W_SMALL+4096u)
#define W_GATE   (W_SMALL+5120u)
#define W_SRCRE  (W_SMALL+6144u)
#define W_SRCIM  (W_SMALL+7168u)
#define W_OPFRE  (W_SMALL+8192u)
#define W_OPFIM  (W_SMALL+9216u)
#define W_OPDRE  (W_SMALL+10240u)
#define W_OPDIM  (W_SMALL+11264u)
#define W_SCALE  (W_SMALL+12288u)
#define W_EPART  (W_SMALL+13312u)
#define W_XPR    (W_SMALL+17408u)
#define W_XPI    (W_SMALL+21504u)

typedef __attribute__((ext_vector_type(8))) short bf16x8;
typedef __attribute__((ext_vector_type(4))) float f32x4;

// K1: per (bt,d): target_energy, momentum (mean over H*W)
__global__ void k1_reduce_in(const float* __restrict__ xre, const float* __restrict__ xim, float* ws) {
  int bi = blockIdx.x; // bt*64 + d
  const float* pr = xre + (size_t)bi * 4096;
  const float* pi = xim + (size_t)bi * 4096;
  float sr = 0.f, si = 0.f, se = 0.f;
  for (int i = threadIdx.x; i < 4096; i += 256) {
    float r = pr[i], m = pi[i];
    sr += r; si += m; se += r * r + m * m;
  }
  for (int o = 32; o > 0; o >>= 1) {
    sr += __shfl_down(sr, o);
    si += __shfl_down(si, o);
    se += __shfl_down(se, o);
  }
  __shared__ float red[3][4];
  int wid = threadIdx.x >> 6, lane = threadIdx.x & 63;
  if (lane == 0) { red[0][wid] = sr; red[1][wid] = si; red[2][wid] = se; }
  __syncthreads();
  if (threadIdx.x == 0) {
    float a = 0.f, b = 0.f, c = 0.f;
    for (int q = 0; q < 4; q++) { a += red[0][q]; b += red[1][q]; c += red[2][q]; }
    ws[W_MOMRE + bi] = a / 4096.f;
    ws[W_MOMIM + bi] = b / 4096.f;
    ws[W_TE + bi]    = c / 4096.f;
  }
}

// K2: transpose (B,T,D,H,W)->(token,d) xcl; layernorm -> xn bf16 (token,c)
__global__ __launch_bounds__(256) void k2_transpose_ln(
    const float* __restrict__ xre, const float* __restrict__ xim,
    const float* __restrict__ g, const float* __restrict__ bb_, float* ws) {
  int blk = blockIdx.x; int bt = blk >> 6, h = blk & 63;
  __shared__ float tre[64][65], tim[64][65];
  __shared__ float ps[4][64], pq[4][64];
  __shared__ float mean_l[64], rstd_l[64];
  size_t inbase = (size_t)bt * 262144 + (size_t)h * 64; // + d*4096 + w
  for (int i = threadIdx.x; i < 4096; i += 256) {
    int d = i >> 6, w = i & 63;
    tre[d][w] = xre[inbase + (size_t)d * 4096 + w];
    tim[d][w] = xim[inbase + (size_t)d * 4096 + w];
  }
  __syncthreads();
  {
    int w = threadIdx.x & 63, part = threadIdx.x >> 6;
    float s = 0.f, sq = 0.f;
    for (int dd = part * 16; dd < part * 16 + 16; dd++) {
      float vr = tre[dd][w], vi = tim[dd][w];
      s += vr + vi; sq += vr * vr + vi * vi;
    }
    ps[part][w] = s; pq[part][w] = sq;
  }
  __syncthreads();
  if (threadIdx.x < 64) {
    int w = threadIdx.x;
    float s  = ps[0][w] + ps[1][w] + ps[2][w] + ps[3][w];
    float sq = pq[0][w] + pq[1][w] + pq[2][w] + pq[3][w];
    float m = s / 128.f;
    float v = sq / 128.f - m * m;
    mean_l[w] = m; rstd_l[w] = rsqrtf(v + 1e-5f);
  }
  __syncthreads();
  size_t tokbase = (size_t)blk * 64;
  for (int i = threadIdx.x; i < 4096; i += 256) {
    int w = i >> 6, d = i & 63;
    ws[W_XCL_RE + tokbase * 64 + (size_t)w * 64 + d] = tre[d][w];
    ws[W_XCL_IM + tokbase * 64 + (size_t)w * 64 + d] = tim[d][w];
  }
  // LN -> bf16 xn, packed u32 stores (2 channels/thread)
  __hip_bfloat16* xnb = (__hip_bfloat16*)(ws + W_C);
  int c0 = (threadIdx.x & 63) * 2, wg = threadIdx.x >> 6;
  float gc0 = g[c0], bc0 = bb_[c0], gc1 = g[c0 + 1], bc1 = bb_[c0 + 1];
  for (int pass = 0; pass < 16; pass++) {
    int w = pass * 4 + wg;
    float m = mean_l[w], rs = rstd_l[w];
    float v0 = (c0 < 64) ? tre[c0][w] : tim[c0 - 64][w];
    float v1 = (c0 + 1 < 64) ? tre[c0 + 1][w] : tim[c0 + 1 - 64][w];
    __hip_bfloat16 o0 = __float2bfloat16((v0 - m) * rs * gc0 + bc0);
    __hip_bfloat16 o1 = __float2bfloat16((v1 - m) * rs * gc1 + bc1);
    unsigned int pk = ((unsigned int)*(unsigned short*)&o1 << 16) | *(unsigned short*)&o0;
    *(unsigned int*)&xnb[tokbase * 128 + (size_t)w * 128 + c0] = pk;
  }
}

// K2b: mom_cat @ mom_w + mom_b -> momentum advection term per (bt,d)
__global__ void k2b_mom(const float* __restrict__ mom_w, const float* __restrict__ mom_b,
                        const float* __restrict__ adv_w, const float* __restrict__ dt, float* ws) {
  int bt = blockIdx.x; int t = bt & 7;
  __shared__ float mc[128], outl[128];
  int tid = threadIdx.x; // 128 threads
  mc[tid] = (tid < 64) ? ws[W_MOMRE + bt * 64 + tid] : ws[W_MOMIM + bt * 64 + tid - 64];
  __syncthreads();
  float acc = mom_b[tid];
  for (int k = 0; k < 128; k++) acc += mc[k] * mom_w[k * 128 + tid];
  outl[tid] = acc;
  __syncthreads();
  if (tid < 64) {
    float f = adv_w[0] * dt[t];
    ws[W_MTRE + bt * 64 + tid] = outl[tid] * f;
    ws[W_MTIM + bt * 64 + tid] = outl[64 + tid] * f;
  }
}

// K0w: convert weights to bf16: MoE w1/w2 transposed + conv weights in fragment order
__global__ void k0_wprep(const float* __restrict__ w1, const float* __restrict__ w2,
                         const float* __restrict__ cw, float* ws) {
  __hip_bfloat16* w1t = (__hip_bfloat16*)(ws + W_W1T);
  __hip_bfloat16* w2t = (__hip_bfloat16*)(ws + W_W2T);
  __hip_bfloat16* cwt = (__hip_bfloat16*)(ws + W_CWT);
  int idx = blockIdx.x * 256 + threadIdx.x; // 0..147455
  if (idx < 131072) {
    // w1t[(e*256+h)*128+d] = w1[(e*128+d)*256+h]
    int d = idx & 127, r = idx >> 7;
    int hh = r & 255, e = r >> 8;
    w1t[idx] = __float2bfloat16(w1[((size_t)(e * 128 + d)) * 256 + hh]);
    // w2t[(e*128+dout)*256+h] = w2[(e*256+h)*128+dout]
    int h2 = idx & 255, r2 = idx >> 8;
    int dout = r2 & 127, e2 = r2 >> 7;
    w2t[idx] = __float2bfloat16(w2[((size_t)(e2 * 256 + h2)) * 128 + dout]);
  }
  if (idx < 147456) {
    // fragment order: cwt[(((tap*8+nt)*4+kt)*512) + lane*8 + j]
    // cout = nt*16 + (lane&15); cin = kt*32 + (lane>>4)*8 + j
    int j = idx & 7, lane = (idx >> 3) & 63, kt = (idx >> 9) & 3, r = idx >> 11;
    int nt = r & 7, tap = r >> 3;
    int cout = nt * 16 + (lane & 15);
    int cin = kt * 32 + (lane >> 4) * 8 + j;
    cwt[idx] = __float2bfloat16(cw[((size_t)(tap * 128 + cin)) * 128 + cout]);
  }
}

// K3: 3x3 SAME conv via bf16 MFMA; xcl += conv_y + conv_b + mom_term
__global__ __launch_bounds__(256) void k3_conv(const float* __restrict__ cb, float* ws) {
  int blk = blockIdx.x; int bt = blk >> 6, h = blk & 63;
  const __hip_bfloat16* xnb = (const __hip_bfloat16*)(ws + W_C);
  const __hip_bfloat16* cwt = (const __hip_bfloat16*)(ws + W_CWT);
  __shared__ __align__(16) __hip_bfloat16 xin[3][66][136];
  int tid = threadIdx.x, lane = tid & 63, wv = tid >> 6;
  int arow = lane & 15, kgrp = (lane >> 4) * 8, rbase = (lane >> 4) * 4;

  // stage 3 input rows (w-halo zeroed)
  for (int r = 0; r < 3; r++) {
    int hh = h + r - 1;
    if (hh < 0 || hh >= 64) {
      unsigned int* z = (unsigned int*)&xin[r][0][0];
      for (int i = tid; i < 4488; i += 256) z[i] = 0u; // 66*136 bf16
    } else {
      // halo columns wp=0, wp=65
      if (tid < 68) *(unsigned int*)&xin[r][0][tid * 2] = 0u;
      else if (tid < 136) *(unsigned int*)&xin[r][65][(tid - 136 + 68) * 2] = 0u;
      const __hip_bfloat16* src = xnb + ((size_t)bt * 4096 + (size_t)hh * 64) * 128;
      for (int i = tid; i < 1024; i += 256) {
        int wp = (i >> 4) + 1, c8 = (i & 15) * 8;
        *(bf16x8*)&xin[r][wp][c8] = *(const bf16x8*)&src[(size_t)(wp - 1) * 128 + c8];
      }
    }
  }
  __syncthreads();

  f32x4 oacc[4][2];
  #pragma unroll
  for (int m = 0; m < 4; m++) {
    oacc[m][0] = (f32x4){0.f, 0.f, 0.f, 0.f};
    oacc[m][1] = (f32x4){0.f, 0.f, 0.f, 0.f};
  }

  for (int tap = 0; tap < 9; tap++) {
    int kh = tap / 3, kw = tap % 3;
    const __hip_bfloat16* wt0 = cwt + ((size_t)(tap * 8 + wv * 2) * 4) * 512 + lane * 8;
    #pragma unroll
    for (int kt = 0; kt < 4; kt++) {
      bf16x8 a[4];
      #pragma unroll
      for (int m = 0; m < 4; m++)
        a[m] = *(const bf16x8*)&xin[kh][m * 16 + arow + kw][kt * 32 + kgrp];
      bf16x8 b0 = *(const bf16x8*)&wt0[(size_t)kt * 512];
      bf16x8 b1 = *(const bf16x8*)&wt0[(size_t)(kt + 4) * 512];
      #pragma unroll
      for (int m = 0; m < 4; m++) {
        oacc[m][0] = __builtin_amdgcn_mfma_f32_16x16x32_bf16(a[m], b0, oacc[m][0], 0, 0, 0);
        oacc[m][1] = __builtin_amdgcn_mfma_f32_16x16x32_bf16(a[m], b1, oacc[m][1], 0, 0, 0);
      }
    }
  }

  // epilogue: xcl += acc + conv_b + mom_term
  size_t rowtok = (size_t)blk * 64;
  #pragma unroll
  for (int n = 0; n < 2; n++) {
    int cout = (wv * 2 + n) * 16 + arow;
    bool isre = cout < 64;
    int d = cout & 63;
    float add = cb[cout] + ws[(isre ? W_MTRE : W_MTIM) + bt * 64 + d];
    float* xcl = ws + (isre ? W_XCL_RE : W_XCL_IM);
    #pragma unroll
    for (int m = 0; m < 4; m++)
      #pragma unroll
      for (int r = 0; r < 4; r++) {
        int w = m * 16 + rbase + r;
        xcl[(rowtok + w) * 64 + d] += oacc[m][n][r] + add;
      }
  }
}

// generic per-token complex matmul (64x64), block = one (bt,h) row; in-place safe
__global__ __launch_bounds__(256) void k_cmatmul(const float* __restrict__ wre,
                                                 const float* __restrict__ wim, float* ws,
                                                 long ire_off, long iim_off,
                                                 long ore_off, long oim_off) {
  int blk = blockIdx.x;
  __shared__ float sre[64][64], sim[64][64];
  size_t tokbase = (size_t)blk * 64;
  for (int i = threadIdx.x; i < 4096; i += 256) {
    sre[i >> 6][i & 63] = ws[ire_off + tokbase * 64 + i];
    sim[i >> 6][i & 63] = ws[iim_off + tokbase * 64 + i];
  }
  __syncthreads();
  int j = threadIdx.x & 63, wg = threadIdx.x >> 6;
  float ar[16], ai[16];
  #pragma unroll
  for (int kk = 0; kk < 16; kk++) { ar[kk] = 0.f; ai[kk] = 0.f; }
  for (int d = 0; d < 64; d++) {
    float wr = wre[d * 64 + j], wi = wim[d * 64 + j];
    #pragma unroll
    for (int kk = 0; kk < 16; kk++) {
      float xr = sre[wg * 16 + kk][d], xi = sim[wg * 16 + kk][d];
      ar[kk] += xr * wr - xi * wi;
      ai[kk] += xr * wi + xi * wr;
    }
  }
  for (int kk = 0; kk < 16; kk++) {
    int w = wg * 16 + kk;
    ws[ore_off + (tokbase + w) * 64 + j] = ar[kk];
    ws[oim_off + (tokbase + w) * 64 + j] = ai[kk];
  }
}

// partial spatial reductions over eig buffer. mode 0: sum re/im (x_mean); mode 1: sum |.|^2
__global__ void k_partial(float* ws, int mode) {
  int blk = blockIdx.x; int bt = blk >> 2, q = blk & 3;
  __shared__ float pr[4][64], pi[4][64];
  int j = threadIdx.x & 63, sub = threadIdx.x >> 6;
  float sr = 0.f, si = 0.f;
  size_t base = (size_t)bt * 4096;
  int tk0 = q * 1024 + sub * 256;
  for (int tk = tk0; tk < tk0 + 256; tk++) {
    float r = ws[W_EIG_RE + (base + tk) * 64 + j];
    float m = ws[W_EIG_IM + (base + tk) * 64 + j];
    if (mode == 0) { sr += r; si += m; }
    else { sr += r * r + m * m; }
  }
  pr[sub][j] = sr; pi[sub][j] = si;
  __syncthreads();
  if (threadIdx.x < 64) {
    float a = pr[0][j] + pr[1][j] + pr[2][j] + pr[3][j];
    if (mode == 0) {
      ws[W_XPR + blk * 64 + j] = a;
      ws[W_XPI + blk * 64 + j] = pi[0][j] + pi[1][j] + pi[2][j] + pi[3][j];
    } else {
      ws[W_EPART + blk * 64 + j] = a;
    }
  }
}

__device__ __forceinline__ float softplusf(float x) {
  return (x > 20.f) ? x : log1pf(expf(x));
}

// K6: X_flux, flux scan, source, gate, op_decay/op_forcing — all tiny (B,T,D) work
__global__ void k6_seq(const float* __restrict__ fin_re, const float* __restrict__ fin_im,
                       const float* __restrict__ fproj_re, const float* __restrict__ fproj_im,
                       const float* __restrict__ flux_a_re, const float* __restrict__ flux_a_im,
                       const float* __restrict__ gate_w, const float* __restrict__ gate_b,
                       const float* __restrict__ lam_re, const float* __restrict__ lam_im,
                       const float* __restrict__ dt, float* ws) {
  __shared__ float xmr[1024], xmi[1024], Xfr[1024], Xfi[1024], flr[1024], fli[1024];
  int tid = threadIdx.x;
  for (int i = tid; i < 1024; i += 256) {
    int bt = i >> 6, j = i & 63;
    float sr = 0.f, si = 0.f;
    for (int q = 0; q < 4; q++) {
      sr += ws[W_XPR + (bt * 4 + q) * 64 + j];
      si += ws[W_XPI + (bt * 4 + q) * 64 + j];
    }
    xmr[i] = sr / 4096.f; xmi[i] = si / 4096.f;
  }
  __syncthreads();
  for (int i = tid; i < 1024; i += 256) {
    int bt = i >> 6, j = i & 63;
    float ar = 0.f, ai = 0.f;
    for (int d = 0; d < 64; d++) {
      float xr = xmr[bt * 64 + d], xi = xmi[bt * 64 + d];
      float wr = fin_re[d * 64 + j], wi = fin_im[d * 64 + j];
      ar += xr * wr - xi * wi; ai += xr * wi + xi * wr;
    }
    Xfr[i] = ar; Xfi[i] = ai;
  }
  __syncthreads();
  if (tid < 128) {
    int b = tid >> 6, j = tid & 63;
    float mag = expf(-softplusf(flux_a_re[j]));
    float aar = mag * cosf(flux_a_im[j]), aai = mag * sinf(flux_a_im[j]);
    float sr = 0.f, si = 0.f;
    for (int t = 0; t < 8; t++) {
      int idx = (b * 8 + t) * 64 + j;
      float nr = aar * sr - aai * si + Xfr[idx];
      float ni = aar * si + aai * sr + Xfi[idx];
      sr = nr; si = ni;
      flr[idx] = sr; fli[idx] = si;
    }
  }
  __syncthreads();
  for (int i = tid; i < 1024; i += 256) {
    int bt = i >> 6, j = i & 63;
    float ar = 0.f, ai = 0.f, lg = 0.f;
    for (int d = 0; d < 64; d++) {
      float fr = flr[bt * 64 + d], fi = fli[bt * 64 + d];
      float wr = fproj_re[d * 64 + j], wi = fproj_im[d * 64 + j];
      ar += fr * wr - fi * wi; ai += fr * wi + fi * wr;
      lg += fr * gate_w[d * 64 + j] + fi * gate_w[(64 + d) * 64 + j];
    }
    ws[W_SRCRE + i] = ar; ws[W_SRCIM + i] = ai;
    ws[W_GATE + i] = 1.f / (1.f + expf(-(lg + gate_b[j])));
  }
  for (int i = tid; i < 1024; i += 256) {
    int bt = i >> 6, d = i & 63, t = bt & 7;
    float lr = -softplusf(lam_re[d]), li = lam_im[d];
    float dtv = dt[t];
    float mag = expf(lr * dtv);
    float dr = mag * cosf(li * dtv), di = mag * sinf(li * dtv);
    ws[W_OPDRE + i] = dr; ws[W_OPDIM + i] = di;
    float omr = dr - 1.f, omi = di;
    float den = lr * lr + li * li;
    ws[W_OPFRE + i] = (omr * lr + omi * li) / den;
    ws[W_OPFIM + i] = (omi * lr - omr * li) / den;
  }
}

// K7: forcing -> u_t -> time scan (T=8) -> + noise, in place over eig buffer
__global__ __launch_bounds__(256) void k7_scan(const float* __restrict__ nre,
                                               const float* __restrict__ nim,
                                               const float* __restrict__ dt, float* ws) {
  int blk = blockIdx.x; int b = blk >> 6, h = blk & 63;
  __shared__ float gl[8][64], srl[8][64], sil[8][64], ofr[8][64], ofi[8][64], odr[8][64], odi[8][64];
  int tid = threadIdx.x;
  for (int i = tid; i < 512; i += 256) {
    int t = i >> 6, d = i & 63, idx = (b * 8 + t) * 64 + d;
    gl[t][d]  = ws[W_GATE + idx];
    srl[t][d] = ws[W_SRCRE + idx]; sil[t][d] = ws[W_SRCIM + idx];
    ofr[t][d] = ws[W_OPFRE + idx]; ofi[t][d] = ws[W_OPFIM + idx];
    odr[t][d] = ws[W_OPDRE + idx]; odi[t][d] = ws[W_OPDIM + idx];
  }
  __syncthreads();
  float ur[16], ui[16];
  #pragma unroll
  for (int k = 0; k < 16; k++) { ur[k] = 0.f; ui[k] = 0.f; }
  for (int t = 0; t < 8; t++) {
    float ns = 0.01f * sqrtf(dt[t]);
    size_t tokbase = ((size_t)(b * 8 + t) * 64 + h) * 64;
    for (int k = 0; k < 16; k++) {
      int idx = tid + 256 * k;
      int w = idx >> 6, d = idx & 63;
      size_t off = (tokbase + w) * 64 + d;
      float er_ = ws[W_EIG_RE + off], ei_ = ws[W_EIG_IM + off];
      float gg = gl[t][d];
      float fre = er_ * gg + srl[t][d] * (1.f - gg);
      float fim = ei_ * gg + sil[t][d] * (1.f - gg);
      float utr = fre * ofr[t][d] - fim * ofi[t][d];
      float uti = fre * ofi[t][d] + fim * ofr[t][d];
      float nur = odr[t][d] * ur[k] - odi[t][d] * ui[k] + utr;
      float nui = odr[t][d] * ui[k] + odi[t][d] * ur[k] + uti;
      ur[k] = nur; ui[k] = nui;
      ws[W_EIG_RE + off] = nur + ns * nre[off];
      ws[W_EIG_IM + off] = nui + ns * nim[off];
    }
  }
}

// K9b: combine |x_out|^2 partials -> energy rescale factor per (bt,d)
__global__ void k9b_scale(const float* __restrict__ escale, float* ws) {
  int bt = blockIdx.x; int j = threadIdx.x; // 64 threads
  float s = ws[W_EPART + (bt * 4 + 0) * 64 + j] + ws[W_EPART + (bt * 4 + 1) * 64 + j]
          + ws[W_EPART + (bt * 4 + 2) * 64 + j] + ws[W_EPART + (bt * 4 + 3) * 64 + j];
  float cur = s / 4096.f;
  float te = ws[W_TE + bt * 64 + j];
  float ratio = te / (cur + 1e-8f);
  ratio = fminf(fmaxf(ratio, 0.5f), 2.0f);
  ws[W_SCALE + bt * 64 + j] = 1.f + escale[0] * (sqrtf(ratio) - 1.f);
}

// K10: scale x_out by sf, layernorm(ln_t) -> tok (token,c) BF16 into W_C
__global__ __launch_bounds__(256) void k10_scale_ln(const float* __restrict__ g2,
                                                    const float* __restrict__ b2_, float* ws) {
  int blk = blockIdx.x; int bt = blk >> 6;
  __shared__ float lv[64][129];
  __shared__ float ps[4][64], pq[4][64], mean_l[64], rstd_l[64];
  size_t tokbase = (size_t)blk * 64;
  int tid = threadIdx.x;
  for (int i = tid; i < 4096; i += 256) {
    int w = i >> 6, d = i & 63;
    float s = ws[W_SCALE + bt * 64 + d];
    lv[w][d]      = ws[W_EIG_RE + (tokbase + w) * 64 + d] * s;
    lv[w][64 + d] = ws[W_EIG_IM + (tokbase + w) * 64 + d] * s;
  }
  __syncthreads();
  {
    int w = tid & 63, part = tid >> 6;
    float s = 0.f, sq = 0.f;
    for (int c = part * 32; c < part * 32 + 32; c++) {
      float v = lv[w][c]; s += v; sq += v * v;
    }
    ps[part][w] = s; pq[part][w] = sq;
  }
  __syncthreads();
  if (tid < 64) {
    int w = tid;
    float s  = ps[0][w] + ps[1][w] + ps[2][w] + ps[3][w];
    float sq = pq[0][w] + pq[1][w] + pq[2][w] + pq[3][w];
    float m = s / 128.f, v = sq / 128.f - m * m;
    mean_l[w] = m; rstd_l[w] = rsqrtf(v + 1e-5f);
  }
  __syncthreads();
  __hip_bfloat16* tokb = (__hip_bfloat16*)(ws + W_C);
  int c = tid & 127, wh = tid >> 7;
  float gc = g2[c], bc = b2_[c];
  for (int pass = 0; pass < 32; pass++) {
    int w = pass * 2 + wh;
    tokb[tokbase * 128 + (size_t)w * 128 + c] =
        __float2bfloat16((lv[w][c] - mean_l[w]) * rstd_l[w] * gc + bc);
  }
}

// K11: MFMA bf16 MoE + residuals + fused output transpose.
__global__ __launch_bounds__(256) void k11_moe(
    const float* __restrict__ rw, const float* __restrict__ rb,
    const float* __restrict__ b1, const float* __restrict__ b2,
    float* __restrict__ ws, float* __restrict__ out) {
  int blk = blockIdx.x; int bt = blk >> 6, h = blk & 63;
  const __hip_bfloat16* tokg = (const __hip_bfloat16*)(ws + W_C);
  const __hip_bfloat16* w1t  = (const __hip_bfloat16*)(ws + W_W1T);
  const __hip_bfloat16* w2t  = (const __hip_bfloat16*)(ws + W_W2T);
  __shared__ __align__(16) __hip_bfloat16 ltok[64][136];
  __shared__ __align__(16) char hmem[64 * 264 * 2]; // hbuf bf16[64][264] / obuf f32[64][129]
  __shared__ float pl[64][4];
  __hip_bfloat16 (*hbuf)[264] = (__hip_bfloat16(*)[264])hmem;
  float (*obuf)[129] = (float(*)[129])hmem;
  int tid = threadIdx.x, lane = tid & 63, wv = tid >> 6;
  int arow = lane & 15, kgrp = (lane >> 4) * 8, rbase = (lane >> 4) * 4;
  size_t tokbase = (size_t)blk * 64;

  // load ltok (bf16, 2 elems per 4B)
  {
    const unsigned int* tg32 = (const unsigned int*)(tokg + tokbase * 128);
    for (int i = tid; i < 4096; i += 256)
      *(unsigned int*)&ltok[i >> 6][(i & 63) * 2] = tg32[i];
  }
  __syncthreads();

  // router logits (fp32 from bf16 tok)
  {
    int l = tid >> 2, e = tid & 3;
    float acc = rb[e];
    const float* rwe = rw + e;
    for (int dd = 0; dd < 128; dd += 2) {
      unsigned int u = *(const unsigned int*)&ltok[l][dd];
      float x0 = __uint_as_float(u << 16);
      float x1 = __uint_as_float(u & 0xffff0000u);
      acc += x0 * rwe[dd * 4] + x1 * rwe[dd * 4 + 4];
    }
    pl[l][e] = acc;
  }
  __syncthreads();
  if (tid < 64) {
    float m = fmaxf(fmaxf(pl[tid][0], pl[tid][1]), fmaxf(pl[tid][2], pl[tid][3]));
    float e0 = expf(pl[tid][0] - m), e1 = expf(pl[tid][1] - m);
    float e2 = expf(pl[tid][2] - m), e3 = expf(pl[tid][3] - m);
    float s = e0 + e1 + e2 + e3;
    pl[tid][0] = e0 / s; pl[tid][1] = e1 / s; pl[tid][2] = e2 / s; pl[tid][3] = e3 / s;
  }

  // out accumulator init = tok residual
  f32x4 oacc[4][2];
  #pragma unroll
  for (int m = 0; m < 4; m++)
    #pragma unroll
    for (int n2 = 0; n2 < 2; n2++) {
      int col = (wv * 2 + n2) * 16 + arow;
      #pragma unroll
      for (int r = 0; r < 4; r++)
        oacc[m][n2][r] = __bfloat162float(ltok[m * 16 + rbase + r][col]);
    }
  __syncthreads();

  for (int e = 0; e < 4; e++) {
    // ---- layer1: h = tok @ w1[e], tiles 4m x 4n per wave ----
    f32x4 acc1[4][4];
    #pragma unroll
    for (int m = 0; m < 4; m++)
      #pragma unroll
      for (int n = 0; n < 4; n++) acc1[m][n] = (f32x4){0.f, 0.f, 0.f, 0.f};
    const __hip_bfloat16* w1e = w1t + (size_t)e * 32768;
    for (int kt = 0; kt < 4; kt++) {
      bf16x8 a[4], b[4];
      #pragma unroll
      for (int m = 0; m < 4; m++)
        a[m] = *(const bf16x8*)&ltok[m * 16 + arow][kt * 32 + kgrp];
      #pragma unroll
      for (int n = 0; n < 4; n++)
        b[n] = *(const bf16x8*)&w1e[((size_t)((wv * 4 + n) * 16 + arow)) * 128 + kt * 32 + kgrp];
      #pragma unroll
      for (int m = 0; m < 4; m++)
        #pragma unroll
        for (int n = 0; n < 4; n++)
          acc1[m][n] = __builtin_amdgcn_mfma_f32_16x16x32_bf16(a[m], b[n], acc1[m][n], 0, 0, 0);
    }
    __syncthreads(); // hbuf free (previous expert's layer2 reads done)
    #pragma unroll
    for (int n = 0; n < 4; n++) {
      int col = (wv * 4 + n) * 16 + arow;
      float bv = b1[e * 256 + col];
      #pragma unroll
      for (int m = 0; m < 4; m++)
        #pragma unroll
        for (int r = 0; r < 4; r++) {
          float hv = acc1[m][n][r] + bv;
          float z = 1.5957691216f * hv + 0.0713548162f * hv * hv * hv;
          float gelu = hv / (1.f + __expf(-z));
          hbuf[m * 16 + rbase + r][col] = __float2bfloat16(gelu);
        }
    }
    __syncthreads();
    // ---- layer2: eout = h @ w2[e], tiles 4m x 2n per wave ----
    f32x4 acc2[4][2];
    #pragma unroll
    for (int m = 0; m < 4; m++)
      #pragma unroll
      for (int n = 0; n < 2; n++) acc2[m][n] = (f32x4){0.f, 0.f, 0.f, 0.f};
    const __hip_bfloat16* w2e = w2t + (size_t)e * 32768;
    for (int kt = 0; kt < 8; kt++) {
      bf16x8 a2[4], bb[2];
      #pragma unroll
      for (int m = 0; m < 4; m++)
        a2[m] = *(const bf16x8*)&hbuf[m * 16 + arow][kt * 32 + kgrp];
      #pragma unroll
      for (int n = 0; n < 2; n++)
        bb[n] = *(const bf16x8*)&w2e[((size_t)((wv * 2 + n) * 16 + arow)) * 256 + kt * 32 + kgrp];
      #pragma unroll
      for (int m = 0; m < 4; m++)
        #pragma unroll
        for (int n = 0; n < 2; n++)
          acc2[m][n] = __builtin_amdgcn_mfma_f32_16x16x32_bf16(a2[m], bb[n], acc2[m][n], 0, 0, 0);
    }
    #pragma unroll
    for (int n = 0; n < 2; n++) {
      int col = (wv * 2 + n) * 16 + arow;
      float bv2 = b2[e * 128 + col];
      #pragma unroll
      for (int m = 0; m < 4; m++)
        #pragma unroll
        for (int r = 0; r < 4; r++)
          oacc[m][n][r] += pl[m * 16 + rbase + r][e] * (acc2[m][n][r] + bv2);
    }
  }

  __syncthreads(); // last layer2 hbuf reads done -> reuse as obuf
  #pragma unroll
  for (int m = 0; m < 4; m++)
    #pragma unroll
    for (int n2 = 0; n2 < 2; n2++) {
      int col = (wv * 2 + n2) * 16 + arow;
      #pragma unroll
      for (int r = 0; r < 4; r++)
        obuf[m * 16 + rbase + r][col] = oacc[m][n2][r];
    }
  __syncthreads();

  // epilogue: + xcl residual, transpose to out[half][bt][d][h][w]
  const float* xre = ws + W_XCL_RE;
  const float* xim = ws + W_XCL_IM;
  for (int i = tid; i < 8192; i += 256) {
    int d2 = i >> 6, w = i & 63;
    int dd = d2 & 63;
    float res = (d2 < 64) ? xre[(tokbase + w) * 64 + dd] : xim[(tokbase + w) * 64 + dd];
    out[(size_t)(d2 >> 6) * 4194304 + (size_t)bt * 262144 + (size_t)dd * 4096
        + (size_t)h * 64 + w] = obuf[w][d2] + res;
  }
}

extern "C" void kernel_launch(void* const* d_in, const int* in_sizes, int n_in,
                              void* d_out, int out_size, void* d_ws, size_t ws_size,
                              hipStream_t stream) {
  const float* x_re      = (const float*)d_in[0];
  const float* x_im      = (const float*)d_in[1];
  const float* dt        = (const float*)d_in[2];
  const float* ln_s_g    = (const float*)d_in[3];
  const float* ln_s_b    = (const float*)d_in[4];
  const float* conv_w    = (const float*)d_in[5];
  const float* conv_b    = (const float*)d_in[6];
  const float* mom_w     = (const float*)d_in[7];
  const float* mom_b     = (const float*)d_in[8];
  const float* adv_w     = (const float*)d_in[9];
  const float* enc_re    = (const float*)d_in[10];
  const float* enc_im    = (const float*)d_in[11];
  const float* dec_re    = (const float*)d_in[12];
  const float* dec_im    = (const float*)d_in[13];
  const float* flux_a_re = (const float*)d_in[14];
  const float* flux_a_im = (const float*)d_in[15];
  const float* fin_re    = (const float*)d_in[16];
  const float* fin_im    = (const float*)d_in[17];
  const float* fproj_re  = (const float*)d_in[18];
  const float* fproj_im  = (const float*)d_in[19];
  const float* gate_w    = (const float*)d_in[20];
  const float* gate_b    = (const float*)d_in[21];
  const float* lam_re    = (const float*)d_in[22];
  const float* lam_im    = (const float*)d_in[23];
  const float* noise_re  = (const float*)d_in[24];
  const float* noise_im  = (const float*)d_in[25];
  const float* e_scale   = (const float*)d_in[26];
  const float* ln_t_g    = (const float*)d_in[27];
  const float* ln_t_b    = (const float*)d_in[28];
  const float* router_w  = (const float*)d_in[29];
  const float* router_b  = (const float*)d_in[30];
  const float* w1        = (const float*)d_in[31];
  const float* b1        = (const float*)d_in[32];
  const float* w2        = (const float*)d_in[33];
  const float* b2        = (const float*)d_in[34];
  float* ws  = (float*)d_ws;
  float* out = (float*)d_out;

  k0_wprep<<<576, 256, 0, stream>>>(w1, w2, conv_w, ws);
  k1_reduce_in<<<1024, 256, 0, stream>>>(x_re, x_im, ws);
  k2_transpose_ln<<<1024, 256, 0, stream>>>(x_re, x_im, ln_s_g, ln_s_b, ws);
  k2b_mom<<<16, 128, 0, stream>>>(mom_w, mom_b, adv_w, dt, ws);
  k3_conv<<<1024, 256, 0, stream>>>(conv_b, ws);
  k_cmatmul<<<1024, 256, 0, stream>>>(enc_re, enc_im, ws,
      (long)W_XCL_RE, (long)W_XCL_IM, (long)W_EIG_RE, (long)W_EIG_IM);
  k_partial<<<64, 256, 0, stream>>>(ws, 0);
  k6_seq<<<1, 256, 0, stream>>>(fin_re, fin_im, fproj_re, fproj_im, flux_a_re, flux_a_im,
                                gate_w, gate_b, lam_re, lam_im, dt, ws);
  k7_scan<<<128, 256, 0, stream>>>(noise_re, noise_im, dt, ws);
  k_cmatmul<<<1024, 256, 0, stream>>>(dec_re, dec_im, ws,
      (long)W_EIG_RE, (long)W_EIG_IM, (long)W_EIG_RE, (long)W_EIG_IM);
  k_partial<<<64, 256, 0, stream>>>(ws, 1);
  k9b_scale<<<16, 64, 0, stream>>>(e_scale, ws);
  k10_scale_ln<<<1024, 256, 0, stream>>>(ln_t_g, ln_t_b, ws);
  k11_moe<<<1024, 256, 0, stream>>>(router_b ? router_w : router_w, router_b, b1, b2, ws, out);
}

// Round 6
// 395.124 us; speedup vs baseline: 4.7989x; 1.3785x over previous
//
#include <hip/hip_runtime.h>
#include <hip/hip_bf16.h>
#include <math.h>

// Problem constants: B=2,T=8,D=64,H=64,W=64,D2=128,E=4,HID=256
// token index = ((bt)*64 + h)*64 + w ; bt = b*8+t ; NTOK = 65536

// -------- workspace layout (float offsets) --------
#define W_XCL_RE 0u
#define W_XCL_IM 4194304u
#define W_C      8388608u     // xn BF16 [tok][128] (conv input); dead after k3
#define W_XMP_RE 8388608u     // x_mean partials [1024 blk][64] (reuses dead xn space, written by enc-cgemm)
#define W_XMP_IM 8454144u
#define W_EP_RE  8519680u     // |x_out|^2 partials (written by dec-cgemm)
#define W_EP_IM  8585216u
#define W_CWT    12582912u    // bf16 conv weights, fragment order [9][8][4][64][8] -> [12582912,12656640)
#define W_W1T    14680064u    // bf16 w1 transposed [4][256][128] = 65536 float-slots -> [14680064,14745600)
#define W_W2T    14745600u    // bf16 w2 transposed [4][128][256] = 65536 float-slots -> [14745600,14811136)
#define W_ENCM   14811136u    // bf16 enc cat-matrix frag order, 16384 elems = 8192 floats (AFTER w2t!)
#define W_DECM   14819328u    // bf16 dec cat-matrix frag order
#define W_EIG_RE 16777216u    // x_eigen -> u_out -> x_out (in place)
#define W_EIG_IM 20971520u
// k1 partials live in dead eig space; each is 64*1024 = 65536 floats
#define W_K1R    16777216u
#define W_K1I    16842752u
#define W_K1E    16908288u
#define W_SMALL  25165824u
#define W_TE     (W_SMALL+0u)
#define W_MOMRE  (W_SMALL+1024u)
#define W_MOMIM  (W_SMALL+2048u)
#define W_MTRE   (W_SMALL+3072u)
#define W_MTIM   (W_SMALL+4096u)
#define W_GATE   (W_SMALL+5120u)
#define W_SRCRE  (W_SMALL+6144u)
#define W_SRCIM  (W_SMALL+7168u)
#define W_OPFRE  (W_SMALL+8192u)
#define W_OPFIM  (W_SMALL+9216u)
#define W_OPDRE  (W_SMALL+10240u)
#define W_OPDIM  (W_SMALL+11264u)
#define W_SCALE  (W_SMALL+12288u)

typedef __attribute__((ext_vector_type(8))) short bf16x8;
typedef __attribute__((ext_vector_type(4))) float f32x4;

__device__ __forceinline__ unsigned short bfr(float x) {
  __hip_bfloat16 h = __float2bfloat16(x);
  return *(unsigned short*)&h;
}
__device__ __forceinline__ unsigned int pk2(float a, float b) {
  return ((unsigned int)bfr(b) << 16) | (unsigned int)bfr(a);
}

// K2: transpose (B,T,D,H,W)->(token,d) xcl; layernorm -> xn bf16; k1 partial reductions
__global__ __launch_bounds__(256) void k2_transpose_ln(
    const float* __restrict__ xre, const float* __restrict__ xim,
    const float* __restrict__ g, const float* __restrict__ bb_, float* ws) {
  int blk = blockIdx.x; int bt = blk >> 6, h = blk & 63;
  __shared__ float tre[64][65], tim[64][65];
  __shared__ float ps[4][64], pq[4][64], pe[4][64];
  __shared__ float mean_l[64], rstd_l[64];
  size_t inbase = (size_t)bt * 262144 + (size_t)h * 64; // + d*4096 + w
  for (int i = threadIdx.x; i < 4096; i += 256) {
    int d = i >> 6, w = i & 63;
    tre[d][w] = xre[inbase + (size_t)d * 4096 + w];
    tim[d][w] = xim[inbase + (size_t)d * 4096 + w];
  }
  __syncthreads();
  {
    int w = threadIdx.x & 63, part = threadIdx.x >> 6;
    float s = 0.f, sq = 0.f;
    for (int dd = part * 16; dd < part * 16 + 16; dd++) {
      float vr = tre[dd][w], vi = tim[dd][w];
      s += vr + vi; sq += vr * vr + vi * vi;
    }
    ps[part][w] = s; pq[part][w] = sq;
  }
  __syncthreads();
  if (threadIdx.x < 64) {
    int w = threadIdx.x;
    float s  = ps[0][w] + ps[1][w] + ps[2][w] + ps[3][w];
    float sq = pq[0][w] + pq[1][w] + pq[2][w] + pq[3][w];
    float m = s / 128.f;
    float v = sq / 128.f - m * m;
    mean_l[w] = m; rstd_l[w] = rsqrtf(v + 1e-5f);
  }
  __syncthreads();
  // k1 partials: per d, sum over this block's w of re, im, |.|^2  (reuses ps/pq)
  {
    int d = threadIdx.x & 63, part = threadIdx.x >> 6;
    float sr = 0.f, si = 0.f, se = 0.f;
    for (int w = part * 16; w < part * 16 + 16; w++) {
      float vr = tre[d][w], vi = tim[d][w];
      sr += vr; si += vi; se += vr * vr + vi * vi;
    }
    ps[part][d] = sr; pq[part][d] = si; pe[part][d] = se;
  }
  __syncthreads();
  if (threadIdx.x < 64) {
    int d = threadIdx.x;
    int idx = h * 1024 + bt * 64 + d;
    ws[W_K1R + idx] = ps[0][d] + ps[1][d] + ps[2][d] + ps[3][d];
    ws[W_K1I + idx] = pq[0][d] + pq[1][d] + pq[2][d] + pq[3][d];
    ws[W_K1E + idx] = pe[0][d] + pe[1][d] + pe[2][d] + pe[3][d];
  }
  size_t tokbase = (size_t)blk * 64;
  for (int i = threadIdx.x; i < 4096; i += 256) {
    int w = i >> 6, d = i & 63;
    ws[W_XCL_RE + tokbase * 64 + (size_t)w * 64 + d] = tre[d][w];
    ws[W_XCL_IM + tokbase * 64 + (size_t)w * 64 + d] = tim[d][w];
  }
  // LN -> bf16 xn, packed u32 stores (2 channels/thread)
  __hip_bfloat16* xnb = (__hip_bfloat16*)(ws + W_C);
  int c0 = (threadIdx.x & 63) * 2, wg = threadIdx.x >> 6;
  float gc0 = g[c0], bc0 = bb_[c0], gc1 = g[c0 + 1], bc1 = bb_[c0 + 1];
  for (int pass = 0; pass < 16; pass++) {
    int w = pass * 4 + wg;
    float m = mean_l[w], rs = rstd_l[w];
    float v0 = (c0 < 64) ? tre[c0][w] : tim[c0 - 64][w];
    float v1 = (c0 + 1 < 64) ? tre[c0 + 1][w] : tim[c0 + 1 - 64][w];
    *(unsigned int*)&xnb[tokbase * 128 + (size_t)w * 128 + c0] =
        pk2((v0 - m) * rs * gc0 + bc0, (v1 - m) * rs * gc1 + bc1);
  }
}

// K1b: finalize k1 partials -> momentum / target_energy per (bt,d)
__global__ void k1b_finish(float* ws) {
  int bt = blockIdx.x, d = threadIdx.x; // 16 x 64
  float a = 0.f, b = 0.f, c = 0.f;
  for (int h = 0; h < 64; h++) {
    int idx = h * 1024 + bt * 64 + d;
    a += ws[W_K1R + idx]; b += ws[W_K1I + idx]; c += ws[W_K1E + idx];
  }
  ws[W_MOMRE + bt * 64 + d] = a / 4096.f;
  ws[W_MOMIM + bt * 64 + d] = b / 4096.f;
  ws[W_TE + bt * 64 + d]    = c / 4096.f;
}

// K2b: mom_cat @ mom_w + mom_b -> momentum advection term per (bt,d)
__global__ void k2b_mom(const float* __restrict__ mom_w, const float* __restrict__ mom_b,
                        const float* __restrict__ adv_w, const float* __restrict__ dt, float* ws) {
  int bt = blockIdx.x; int t = bt & 7;
  __shared__ float mc[128], outl[128];
  int tid = threadIdx.x; // 128 threads
  mc[tid] = (tid < 64) ? ws[W_MOMRE + bt * 64 + tid] : ws[W_MOMIM + bt * 64 + tid - 64];
  __syncthreads();
  float acc = mom_b[tid];
  for (int k = 0; k < 128; k++) acc += mc[k] * mom_w[k * 128 + tid];
  outl[tid] = acc;
  __syncthreads();
  if (tid < 64) {
    float f = adv_w[0] * dt[t];
    ws[W_MTRE + bt * 64 + tid] = outl[tid] * f;
    ws[W_MTIM + bt * 64 + tid] = outl[64 + tid] * f;
  }
}

// K0w: bf16 weight prep: MoE w1/w2, conv frag-order, enc/dec cat-matrices frag-order
__global__ void k0_wprep(const float* __restrict__ w1, const float* __restrict__ w2,
                         const float* __restrict__ cw,
                         const float* __restrict__ enc_re, const float* __restrict__ enc_im,
                         const float* __restrict__ dec_re, const float* __restrict__ dec_im,
                         float* ws) {
  __hip_bfloat16* w1t = (__hip_bfloat16*)(ws + W_W1T);
  __hip_bfloat16* w2t = (__hip_bfloat16*)(ws + W_W2T);
  __hip_bfloat16* cwt = (__hip_bfloat16*)(ws + W_CWT);
  __hip_bfloat16* encM = (__hip_bfloat16*)(ws + W_ENCM);
  __hip_bfloat16* decM = (__hip_bfloat16*)(ws + W_DECM);
  int idx = blockIdx.x * 256 + threadIdx.x; // 0..147455
  if (idx < 131072) {
    int d = idx & 127, r = idx >> 7;
    int hh = r & 255, e = r >> 8;
    w1t[idx] = __float2bfloat16(w1[((size_t)(e * 128 + d)) * 256 + hh]);
    int h2 = idx & 255, r2 = idx >> 8;
    int dout = r2 & 127, e2 = r2 >> 7;
    w2t[idx] = __float2bfloat16(w2[((size_t)(e2 * 256 + h2)) * 128 + dout]);
  }
  if (idx < 147456) {
    int j = idx & 7, lane = (idx >> 3) & 63, kt = (idx >> 9) & 3, r = idx >> 11;
    int nt = r & 7, tap = r >> 3;
    int cout = nt * 16 + (lane & 15);
    int cin = kt * 32 + (lane >> 4) * 8 + j;
    cwt[idx] = __float2bfloat16(cw[((size_t)(tap * 128 + cin)) * 128 + cout]);
  }
  if (idx < 16384) {
    // cat matrix frag order: eidx = ((nt*4+kt)*64+lane)*8+jj
    int jj = idx & 7, lane = (idx >> 3) & 63, kt = (idx >> 9) & 3, nt = idx >> 11;
    int jc = nt * 16 + (lane & 15);
    int k = kt * 32 + (lane >> 4) * 8 + jj;
    float ve, vd;
    if (k < 64) {
      ve = (jc < 64) ? enc_re[k * 64 + jc] : enc_im[k * 64 + (jc - 64)];
      vd = (jc < 64) ? dec_re[k * 64 + jc] : dec_im[k * 64 + (jc - 64)];
    } else {
      int kk = k - 64;
      ve = (jc < 64) ? -enc_im[kk * 64 + jc] : enc_re[kk * 64 + (jc - 64)];
      vd = (jc < 64) ? -dec_im[kk * 64 + jc] : dec_re[kk * 64 + (jc - 64)];
    }
    encM[idx] = __float2bfloat16(ve);
    decM[idx] = __float2bfloat16(vd);
  }
}

// K3: 3x3 SAME conv via bf16 MFMA; xcl += conv_y + conv_b + mom_term
__global__ __launch_bounds__(256) void k3_conv(const float* __restrict__ cb, float* ws) {
  int blk = blockIdx.x; int bt = blk >> 6, h = blk & 63;
  const __hip_bfloat16* xnb = (const __hip_bfloat16*)(ws + W_C);
  const __hip_bfloat16* cwt = (const __hip_bfloat16*)(ws + W_CWT);
  __shared__ __align__(16) __hip_bfloat16 xin[3][66][136];
  int tid = threadIdx.x, lane = tid & 63, wv = tid >> 6;
  int arow = lane & 15, kgrp = (lane >> 4) * 8, rbase = (lane >> 4) * 4;

  for (int r = 0; r < 3; r++) {
    int hh = h + r - 1;
    if (hh < 0 || hh >= 64) {
      unsigned int* z = (unsigned int*)&xin[r][0][0];
      for (int i = tid; i < 4488; i += 256) z[i] = 0u;
    } else {
      if (tid < 68) *(unsigned int*)&xin[r][0][tid * 2] = 0u;
      else if (tid < 136) *(unsigned int*)&xin[r][65][(tid - 136 + 68) * 2] = 0u;
      const __hip_bfloat16* src = xnb + ((size_t)bt * 4096 + (size_t)hh * 64) * 128;
      for (int i = tid; i < 1024; i += 256) {
        int wp = (i >> 4) + 1, c8 = (i & 15) * 8;
        *(bf16x8*)&xin[r][wp][c8] = *(const bf16x8*)&src[(size_t)(wp - 1) * 128 + c8];
      }
    }
  }
  __syncthreads();

  f32x4 oacc[4][2];
  #pragma unroll
  for (int m = 0; m < 4; m++) {
    oacc[m][0] = (f32x4){0.f, 0.f, 0.f, 0.f};
    oacc[m][1] = (f32x4){0.f, 0.f, 0.f, 0.f};
  }

  for (int tap = 0; tap < 9; tap++) {
    int kh = tap / 3, kw = tap % 3;
    const __hip_bfloat16* wt0 = cwt + ((size_t)(tap * 8 + wv * 2) * 4) * 512 + lane * 8;
    #pragma unroll
    for (int kt = 0; kt < 4; kt++) {
      bf16x8 a[4];
      #pragma unroll
      for (int m = 0; m < 4; m++)
        a[m] = *(const bf16x8*)&xin[kh][m * 16 + arow + kw][kt * 32 + kgrp];
      bf16x8 b0 = *(const bf16x8*)&wt0[(size_t)kt * 512];
      bf16x8 b1 = *(const bf16x8*)&wt0[(size_t)(kt + 4) * 512];
      #pragma unroll
      for (int m = 0; m < 4; m++) {
        oacc[m][0] = __builtin_amdgcn_mfma_f32_16x16x32_bf16(a[m], b0, oacc[m][0], 0, 0, 0);
        oacc[m][1] = __builtin_amdgcn_mfma_f32_16x16x32_bf16(a[m], b1, oacc[m][1], 0, 0, 0);
      }
    }
  }

  size_t rowtok = (size_t)blk * 64;
  #pragma unroll
  for (int n = 0; n < 2; n++) {
    int cout = (wv * 2 + n) * 16 + arow;
    bool isre = cout < 64;
    int d = cout & 63;
    float add = cb[cout] + ws[(isre ? W_MTRE : W_MTIM) + bt * 64 + d];
    float* xcl = ws + (isre ? W_XCL_RE : W_XCL_IM);
    #pragma unroll
    for (int m = 0; m < 4; m++)
      #pragma unroll
      for (int r = 0; r < 4; r++) {
        int w = m * 16 + rbase + r;
        xcl[(rowtok + w) * 64 + d] += oacc[m][n][r] + add;
      }
  }
}

// K_CGEMM: complex 64x64 matmul as 64x128x128 bf16 MFMA GEMM with fused spatial partials.
// mode 1: partial = sum(C) (x_mean); mode 2: partial = sum(C^2) (|x_out|^2)
__global__ __launch_bounds__(256) void k_cgemm(float* ws, long moff,
                                               long ire, long iim, long ore, long oim,
                                               long pre, long pim, int mode) {
  int blk = blockIdx.x;
  const __hip_bfloat16* M = (const __hip_bfloat16*)(ws + moff);
  __shared__ __align__(16) char A[16384]; // bf16 [64 rows][256B] XOR-swizzled
  int tid = threadIdx.x, lane = tid & 63, wv = tid >> 6;
  int arow = lane & 15, kgrp = (lane >> 4) * 8, rbase = (lane >> 4) * 4;
  size_t tokbase = (size_t)blk * 64;
  const float* pr_ = ws + ire;
  const float* pi_ = ws + iim;
  for (int i = tid; i < 2048; i += 256) {
    int w = i >> 5, dp = (i & 31) * 2;
    float2 vr = *(const float2*)&pr_[(tokbase + w) * 64 + dp];
    float2 vi = *(const float2*)&pi_[(tokbase + w) * 64 + dp];
    int sz = (w & 7) << 4;
    *(unsigned int*)(A + w * 256 + ((dp * 2) ^ sz)) = pk2(vr.x, vr.y);
    *(unsigned int*)(A + w * 256 + (((64 + dp) * 2) ^ sz)) = pk2(vi.x, vi.y);
  }
  __syncthreads();
  f32x4 acc[4][2];
  #pragma unroll
  for (int m = 0; m < 4; m++) {
    acc[m][0] = (f32x4){0.f, 0.f, 0.f, 0.f};
    acc[m][1] = (f32x4){0.f, 0.f, 0.f, 0.f};
  }
  #pragma unroll
  for (int kt = 0; kt < 4; kt++) {
    bf16x8 a[4];
    #pragma unroll
    for (int m = 0; m < 4; m++)
      a[m] = *(const bf16x8*)(A + (m * 16 + arow) * 256 + (((kt * 32 + kgrp) * 2) ^ ((arow & 7) << 4)));
    bf16x8 b0 = *(const bf16x8*)&M[(((size_t)(wv * 2 + 0) * 4 + kt) * 64 + lane) * 8];
    bf16x8 b1 = *(const bf16x8*)&M[(((size_t)(wv * 2 + 1) * 4 + kt) * 64 + lane) * 8];
    #pragma unroll
    for (int m = 0; m < 4; m++) {
      acc[m][0] = __builtin_amdgcn_mfma_f32_16x16x32_bf16(a[m], b0, acc[m][0], 0, 0, 0);
      acc[m][1] = __builtin_amdgcn_mfma_f32_16x16x32_bf16(a[m], b1, acc[m][1], 0, 0, 0);
    }
  }
  float* orp = ws + ore;
  float* oip = ws + oim;
  #pragma unroll
  for (int n = 0; n < 2; n++) {
    int jc = (wv * 2 + n) * 16 + arow;
    float* dst = (jc < 64) ? orp : oip;
    int col = jc & 63;
    #pragma unroll
    for (int m = 0; m < 4; m++)
      #pragma unroll
      for (int r = 0; r < 4; r++)
        dst[(tokbase + m * 16 + rbase + r) * 64 + col] = acc[m][n][r];
    // fused spatial partial over this block's 64 tokens
    float s = 0.f;
    if (mode == 1) {
      #pragma unroll
      for (int m = 0; m < 4; m++)
        #pragma unroll
        for (int r = 0; r < 4; r++) s += acc[m][n][r];
    } else {
      #pragma unroll
      for (int m = 0; m < 4; m++)
        #pragma unroll
        for (int r = 0; r < 4; r++) s += acc[m][n][r] * acc[m][n][r];
    }
    s += __shfl_xor(s, 16);
    s += __shfl_xor(s, 32);
    if (lane < 16)
      ws[(jc < 64 ? pre : pim) + (size_t)blk * 64 + (jc & 63)] = s;
  }
}

__device__ __forceinline__ float softplusf(float x) {
  return (x > 20.f) ? x : log1pf(expf(x));
}

// K6: X_flux, flux scan, source, gate, op_decay/op_forcing — tiny (B,T,D) work
__global__ void k6_seq(const float* __restrict__ fin_re, const float* __restrict__ fin_im,
                       const float* __restrict__ fproj_re, const float* __restrict__ fproj_im,
                       const float* __restrict__ flux_a_re, const float* __restrict__ flux_a_im,
                       const float* __restrict__ gate_w, const float* __restrict__ gate_b,
                       const float* __restrict__ lam_re, const float* __restrict__ lam_im,
                       const float* __restrict__ dt, float* ws) {
  __shared__ float xmr[1024], xmi[1024], Xfr[1024], Xfi[1024], flr[1024], fli[1024];
  int tid = threadIdx.x;
  for (int i = tid; i < 1024; i += 256) {
    int bt = i >> 6, j = i & 63;
    float sr = 0.f, si = 0.f;
    for (int q = 0; q < 64; q++) {
      sr += ws[W_XMP_RE + (size_t)(bt * 64 + q) * 64 + j];
      si += ws[W_XMP_IM + (size_t)(bt * 64 + q) * 64 + j];
    }
    xmr[i] = sr / 4096.f; xmi[i] = si / 4096.f;
  }
  __syncthreads();
  for (int i = tid; i < 1024; i += 256) {
    int bt = i >> 6, j = i & 63;
    float ar = 0.f, ai = 0.f;
    for (int d = 0; d < 64; d++) {
      float xr = xmr[bt * 64 + d], xi = xmi[bt * 64 + d];
      float wr = fin_re[d * 64 + j], wi = fin_im[d * 64 + j];
      ar += xr * wr - xi * wi; ai += xr * wi + xi * wr;
    }
    Xfr[i] = ar; Xfi[i] = ai;
  }
  __syncthreads();
  if (tid < 128) {
    int b = tid >> 6, j = tid & 63;
    float mag = expf(-softplusf(flux_a_re[j]));
    float aar = mag * cosf(flux_a_im[j]), aai = mag * sinf(flux_a_im[j]);
    float sr = 0.f, si = 0.f;
    for (int t = 0; t < 8; t++) {
      int idx = (b * 8 + t) * 64 + j;
      float nr = aar * sr - aai * si + Xfr[idx];
      float ni = aar * si + aai * sr + Xfi[idx];
      sr = nr; si = ni;
      flr[idx] = sr; fli[idx] = si;
    }
  }
  __syncthreads();
  for (int i = tid; i < 1024; i += 256) {
    int bt = i >> 6, j = i & 63;
    float ar = 0.f, ai = 0.f, lg = 0.f;
    for (int d = 0; d < 64; d++) {
      float fr = flr[bt * 64 + d], fi = fli[bt * 64 + d];
      float wr = fproj_re[d * 64 + j], wi = fproj_im[d * 64 + j];
      ar += fr * wr - fi * wi; ai += fr * wi + fi * wr;
      lg += fr * gate_w[d * 64 + j] + fi * gate_w[(64 + d) * 64 + j];
    }
    ws[W_SRCRE + i] = ar; ws[W_SRCIM + i] = ai;
    ws[W_GATE + i] = 1.f / (1.f + expf(-(lg + gate_b[j])));
  }
  for (int i = tid; i < 1024; i += 256) {
    int bt = i >> 6, d = i & 63, t = bt & 7;
    float lr = -softplusf(lam_re[d]), li = lam_im[d];
    float dtv = dt[t];
    float mag = expf(lr * dtv);
    float dr = mag * cosf(li * dtv), di = mag * sinf(li * dtv);
    ws[W_OPDRE + i] = dr; ws[W_OPDIM + i] = di;
    float omr = dr - 1.f, omi = di;
    float den = lr * lr + li * li;
    ws[W_OPFRE + i] = (omr * lr + omi * li) / den;
    ws[W_OPFIM + i] = (omi * lr - omr * li) / den;
  }
}

// K7: forcing -> u_t -> time scan (T=8) -> + noise, in place over eig buffer
__global__ __launch_bounds__(256) void k7_scan(const float* __restrict__ nre,
                                               const float* __restrict__ nim,
                                               const float* __restrict__ dt, float* ws) {
  int blk = blockIdx.x; int b = blk >> 6, h = blk & 63;
  __shared__ float gl[8][64], srl[8][64], sil[8][64], ofr[8][64], ofi[8][64], odr[8][64], odi[8][64];
  int tid = threadIdx.x;
  for (int i = tid; i < 512; i += 256) {
    int t = i >> 6, d = i & 63, idx = (b * 8 + t) * 64 + d;
    gl[t][d]  = ws[W_GATE + idx];
    srl[t][d] = ws[W_SRCRE + idx]; sil[t][d] = ws[W_SRCIM + idx];
    ofr[t][d] = ws[W_OPFRE + idx]; ofi[t][d] = ws[W_OPFIM + idx];
    odr[t][d] = ws[W_OPDRE + idx]; odi[t][d] = ws[W_OPDIM + idx];
  }
  __syncthreads();
  float ur[16], ui[16];
  #pragma unroll
  for (int k = 0; k < 16; k++) { ur[k] = 0.f; ui[k] = 0.f; }
  for (int t = 0; t < 8; t++) {
    float ns = 0.01f * sqrtf(dt[t]);
    size_t tokbase = ((size_t)(b * 8 + t) * 64 + h) * 64;
    for (int k = 0; k < 16; k++) {
      int idx = tid + 256 * k;
      int w = idx >> 6, d = idx & 63;
      size_t off = (tokbase + w) * 64 + d;
      float er_ = ws[W_EIG_RE + off], ei_ = ws[W_EIG_IM + off];
      float gg = gl[t][d];
      float fre = er_ * gg + srl[t][d] * (1.f - gg);
      float fim = ei_ * gg + sil[t][d] * (1.f - gg);
      float utr = fre * ofr[t][d] - fim * ofi[t][d];
      float uti = fre * ofi[t][d] + fim * ofr[t][d];
      float nur = odr[t][d] * ur[k] - odi[t][d] * ui[k] + utr;
      float nui = odr[t][d] * ui[k] + odi[t][d] * ur[k] + uti;
      ur[k] = nur; ui[k] = nui;
      ws[W_EIG_RE + off] = nur + ns * nre[off];
      ws[W_EIG_IM + off] = nui + ns * nim[off];
    }
  }
}

// K9b: combine |x_out|^2 partials -> energy rescale factor per (bt,d)
__global__ void k9b_scale(const float* __restrict__ escale, float* ws) {
  int bt = blockIdx.x; int j = threadIdx.x; // 16 x 64
  float s = 0.f;
  for (int q = 0; q < 64; q++) {
    size_t idx = (size_t)(bt * 64 + q) * 64 + j;
    s += ws[W_EP_RE + idx] + ws[W_EP_IM + idx];
  }
  float cur = s / 4096.f;
  float te = ws[W_TE + bt * 64 + j];
  float ratio = te / (cur + 1e-8f);
  ratio = fminf(fmaxf(ratio, 0.5f), 2.0f);
  ws[W_SCALE + bt * 64 + j] = 1.f + escale[0] * (sqrtf(ratio) - 1.f);
}

// K11: fused scale+LN2 + MFMA MoE + residuals + output transpose (k10+k11+k12)
__global__ __launch_bounds__(256) void k11_moe(
    const float* __restrict__ rw, const float* __restrict__ rb,
    const float* __restrict__ b1, const float* __restrict__ b2,
    const float* __restrict__ g2, const float* __restrict__ b2_,
    float* __restrict__ ws, float* __restrict__ out) {
  int blk = blockIdx.x; int bt = blk >> 6, h = blk & 63;
  const __hip_bfloat16* w1t = (const __hip_bfloat16*)(ws + W_W1T);
  const __hip_bfloat16* w2t = (const __hip_bfloat16*)(ws + W_W2T);
  __shared__ __align__(16) char bufA[33024]; // lv f32[64][129] -> hbuf bf16 64x512B -> obuf f32[64][129]
  __shared__ __align__(16) char bufB[16384]; // ltok bf16 64x256B XOR-swizzled
  __shared__ float pl[64][4];
  __shared__ float sc[64];
  __shared__ float ps[4][64], pq[4][64], mean_l[64], rstd_l[64];
  float (*lv)[129] = (float(*)[129])bufA;
  float (*obuf)[129] = (float(*)[129])bufA;
  char* hb = bufA;
  char* lt = bufB;
  int tid = threadIdx.x, lane = tid & 63, wv = tid >> 6;
  int arow = lane & 15, kgrp = (lane >> 4) * 8, rbase = (lane >> 4) * 4;
  size_t tokbase = (size_t)blk * 64;

  if (tid < 64) sc[tid] = ws[W_SCALE + bt * 64 + tid];
  __syncthreads();
  // load x_out * sf into lv
  {
    const float* er = ws + W_EIG_RE;
    const float* ei = ws + W_EIG_IM;
    for (int i = tid; i < 4096; i += 256) {
      int w = i >> 6, d = i & 63;
      float s = sc[d];
      lv[w][d]      = er[(tokbase + w) * 64 + d] * s;
      lv[w][64 + d] = ei[(tokbase + w) * 64 + d] * s;
    }
  }
  __syncthreads();
  // LN stats
  {
    int w = tid & 63, part = tid >> 6;
    float s = 0.f, sq = 0.f;
    for (int c = part * 32; c < part * 32 + 32; c++) {
      float v = lv[w][c]; s += v; sq += v * v;
    }
    ps[part][w] = s; pq[part][w] = sq;
  }
  __syncthreads();
  if (tid < 64) {
    int w = tid;
    float s  = ps[0][w] + ps[1][w] + ps[2][w] + ps[3][w];
    float sq = pq[0][w] + pq[1][w] + pq[2][w] + pq[3][w];
    float m = s / 128.f, v = sq / 128.f - m * m;
    mean_l[w] = m; rstd_l[w] = rsqrtf(v + 1e-5f);
  }
  __syncthreads();
  // LN -> ltok bf16 (swizzled)
  {
    int c0 = (tid & 63) * 2, wg = tid >> 6;
    float gc0 = g2[c0], bc0 = b2_[c0], gc1 = g2[c0 + 1], bc1 = b2_[c0 + 1];
    for (int pass = 0; pass < 16; pass++) {
      int w = pass * 4 + wg;
      float m = mean_l[w], rs = rstd_l[w];
      *(unsigned int*)(lt + w * 256 + (((unsigned)c0 * 2) ^ ((w & 7) << 4))) =
          pk2((lv[w][c0] - m) * rs * gc0 + bc0, (lv[w][c0 + 1] - m) * rs * gc1 + bc1);
    }
  }
  __syncthreads(); // lv dead; ltok ready
  // router logits
  {
    int l = tid >> 2, e = tid & 3;
    float acc = rb[e];
    const float* rwe = rw + e;
    int sz = (l & 7) << 4;
    for (int dd = 0; dd < 128; dd += 2) {
      unsigned int u = *(const unsigned int*)(lt + l * 256 + ((dd * 2) ^ sz));
      float x0 = __uint_as_float(u << 16);
      float x1 = __uint_as_float(u & 0xffff0000u);
      acc += x0 * rwe[dd * 4] + x1 * rwe[dd * 4 + 4];
    }
    pl[l][e] = acc;
  }
  __syncthreads();
  if (tid < 64) {
    float m = fmaxf(fmaxf(pl[tid][0], pl[tid][1]), fmaxf(pl[tid][2], pl[tid][3]));
    float e0 = expf(pl[tid][0] - m), e1 = expf(pl[tid][1] - m);
    float e2 = expf(pl[tid][2] - m), e3 = expf(pl[tid][3] - m);
    float s = e0 + e1 + e2 + e3;
    pl[tid][0] = e0 / s; pl[tid][1] = e1 / s; pl[tid][2] = e2 / s; pl[tid][3] = e3 / s;
  }

  // out accumulator init = tok residual
  f32x4 oacc[4][2];
  #pragma unroll
  for (int m = 0; m < 4; m++)
    #pragma unroll
    for (int n2 = 0; n2 < 2; n2++) {
      int col = (wv * 2 + n2) * 16 + arow;
      #pragma unroll
      for (int r = 0; r < 4; r++) {
        int row = m * 16 + rbase + r;
        oacc[m][n2][r] = __bfloat162float(
            *(const __hip_bfloat16*)(lt + row * 256 + ((col * 2) ^ ((row & 7) << 4))));
      }
    }
  __syncthreads();

  for (int e = 0; e < 4; e++) {
    // layer1: h = tok @ w1[e]
    f32x4 acc1[4][4];
    #pragma unroll
    for (int m = 0; m < 4; m++)
      #pragma unroll
      for (int n = 0; n < 4; n++) acc1[m][n] = (f32x4){0.f, 0.f, 0.f, 0.f};
    const __hip_bfloat16* w1e = w1t + (size_t)e * 32768;
    for (int kt = 0; kt < 4; kt++) {
      bf16x8 a[4], b[4];
      #pragma unroll
      for (int m = 0; m < 4; m++) {
        int row = m * 16 + arow;
        a[m] = *(const bf16x8*)(lt + row * 256 + (((kt * 32 + kgrp) * 2) ^ ((arow & 7) << 4)));
      }
      #pragma unroll
      for (int n = 0; n < 4; n++)
        b[n] = *(const bf16x8*)&w1e[((size_t)((wv * 4 + n) * 16 + arow)) * 128 + kt * 32 + kgrp];
      #pragma unroll
      for (int m = 0; m < 4; m++)
        #pragma unroll
        for (int n = 0; n < 4; n++)
          acc1[m][n] = __builtin_amdgcn_mfma_f32_16x16x32_bf16(a[m], b[n], acc1[m][n], 0, 0, 0);
    }
    __syncthreads(); // hbuf region free
    #pragma unroll
    for (int n = 0; n < 4; n++) {
      int col = (wv * 4 + n) * 16 + arow;
      float bv = b1[e * 256 + col];
      #pragma unroll
      for (int m = 0; m < 4; m++)
        #pragma unroll
        for (int r = 0; r < 4; r++) {
          float hv = acc1[m][n][r] + bv;
          float z = 1.5957691216f * hv + 0.0713548162f * hv * hv * hv;
          float gelu = hv / (1.f + __expf(-z));
          int row = m * 16 + rbase + r;
          *(__hip_bfloat16*)(hb + row * 512 + ((col * 2) ^ ((row & 7) << 4))) =
              __float2bfloat16(gelu);
        }
    }
    __syncthreads();
    // layer2: eout = h @ w2[e]
    f32x4 acc2[4][2];
    #pragma unroll
    for (int m = 0; m < 4; m++)
      #pragma unroll
      for (int n = 0; n < 2; n++) acc2[m][n] = (f32x4){0.f, 0.f, 0.f, 0.f};
    const __hip_bfloat16* w2e = w2t + (size_t)e * 32768;
    for (int kt = 0; kt < 8; kt++) {
      bf16x8 a2[4], bb[2];
      #pragma unroll
      for (int m = 0; m < 4; m++) {
        int row = m * 16 + arow;
        a2[m] = *(const bf16x8*)(hb + row * 512 + (((kt * 32 + kgrp) * 2) ^ ((arow & 7) << 4)));
      }
      #pragma unroll
      for (int n = 0; n < 2; n++)
        bb[n] = *(const bf16x8*)&w2e[((size_t)((wv * 2 + n) * 16 + arow)) * 256 + kt * 32 + kgrp];
      #pragma unroll
      for (int m = 0; m < 4; m++)
        #pragma unroll
        for (int n = 0; n < 2; n++)
          acc2[m][n] = __builtin_amdgcn_mfma_f32_16x16x32_bf16(a2[m], bb[n], acc2[m][n], 0, 0, 0);
    }
    #pragma unroll
    for (int n = 0; n < 2; n++) {
      int col = (wv * 2 + n) * 16 + arow;
      float bv2 = b2[e * 128 + col];
      #pragma unroll
      for (int m = 0; m < 4; m++)
        #pragma unroll
        for (int r = 0; r < 4; r++)
          oacc[m][n][r] += pl[m * 16 + rbase + r][e] * (acc2[m][n][r] + bv2);
    }
  }

  __syncthreads(); // hbuf reads done -> obuf
  #pragma unroll
  for (int m = 0; m < 4; m++)
    #pragma unroll
    for (int n2 = 0; n2 < 2; n2++) {
      int col = (wv * 2 + n2) * 16 + arow;
      #pragma unroll
      for (int r = 0; r < 4; r++)
        obuf[m * 16 + rbase + r][col] = oacc[m][n2][r];
    }
  __syncthreads();

  // residual add (coalesced reads)
  {
    const float* xre = ws + W_XCL_RE;
    const float* xim = ws + W_XCL_IM;
    for (int i = tid; i < 8192; i += 256) {
      int w = i >> 7, c = i & 127, dd = c & 63;
      float val = ((c < 64) ? xre : xim)[(tokbase + w) * 64 + dd];
      obuf[w][c] += val;
    }
  }
  __syncthreads();
  // transpose out to (2,B,T,D,H,W)
  for (int i = tid; i < 8192; i += 256) {
    int d2 = i >> 6, w = i & 63;
    out[(size_t)(d2 >> 6) * 4194304 + (size_t)bt * 262144 + (size_t)(d2 & 63) * 4096
        + (size_t)h * 64 + w] = obuf[w][d2];
  }
}

extern "C" void kernel_launch(void* const* d_in, const int* in_sizes, int n_in,
                              void* d_out, int out_size, void* d_ws, size_t ws_size,
                              hipStream_t stream) {
  const float* x_re      = (const float*)d_in[0];
  const float* x_im      = (const float*)d_in[1];
  const float* dt        = (const float*)d_in[2];
  const float* ln_s_g    = (const float*)d_in[3];
  const float* ln_s_b    = (const float*)d_in[4];
  const float* conv_w    = (const float*)d_in[5];
  const float* conv_b    = (const float*)d_in[6];
  const float* mom_w     = (const float*)d_in[7];
  const float* mom_b     = (const float*)d_in[8];
  const float* adv_w     = (const float*)d_in[9];
  const float* enc_re    = (const float*)d_in[10];
  const float* enc_im    = (const float*)d_in[11];
  const float* dec_re    = (const float*)d_in[12];
  const float* dec_im    = (const float*)d_in[13];
  const float* flux_a_re = (const float*)d_in[14];
  const float* flux_a_im = (const float*)d_in[15];
  const float* fin_re    = (const float*)d_in[16];
  const float* fin_im    = (const float*)d_in[17];
  const float* fproj_re  = (const float*)d_in[18];
  const float* fproj_im  = (const float*)d_in[19];
  const float* gate_w    = (const float*)d_in[20];
  const float* gate_b    = (const float*)d_in[21];
  const float* lam_re    = (const float*)d_in[22];
  const float* lam_im    = (const float*)d_in[23];
  const float* noise_re  = (const float*)d_in[24];
  const float* noise_im  = (const float*)d_in[25];
  const float* e_scale   = (const float*)d_in[26];
  const float* ln_t_g    = (const float*)d_in[27];
  const float* ln_t_b    = (const float*)d_in[28];
  const float* router_w  = (const float*)d_in[29];
  const float* router_b  = (const float*)d_in[30];
  const float* w1        = (const float*)d_in[31];
  const float* b1        = (const float*)d_in[32];
  const float* w2        = (const float*)d_in[33];
  const float* b2        = (const float*)d_in[34];
  float* ws  = (float*)d_ws;
  float* out = (float*)d_out;

  k0_wprep<<<576, 256, 0, stream>>>(w1, w2, conv_w, enc_re, enc_im, dec_re, dec_im, ws);
  k2_transpose_ln<<<1024, 256, 0, stream>>>(x_re, x_im, ln_s_g, ln_s_b, ws);
  k1b_finish<<<16, 64, 0, stream>>>(ws);
  k2b_mom<<<16, 128, 0, stream>>>(mom_w, mom_b, adv_w, dt, ws);
  k3_conv<<<1024, 256, 0, stream>>>(conv_b, ws);
  k_cgemm<<<1024, 256, 0, stream>>>(ws, (long)W_ENCM,
      (long)W_XCL_RE, (long)W_XCL_IM, (long)W_EIG_RE, (long)W_EIG_IM,
      (long)W_XMP_RE, (long)W_XMP_IM, 1);
  k6_seq<<<1, 256, 0, stream>>>(fin_re, fin_im, fproj_re, fproj_im, flux_a_re, flux_a_im,
                                gate_w, gate_b, lam_re, lam_im, dt, ws);
  k7_scan<<<128, 256, 0, stream>>>(noise_re, noise_im, dt, ws);
  k_cgemm<<<1024, 256, 0, stream>>>(ws, (long)W_DECM,
      (long)W_EIG_RE, (long)W_EIG_IM, (long)W_EIG_RE, (long)W_EIG_IM,
      (long)W_EP_RE, (long)W_EP_IM, 2);
  k9b_scale<<<16, 64, 0, stream>>>(e_scale, ws);
  k11_moe<<<1024, 256, 0, stream>>>(router_w, router_b, b1, b2, ln_t_g, ln_t_b, ws, out);
}

// Round 7
// 339.580 us; speedup vs baseline: 5.5839x; 1.1636x over previous
//
#include <hip/hip_runtime.h>
#include <hip/hip_bf16.h>
#include <math.h>

// Problem constants: B=2,T=8,D=64,H=64,W=64,D2=128,E=4,HID=256
// token index = ((bt)*64 + h)*64 + w ; bt = b*8+t ; NTOK = 65536

// -------- workspace layout (float offsets) --------
#define W_XCL_RE 0u
#define W_XCL_IM 4194304u
#define W_C      8388608u     // xn BF16 [tok][128] (conv input); dead after k3
#define W_XMP_RE 8388608u     // x_mean partials [1024 blk][64] (reuses dead xn space, written by enc-cgemm)
#define W_XMP_IM 8454144u
#define W_EP_RE  8519680u     // |x_out|^2 partials (written by dec-cgemm)
#define W_EP_IM  8585216u
#define W_CWT    12582912u    // bf16 conv weights, fragment order [9][8][4][64][8] -> [12582912,12656640)
#define W_W1T    14680064u    // bf16 w1 FRAGMENT order [4][16 nt][4 kt][64][8] -> [14680064,14745600)
#define W_W2T    14745600u    // bf16 w2 FRAGMENT order [4][8 nt][8 kt][64][8] -> [14745600,14811136)
#define W_ENCM   14811136u    // bf16 enc cat-matrix frag order, 16384 elems = 8192 floats
#define W_DECM   14819328u    // bf16 dec cat-matrix frag order
#define W_EIG_RE 16777216u    // x_eigen -> u_out -> x_out (in place)
#define W_EIG_IM 20971520u
// k1 partials live in dead eig space; each is 64*1024 = 65536 floats
#define W_K1R    16777216u
#define W_K1I    16842752u
#define W_K1E    16908288u
#define W_SMALL  25165824u
#define W_TE     (W_SMALL+0u)
#define W_MOMRE  (W_SMALL+1024u)
#define W_MOMIM  (W_SMALL+2048u)
#define W_MTRE   (W_SMALL+3072u)
#define W_MTIM   (W_SMALL+4096u)
#define W_GATE   (W_SMALL+5120u)
#define W_SRCRE  (W_SMALL+6144u)
#define W_SRCIM  (W_SMALL+7168u)
#define W_OPFRE  (W_SMALL+8192u)
#define W_OPFIM  (W_SMALL+9216u)
#define W_OPDRE  (W_SMALL+10240u)
#define W_OPDIM  (W_SMALL+11264u)
#define W_SCALE  (W_SMALL+12288u)

typedef __attribute__((ext_vector_type(8))) short bf16x8;
typedef __attribute__((ext_vector_type(4))) float f32x4;

__device__ __forceinline__ unsigned short bfr(float x) {
  __hip_bfloat16 h = __float2bfloat16(x);
  return *(unsigned short*)&h;
}
__device__ __forceinline__ unsigned int pk2(float a, float b) {
  return ((unsigned int)bfr(b) << 16) | (unsigned int)bfr(a);
}

// K2: transpose (B,T,D,H,W)->(token,d) xcl; layernorm -> xn bf16; k1 partial reductions
__global__ __launch_bounds__(256) void k2_transpose_ln(
    const float* __restrict__ xre, const float* __restrict__ xim,
    const float* __restrict__ g, const float* __restrict__ bb_, float* ws) {
  int blk = blockIdx.x; int bt = blk >> 6, h = blk & 63;
  __shared__ float tre[64][65], tim[64][65];
  __shared__ float ps[4][64], pq[4][64], pe[4][64];
  __shared__ float mean_l[64], rstd_l[64];
  size_t inbase = (size_t)bt * 262144 + (size_t)h * 64; // + d*4096 + w
  for (int i = threadIdx.x; i < 1024; i += 256) {
    int d = i >> 4, w4 = (i & 15) * 4;
    float4 vr = *(const float4*)&xre[inbase + (size_t)d * 4096 + w4];
    float4 vi = *(const float4*)&xim[inbase + (size_t)d * 4096 + w4];
    tre[d][w4] = vr.x; tre[d][w4 + 1] = vr.y; tre[d][w4 + 2] = vr.z; tre[d][w4 + 3] = vr.w;
    tim[d][w4] = vi.x; tim[d][w4 + 1] = vi.y; tim[d][w4 + 2] = vi.z; tim[d][w4 + 3] = vi.w;
  }
  __syncthreads();
  {
    int w = threadIdx.x & 63, part = threadIdx.x >> 6;
    float s = 0.f, sq = 0.f;
    for (int dd = part * 16; dd < part * 16 + 16; dd++) {
      float vr = tre[dd][w], vi = tim[dd][w];
      s += vr + vi; sq += vr * vr + vi * vi;
    }
    ps[part][w] = s; pq[part][w] = sq;
  }
  __syncthreads();
  if (threadIdx.x < 64) {
    int w = threadIdx.x;
    float s  = ps[0][w] + ps[1][w] + ps[2][w] + ps[3][w];
    float sq = pq[0][w] + pq[1][w] + pq[2][w] + pq[3][w];
    float m = s / 128.f;
    float v = sq / 128.f - m * m;
    mean_l[w] = m; rstd_l[w] = rsqrtf(v + 1e-5f);
  }
  __syncthreads();
  // k1 partials: per d, sum over this block's w of re, im, |.|^2  (reuses ps/pq)
  {
    int d = threadIdx.x & 63, part = threadIdx.x >> 6;
    float sr = 0.f, si = 0.f, se = 0.f;
    for (int w = part * 16; w < part * 16 + 16; w++) {
      float vr = tre[d][w], vi = tim[d][w];
      sr += vr; si += vi; se += vr * vr + vi * vi;
    }
    ps[part][d] = sr; pq[part][d] = si; pe[part][d] = se;
  }
  __syncthreads();
  if (threadIdx.x < 64) {
    int d = threadIdx.x;
    int idx = h * 1024 + bt * 64 + d;
    ws[W_K1R + idx] = ps[0][d] + ps[1][d] + ps[2][d] + ps[3][d];
    ws[W_K1I + idx] = pq[0][d] + pq[1][d] + pq[2][d] + pq[3][d];
    ws[W_K1E + idx] = pe[0][d] + pe[1][d] + pe[2][d] + pe[3][d];
  }
  size_t tokbase = (size_t)blk * 64;
  for (int i = threadIdx.x; i < 1024; i += 256) {
    int w = i >> 4, d4 = (i & 15) * 4;
    float4 o, p;
    o.x = tre[d4][w]; o.y = tre[d4 + 1][w]; o.z = tre[d4 + 2][w]; o.w = tre[d4 + 3][w];
    p.x = tim[d4][w]; p.y = tim[d4 + 1][w]; p.z = tim[d4 + 2][w]; p.w = tim[d4 + 3][w];
    *(float4*)&ws[W_XCL_RE + tokbase * 64 + (size_t)w * 64 + d4] = o;
    *(float4*)&ws[W_XCL_IM + tokbase * 64 + (size_t)w * 64 + d4] = p;
  }
  // LN -> bf16 xn, packed u32 stores (2 channels/thread)
  __hip_bfloat16* xnb = (__hip_bfloat16*)(ws + W_C);
  int c0 = (threadIdx.x & 63) * 2, wg = threadIdx.x >> 6;
  float gc0 = g[c0], bc0 = bb_[c0], gc1 = g[c0 + 1], bc1 = bb_[c0 + 1];
  for (int pass = 0; pass < 16; pass++) {
    int w = pass * 4 + wg;
    float m = mean_l[w], rs = rstd_l[w];
    float v0 = (c0 < 64) ? tre[c0][w] : tim[c0 - 64][w];
    float v1 = (c0 + 1 < 64) ? tre[c0 + 1][w] : tim[c0 + 1 - 64][w];
    *(unsigned int*)&xnb[tokbase * 128 + (size_t)w * 128 + c0] =
        pk2((v0 - m) * rs * gc0 + bc0, (v1 - m) * rs * gc1 + bc1);
  }
}

// K1b: finalize k1 partials -> momentum / target_energy per (bt,d)
__global__ void k1b_finish(float* ws) {
  int bt = blockIdx.x, d = threadIdx.x; // 16 x 64
  float a = 0.f, b = 0.f, c = 0.f;
  for (int h = 0; h < 64; h++) {
    int idx = h * 1024 + bt * 64 + d;
    a += ws[W_K1R + idx]; b += ws[W_K1I + idx]; c += ws[W_K1E + idx];
  }
  ws[W_MOMRE + bt * 64 + d] = a / 4096.f;
  ws[W_MOMIM + bt * 64 + d] = b / 4096.f;
  ws[W_TE + bt * 64 + d]    = c / 4096.f;
}

// K2b: mom_cat @ mom_w + mom_b -> momentum advection term per (bt,d)
__global__ void k2b_mom(const float* __restrict__ mom_w, const float* __restrict__ mom_b,
                        const float* __restrict__ adv_w, const float* __restrict__ dt, float* ws) {
  int bt = blockIdx.x; int t = bt & 7;
  __shared__ float mc[128], outl[128];
  int tid = threadIdx.x; // 128 threads
  mc[tid] = (tid < 64) ? ws[W_MOMRE + bt * 64 + tid] : ws[W_MOMIM + bt * 64 + tid - 64];
  __syncthreads();
  float acc = mom_b[tid];
  for (int k = 0; k < 128; k++) acc += mc[k] * mom_w[k * 128 + tid];
  outl[tid] = acc;
  __syncthreads();
  if (tid < 64) {
    float f = adv_w[0] * dt[t];
    ws[W_MTRE + bt * 64 + tid] = outl[tid] * f;
    ws[W_MTIM + bt * 64 + tid] = outl[64 + tid] * f;
  }
}

// K0w: bf16 weight prep: MoE w1/w2 fragment order, conv frag-order, enc/dec cat-matrices
__global__ void k0_wprep(const float* __restrict__ w1, const float* __restrict__ w2,
                         const float* __restrict__ cw,
                         const float* __restrict__ enc_re, const float* __restrict__ enc_im,
                         const float* __restrict__ dec_re, const float* __restrict__ dec_im,
                         float* ws) {
  __hip_bfloat16* w1f = (__hip_bfloat16*)(ws + W_W1T);
  __hip_bfloat16* w2f = (__hip_bfloat16*)(ws + W_W2T);
  __hip_bfloat16* cwt = (__hip_bfloat16*)(ws + W_CWT);
  __hip_bfloat16* encM = (__hip_bfloat16*)(ws + W_ENCM);
  __hip_bfloat16* decM = (__hip_bfloat16*)(ws + W_DECM);
  int idx = blockIdx.x * 256 + threadIdx.x; // 0..147455
  if (idx < 131072) {
    // w1f[((e*16+nt)*4+kt)*512 + lane*8 + j] ; cout=nt*16+(lane&15), cin=kt*32+(lane>>4)*8+j
    {
      int j = idx & 7, lane = (idx >> 3) & 63, kt = (idx >> 9) & 3, nt = (idx >> 11) & 15, e = idx >> 15;
      int cout = nt * 16 + (lane & 15);
      int cin = kt * 32 + (lane >> 4) * 8 + j;
      w1f[idx] = __float2bfloat16(w1[((size_t)(e * 128 + cin)) * 256 + cout]);
    }
    // w2f[((e*8+nt)*8+kt)*512 + lane*8 + j] ; cout=nt*16+(lane&15), cin=kt*32+(lane>>4)*8+j
    {
      int j = idx & 7, lane = (idx >> 3) & 63, kt = (idx >> 9) & 7, nt = (idx >> 12) & 7, e = idx >> 15;
      int cout = nt * 16 + (lane & 15);
      int cin = kt * 32 + (lane >> 4) * 8 + j;
      w2f[idx] = __float2bfloat16(w2[((size_t)(e * 256 + cin)) * 128 + cout]);
    }
  }
  if (idx < 147456) {
    int j = idx & 7, lane = (idx >> 3) & 63, kt = (idx >> 9) & 3, r = idx >> 11;
    int nt = r & 7, tap = r >> 3;
    int cout = nt * 16 + (lane & 15);
    int cin = kt * 32 + (lane >> 4) * 8 + j;
    cwt[idx] = __float2bfloat16(cw[((size_t)(tap * 128 + cin)) * 128 + cout]);
  }
  if (idx < 16384) {
    int jj = idx & 7, lane = (idx >> 3) & 63, kt = (idx >> 9) & 3, nt = idx >> 11;
    int jc = nt * 16 + (lane & 15);
    int k = kt * 32 + (lane >> 4) * 8 + jj;
    float ve, vd;
    if (k < 64) {
      ve = (jc < 64) ? enc_re[k * 64 + jc] : enc_im[k * 64 + (jc - 64)];
      vd = (jc < 64) ? dec_re[k * 64 + jc] : dec_im[k * 64 + (jc - 64)];
    } else {
      int kk = k - 64;
      ve = (jc < 64) ? -enc_im[kk * 64 + jc] : enc_re[kk * 64 + (jc - 64)];
      vd = (jc < 64) ? -dec_im[kk * 64 + jc] : dec_re[kk * 64 + (jc - 64)];
    }
    encM[idx] = __float2bfloat16(ve);
    decM[idx] = __float2bfloat16(vd);
  }
}

// K3: 3x3 SAME conv via bf16 MFMA; xcl += conv_y + conv_b + mom_term
__global__ __launch_bounds__(256) void k3_conv(const float* __restrict__ cb, float* ws) {
  int blk = blockIdx.x; int bt = blk >> 6, h = blk & 63;
  const __hip_bfloat16* xnb = (const __hip_bfloat16*)(ws + W_C);
  const __hip_bfloat16* cwt = (const __hip_bfloat16*)(ws + W_CWT);
  __shared__ __align__(16) __hip_bfloat16 xin[3][66][136];
  int tid = threadIdx.x, lane = tid & 63, wv = tid >> 6;
  int arow = lane & 15, kgrp = (lane >> 4) * 8, rbase = (lane >> 4) * 4;

  for (int r = 0; r < 3; r++) {
    int hh = h + r - 1;
    if (hh < 0 || hh >= 64) {
      unsigned int* z = (unsigned int*)&xin[r][0][0];
      for (int i = tid; i < 4488; i += 256) z[i] = 0u;
    } else {
      if (tid < 68) *(unsigned int*)&xin[r][0][tid * 2] = 0u;
      else if (tid < 136) *(unsigned int*)&xin[r][65][(tid - 136 + 68) * 2] = 0u;
      const __hip_bfloat16* src = xnb + ((size_t)bt * 4096 + (size_t)hh * 64) * 128;
      for (int i = tid; i < 1024; i += 256) {
        int wp = (i >> 4) + 1, c8 = (i & 15) * 8;
        *(bf16x8*)&xin[r][wp][c8] = *(const bf16x8*)&src[(size_t)(wp - 1) * 128 + c8];
      }
    }
  }
  __syncthreads();

  f32x4 oacc[4][2];
  #pragma unroll
  for (int m = 0; m < 4; m++) {
    oacc[m][0] = (f32x4){0.f, 0.f, 0.f, 0.f};
    oacc[m][1] = (f32x4){0.f, 0.f, 0.f, 0.f};
  }

  for (int tap = 0; tap < 9; tap++) {
    int kh = tap / 3, kw = tap % 3;
    const __hip_bfloat16* wt0 = cwt + ((size_t)(tap * 8 + wv * 2) * 4) * 512 + lane * 8;
    #pragma unroll
    for (int kt = 0; kt < 4; kt++) {
      bf16x8 a[4];
      #pragma unroll
      for (int m = 0; m < 4; m++)
        a[m] = *(const bf16x8*)&xin[kh][m * 16 + arow + kw][kt * 32 + kgrp];
      bf16x8 b0 = *(const bf16x8*)&wt0[(size_t)kt * 512];
      bf16x8 b1 = *(const bf16x8*)&wt0[(size_t)(kt + 4) * 512];
      #pragma unroll
      for (int m = 0; m < 4; m++) {
        oacc[m][0] = __builtin_amdgcn_mfma_f32_16x16x32_bf16(a[m], b0, oacc[m][0], 0, 0, 0);
        oacc[m][1] = __builtin_amdgcn_mfma_f32_16x16x32_bf16(a[m], b1, oacc[m][1], 0, 0, 0);
      }
    }
  }

  size_t rowtok = (size_t)blk * 64;
  #pragma unroll
  for (int n = 0; n < 2; n++) {
    int cout = (wv * 2 + n) * 16 + arow;
    bool isre = cout < 64;
    int d = cout & 63;
    float add = cb[cout] + ws[(isre ? W_MTRE : W_MTIM) + bt * 64 + d];
    float* xcl = ws + (isre ? W_XCL_RE : W_XCL_IM);
    #pragma unroll
    for (int m = 0; m < 4; m++)
      #pragma unroll
      for (int r = 0; r < 4; r++) {
        int w = m * 16 + rbase + r;
        xcl[(rowtok + w) * 64 + d] += oacc[m][n][r] + add;
      }
  }
}

// K_CGEMM: complex 64x64 matmul as 64x128x128 bf16 MFMA GEMM with fused spatial partials.
// mode 1: partial = sum(C) (x_mean); mode 2: partial = sum(C^2) (|x_out|^2)
__global__ __launch_bounds__(256) void k_cgemm(float* ws, long moff,
                                               long ire, long iim, long ore, long oim,
                                               long pre, long pim, int mode) {
  int blk = blockIdx.x;
  const __hip_bfloat16* M = (const __hip_bfloat16*)(ws + moff);
  __shared__ __align__(16) char A[16384]; // bf16 [64 rows][256B] XOR-swizzled
  int tid = threadIdx.x, lane = tid & 63, wv = tid >> 6;
  int arow = lane & 15, kgrp = (lane >> 4) * 8, rbase = (lane >> 4) * 4;
  size_t tokbase = (size_t)blk * 64;
  const float* pr_ = ws + ire;
  const float* pi_ = ws + iim;
  for (int i = tid; i < 2048; i += 256) {
    int w = i >> 5, dp = (i & 31) * 2;
    float2 vr = *(const float2*)&pr_[(tokbase + w) * 64 + dp];
    float2 vi = *(const float2*)&pi_[(tokbase + w) * 64 + dp];
    int sz = (w & 7) << 4;
    *(unsigned int*)(A + w * 256 + ((dp * 2) ^ sz)) = pk2(vr.x, vr.y);
    *(unsigned int*)(A + w * 256 + (((64 + dp) * 2) ^ sz)) = pk2(vi.x, vi.y);
  }
  __syncthreads();
  f32x4 acc[4][2];
  #pragma unroll
  for (int m = 0; m < 4; m++) {
    acc[m][0] = (f32x4){0.f, 0.f, 0.f, 0.f};
    acc[m][1] = (f32x4){0.f, 0.f, 0.f, 0.f};
  }
  #pragma unroll
  for (int kt = 0; kt < 4; kt++) {
    bf16x8 a[4];
    #pragma unroll
    for (int m = 0; m < 4; m++)
      a[m] = *(const bf16x8*)(A + (m * 16 + arow) * 256 + (((kt * 32 + kgrp) * 2) ^ ((arow & 7) << 4)));
    bf16x8 b0 = *(const bf16x8*)&M[(((size_t)(wv * 2 + 0) * 4 + kt) * 64 + lane) * 8];
    bf16x8 b1 = *(const bf16x8*)&M[(((size_t)(wv * 2 + 1) * 4 + kt) * 64 + lane) * 8];
    #pragma unroll
    for (int m = 0; m < 4; m++) {
      acc[m][0] = __builtin_amdgcn_mfma_f32_16x16x32_bf16(a[m], b0, acc[m][0], 0, 0, 0);
      acc[m][1] = __builtin_amdgcn_mfma_f32_16x16x32_bf16(a[m], b1, acc[m][1], 0, 0, 0);
    }
  }
  float* orp = ws + ore;
  float* oip = ws + oim;
  #pragma unroll
  for (int n = 0; n < 2; n++) {
    int jc = (wv * 2 + n) * 16 + arow;
    float* dst = (jc < 64) ? orp : oip;
    int col = jc & 63;
    #pragma unroll
    for (int m = 0; m < 4; m++)
      #pragma unroll
      for (int r = 0; r < 4; r++)
        dst[(tokbase + m * 16 + rbase + r) * 64 + col] = acc[m][n][r];
    // fused spatial partial over this block's 64 tokens
    float s = 0.f;
    if (mode == 1) {
      #pragma unroll
      for (int m = 0; m < 4; m++)
        #pragma unroll
        for (int r = 0; r < 4; r++) s += acc[m][n][r];
    } else {
      #pragma unroll
      for (int m = 0; m < 4; m++)
        #pragma unroll
        for (int r = 0; r < 4; r++) s += acc[m][n][r] * acc[m][n][r];
    }
    s += __shfl_xor(s, 16);
    s += __shfl_xor(s, 32);
    if (lane < 16)
      ws[(jc < 64 ? pre : pim) + (size_t)blk * 64 + (jc & 63)] = s;
  }
}

__device__ __forceinline__ float softplusf(float x) {
  return (x > 20.f) ? x : log1pf(expf(x));
}

// K6: X_flux, flux scan, source, gate, op_decay/op_forcing — tiny (B,T,D) work
__global__ void k6_seq(const float* __restrict__ fin_re, const float* __restrict__ fin_im,
                       const float* __restrict__ fproj_re, const float* __restrict__ fproj_im,
                       const float* __restrict__ flux_a_re, const float* __restrict__ flux_a_im,
                       const float* __restrict__ gate_w, const float* __restrict__ gate_b,
                       const float* __restrict__ lam_re, const float* __restrict__ lam_im,
                       const float* __restrict__ dt, float* ws) {
  __shared__ float xmr[1024], xmi[1024], Xfr[1024], Xfi[1024], flr[1024], fli[1024];
  int tid = threadIdx.x;
  for (int i = tid; i < 1024; i += 256) {
    int bt = i >> 6, j = i & 63;
    float sr = 0.f, si = 0.f;
    for (int q = 0; q < 64; q++) {
      sr += ws[W_XMP_RE + (size_t)(bt * 64 + q) * 64 + j];
      si += ws[W_XMP_IM + (size_t)(bt * 64 + q) * 64 + j];
    }
    xmr[i] = sr / 4096.f; xmi[i] = si / 4096.f;
  }
  __syncthreads();
  for (int i = tid; i < 1024; i += 256) {
    int bt = i >> 6, j = i & 63;
    float ar = 0.f, ai = 0.f;
    for (int d = 0; d < 64; d++) {
      float xr = xmr[bt * 64 + d], xi = xmi[bt * 64 + d];
      float wr = fin_re[d * 64 + j], wi = fin_im[d * 64 + j];
      ar += xr * wr - xi * wi; ai += xr * wi + xi * wr;
    }
    Xfr[i] = ar; Xfi[i] = ai;
  }
  __syncthreads();
  if (tid < 128) {
    int b = tid >> 6, j = tid & 63;
    float mag = expf(-softplusf(flux_a_re[j]));
    float aar = mag * cosf(flux_a_im[j]), aai = mag * sinf(flux_a_im[j]);
    float sr = 0.f, si = 0.f;
    for (int t = 0; t < 8; t++) {
      int idx = (b * 8 + t) * 64 + j;
      float nr = aar * sr - aai * si + Xfr[idx];
      float ni = aar * si + aai * sr + Xfi[idx];
      sr = nr; si = ni;
      flr[idx] = sr; fli[idx] = si;
    }
  }
  __syncthreads();
  for (int i = tid; i < 1024; i += 256) {
    int bt = i >> 6, j = i & 63;
    float ar = 0.f, ai = 0.f, lg = 0.f;
    for (int d = 0; d < 64; d++) {
      float fr = flr[bt * 64 + d], fi = fli[bt * 64 + d];
      float wr = fproj_re[d * 64 + j], wi = fproj_im[d * 64 + j];
      ar += fr * wr - fi * wi; ai += fr * wi + fi * wr;
      lg += fr * gate_w[d * 64 + j] + fi * gate_w[(64 + d) * 64 + j];
    }
    ws[W_SRCRE + i] = ar; ws[W_SRCIM + i] = ai;
    ws[W_GATE + i] = 1.f / (1.f + expf(-(lg + gate_b[j])));
  }
  for (int i = tid; i < 1024; i += 256) {
    int bt = i >> 6, d = i & 63, t = bt & 7;
    float lr = -softplusf(lam_re[d]), li = lam_im[d];
    float dtv = dt[t];
    float mag = expf(lr * dtv);
    float dr = mag * cosf(li * dtv), di = mag * sinf(li * dtv);
    ws[W_OPDRE + i] = dr; ws[W_OPDIM + i] = di;
    float omr = dr - 1.f, omi = di;
    float den = lr * lr + li * li;
    ws[W_OPFRE + i] = (omr * lr + omi * li) / den;
    ws[W_OPFIM + i] = (omi * lr - omr * li) / den;
  }
}

// K7: forcing -> u_t -> time scan (T=8) -> + noise, in place over eig buffer
__global__ __launch_bounds__(256) void k7_scan(const float* __restrict__ nre,
                                               const float* __restrict__ nim,
                                               const float* __restrict__ dt, float* ws) {
  int blk = blockIdx.x; int b = blk >> 6, h = blk & 63;
  __shared__ float gl[8][64], srl[8][64], sil[8][64], ofr[8][64], ofi[8][64], odr[8][64], odi[8][64];
  int tid = threadIdx.x;
  for (int i = tid; i < 512; i += 256) {
    int t = i >> 6, d = i & 63, idx = (b * 8 + t) * 64 + d;
    gl[t][d]  = ws[W_GATE + idx];
    srl[t][d] = ws[W_SRCRE + idx]; sil[t][d] = ws[W_SRCIM + idx];
    ofr[t][d] = ws[W_OPFRE + idx]; ofi[t][d] = ws[W_OPFIM + idx];
    odr[t][d] = ws[W_OPDRE + idx]; odi[t][d] = ws[W_OPDIM + idx];
  }
  __syncthreads();
  float ur[16], ui[16];
  #pragma unroll
  for (int k = 0; k < 16; k++) { ur[k] = 0.f; ui[k] = 0.f; }
  for (int t = 0; t < 8; t++) {
    float ns = 0.01f * sqrtf(dt[t]);
    size_t tokbase = ((size_t)(b * 8 + t) * 64 + h) * 64;
    for (int k = 0; k < 16; k++) {
      int idx = tid + 256 * k;
      int w = idx >> 6, d = idx & 63;
      size_t off = (tokbase + w) * 64 + d;
      float er_ = ws[W_EIG_RE + off], ei_ = ws[W_EIG_IM + off];
      float gg = gl[t][d];
      float fre = er_ * gg + srl[t][d] * (1.f - gg);
      float fim = ei_ * gg + sil[t][d] * (1.f - gg);
      float utr = fre * ofr[t][d] - fim * ofi[t][d];
      float uti = fre * ofi[t][d] + fim * ofr[t][d];
      float nur = odr[t][d] * ur[k] - odi[t][d] * ui[k] + utr;
      float nui = odr[t][d] * ui[k] + odi[t][d] * ur[k] + uti;
      ur[k] = nur; ui[k] = nui;
      ws[W_EIG_RE + off] = nur + ns * nre[off];
      ws[W_EIG_IM + off] = nui + ns * nim[off];
    }
  }
}

// K9b: combine |x_out|^2 partials -> energy rescale factor per (bt,d)
__global__ void k9b_scale(const float* __restrict__ escale, float* ws) {
  int bt = blockIdx.x; int j = threadIdx.x; // 16 x 64
  float s = 0.f;
  for (int q = 0; q < 64; q++) {
    size_t idx = (size_t)(bt * 64 + q) * 64 + j;
    s += ws[W_EP_RE + idx] + ws[W_EP_IM + idx];
  }
  float cur = s / 4096.f;
  float te = ws[W_TE + bt * 64 + j];
  float ratio = te / (cur + 1e-8f);
  ratio = fminf(fmaxf(ratio, 0.5f), 2.0f);
  ws[W_SCALE + bt * 64 + j] = 1.f + escale[0] * (sqrtf(ratio) - 1.f);
}

// K11 v2: reg-staged scale+LN -> bf16 ltok -> router -> MFMA MoE (L1 split in halves,
// fragment-order weight bursts) -> residuals -> transposed output.
__global__ __launch_bounds__(256) void k11_moe(
    const float* __restrict__ rw, const float* __restrict__ rb,
    const float* __restrict__ b1, const float* __restrict__ b2,
    const float* __restrict__ g2, const float* __restrict__ b2_,
    float* __restrict__ ws, float* __restrict__ out) {
  int blk = blockIdx.x; int bt = blk >> 6, h = blk & 63;
  const __hip_bfloat16* w1f = (const __hip_bfloat16*)(ws + W_W1T);
  const __hip_bfloat16* w2f = (const __hip_bfloat16*)(ws + W_W2T);
  __shared__ __align__(16) char bufA[33024]; // hbuf bf16 64 rows x 512B | obuf f32[64][129]
  __shared__ __align__(16) char lt[16384];   // ltok bf16 64 rows x 256B, XOR-swizzled
  __shared__ float pl[64][4];
  __shared__ float sc[64];
  __shared__ float ps[4][64], pq[4][64], mean_l[64], rstd_l[64];
  char* hb = bufA;
  float (*obuf)[129] = (float(*)[129])bufA;
  int tid = threadIdx.x, lane = tid & 63, wv = tid >> 6;
  int arow = lane & 15, kgrp = (lane >> 4) * 8, rbase = (lane >> 4) * 4;
  size_t tokbase = (size_t)blk * 64;

  if (tid < 64) sc[tid] = ws[W_SCALE + bt * 64 + tid];
  __syncthreads();

  // phase 1: reg-staged scale + LN stats (thread = (row w, quarter part))
  int w = tid >> 2, part = tid & 3;
  int c0 = part * 32, dbase = (part & 1) * 32;
  const float* rowp = ws + ((part < 2) ? W_EIG_RE : W_EIG_IM) + (tokbase + w) * 64 + dbase;
  float4 vv[8];
  {
    float s = 0.f, sq = 0.f;
    #pragma unroll
    for (int q = 0; q < 8; q++) {
      float4 t4 = *(const float4*)&rowp[q * 4];
      t4.x *= sc[dbase + q * 4 + 0];
      t4.y *= sc[dbase + q * 4 + 1];
      t4.z *= sc[dbase + q * 4 + 2];
      t4.w *= sc[dbase + q * 4 + 3];
      vv[q] = t4;
      s  += t4.x + t4.y + t4.z + t4.w;
      sq += t4.x * t4.x + t4.y * t4.y + t4.z * t4.z + t4.w * t4.w;
    }
    ps[part][w] = s; pq[part][w] = sq;
  }
  __syncthreads();
  if (tid < 64) {
    float s  = ps[0][tid] + ps[1][tid] + ps[2][tid] + ps[3][tid];
    float sq = pq[0][tid] + pq[1][tid] + pq[2][tid] + pq[3][tid];
    float m = s / 128.f, v = sq / 128.f - m * m;
    mean_l[tid] = m; rstd_l[tid] = rsqrtf(v + 1e-5f);
  }
  __syncthreads();
  // normalize in regs -> bf16 ltok (swizzled)
  {
    float m = mean_l[w], rs = rstd_l[w];
    int szw = (w & 7) << 4;
    #pragma unroll
    for (int q = 0; q < 8; q++) {
      int c = c0 + q * 4;
      float a0 = (vv[q].x - m) * rs * g2[c]     + b2_[c];
      float a1 = (vv[q].y - m) * rs * g2[c + 1] + b2_[c + 1];
      float a2 = (vv[q].z - m) * rs * g2[c + 2] + b2_[c + 2];
      float a3 = (vv[q].w - m) * rs * g2[c + 3] + b2_[c + 3];
      *(unsigned int*)(lt + w * 256 + ((c * 2) ^ szw)) = pk2(a0, a1);
      *(unsigned int*)(lt + w * 256 + (((c + 2) * 2) ^ szw)) = pk2(a2, a3);
    }
  }
  __syncthreads();
  // router logits from ltok
  {
    int l = tid >> 2, e = tid & 3;
    float acc = rb[e];
    const float* rwe = rw + e;
    int sz = (l & 7) << 4;
    for (int dd = 0; dd < 128; dd += 2) {
      unsigned int u = *(const unsigned int*)(lt + l * 256 + ((dd * 2) ^ sz));
      float x0 = __uint_as_float(u << 16);
      float x1 = __uint_as_float(u & 0xffff0000u);
      acc += x0 * rwe[dd * 4] + x1 * rwe[dd * 4 + 4];
    }
    pl[l][e] = acc;
  }
  __syncthreads();
  if (tid < 64) {
    float m = fmaxf(fmaxf(pl[tid][0], pl[tid][1]), fmaxf(pl[tid][2], pl[tid][3]));
    float e0 = expf(pl[tid][0] - m), e1 = expf(pl[tid][1] - m);
    float e2 = expf(pl[tid][2] - m), e3 = expf(pl[tid][3] - m);
    float s = e0 + e1 + e2 + e3;
    pl[tid][0] = e0 / s; pl[tid][1] = e1 / s; pl[tid][2] = e2 / s; pl[tid][3] = e3 / s;
  }

  // out accumulator init = tok residual (from ltok)
  f32x4 oacc[4][2];
  #pragma unroll
  for (int m = 0; m < 4; m++)
    #pragma unroll
    for (int n2 = 0; n2 < 2; n2++) {
      int col = (wv * 2 + n2) * 16 + arow;
      #pragma unroll
      for (int r = 0; r < 4; r++) {
        int row = m * 16 + rbase + r;
        oacc[m][n2][r] = __bfloat162float(
            *(const __hip_bfloat16*)(lt + row * 256 + ((col * 2) ^ ((row & 7) << 4))));
      }
    }
  __syncthreads();

  for (int e = 0; e < 4; e++) {
    // layer1 in two n-halves (acc1[4][2], coalesced 1KB weight bursts)
    #pragma unroll
    for (int hf = 0; hf < 2; hf++) {
      f32x4 acc1[4][2];
      #pragma unroll
      for (int m = 0; m < 4; m++) {
        acc1[m][0] = (f32x4){0.f, 0.f, 0.f, 0.f};
        acc1[m][1] = (f32x4){0.f, 0.f, 0.f, 0.f};
      }
      #pragma unroll
      for (int kt = 0; kt < 4; kt++) {
        bf16x8 a[4];
        #pragma unroll
        for (int m = 0; m < 4; m++) {
          int row = m * 16 + arow;
          a[m] = *(const bf16x8*)(lt + row * 256 + (((kt * 32 + kgrp) * 2) ^ ((arow & 7) << 4)));
        }
        bf16x8 b0 = *(const bf16x8*)&w1f[(((size_t)(e * 16 + wv * 4 + hf * 2 + 0) * 4 + kt) * 64 + lane) * 8];
        bf16x8 b1 = *(const bf16x8*)&w1f[(((size_t)(e * 16 + wv * 4 + hf * 2 + 1) * 4 + kt) * 64 + lane) * 8];
        #pragma unroll
        for (int m = 0; m < 4; m++) {
          acc1[m][0] = __builtin_amdgcn_mfma_f32_16x16x32_bf16(a[m], b0, acc1[m][0], 0, 0, 0);
          acc1[m][1] = __builtin_amdgcn_mfma_f32_16x16x32_bf16(a[m], b1, acc1[m][1], 0, 0, 0);
        }
      }
      if (hf == 0) __syncthreads(); // hbuf guard: prev expert's L2 reads done
      #pragma unroll
      for (int n = 0; n < 2; n++) {
        int col = (wv * 4 + hf * 2 + n) * 16 + arow;
        float bv = b1[e * 256 + col];
        #pragma unroll
        for (int m = 0; m < 4; m++)
          #pragma unroll
          for (int r = 0; r < 4; r++) {
            float hv = acc1[m][n][r] + bv;
            float z = 1.5957691216f * hv + 0.0713548162f * hv * hv * hv;
            float gelu = hv / (1.f + __expf(-z));
            int row = m * 16 + rbase + r;
            *(__hip_bfloat16*)(hb + row * 512 + ((col * 2) ^ ((row & 7) << 4))) =
                __float2bfloat16(gelu);
          }
      }
    }
    __syncthreads();
    // layer2: eout = h @ w2[e]
    f32x4 acc2[4][2];
    #pragma unroll
    for (int m = 0; m < 4; m++) {
      acc2[m][0] = (f32x4){0.f, 0.f, 0.f, 0.f};
      acc2[m][1] = (f32x4){0.f, 0.f, 0.f, 0.f};
    }
    #pragma unroll
    for (int kt = 0; kt < 8; kt++) {
      bf16x8 a2[4];
      #pragma unroll
      for (int m = 0; m < 4; m++) {
        int row = m * 16 + arow;
        a2[m] = *(const bf16x8*)(hb + row * 512 + (((kt * 32 + kgrp) * 2) ^ ((arow & 7) << 4)));
      }
      bf16x8 bb0 = *(const bf16x8*)&w2f[(((size_t)(e * 8 + wv * 2 + 0) * 8 + kt) * 64 + lane) * 8];
      bf16x8 bb1 = *(const bf16x8*)&w2f[(((size_t)(e * 8 + wv * 2 + 1) * 8 + kt) * 64 + lane) * 8];
      #pragma unroll
      for (int m = 0; m < 4; m++) {
        acc2[m][0] = __builtin_amdgcn_mfma_f32_16x16x32_bf16(a2[m], bb0, acc2[m][0], 0, 0, 0);
        acc2[m][1] = __builtin_amdgcn_mfma_f32_16x16x32_bf16(a2[m], bb1, acc2[m][1], 0, 0, 0);
      }
    }
    #pragma unroll
    for (int n = 0; n < 2; n++) {
      int col = (wv * 2 + n) * 16 + arow;
      float bv2 = b2[e * 128 + col];
      #pragma unroll
      for (int m = 0; m < 4; m++)
        #pragma unroll
        for (int r = 0; r < 4; r++)
          oacc[m][n][r] += pl[m * 16 + rbase + r][e] * (acc2[m][n][r] + bv2);
    }
  }

  __syncthreads(); // last L2 hbuf reads done -> obuf
  #pragma unroll
  for (int m = 0; m < 4; m++)
    #pragma unroll
    for (int n2 = 0; n2 < 2; n2++) {
      int col = (wv * 2 + n2) * 16 + arow;
      #pragma unroll
      for (int r = 0; r < 4; r++)
        obuf[m * 16 + rbase + r][col] = oacc[m][n2][r];
    }
  __syncthreads();

  // residual add (coalesced reads)
  {
    const float* xre = ws + W_XCL_RE;
    const float* xim = ws + W_XCL_IM;
    for (int i = tid; i < 8192; i += 256) {
      int wt = i >> 7, c = i & 127, dd = c & 63;
      float val = ((c < 64) ? xre : xim)[(tokbase + wt) * 64 + dd];
      obuf[wt][c] += val;
    }
  }
  __syncthreads();
  // transpose out to (2,B,T,D,H,W)
  for (int i = tid; i < 8192; i += 256) {
    int d2 = i >> 6, wt = i & 63;
    out[(size_t)(d2 >> 6) * 4194304 + (size_t)bt * 262144 + (size_t)(d2 & 63) * 4096
        + (size_t)h * 64 + wt] = obuf[wt][d2];
  }
}

extern "C" void kernel_launch(void* const* d_in, const int* in_sizes, int n_in,
                              void* d_out, int out_size, void* d_ws, size_t ws_size,
                              hipStream_t stream) {
  const float* x_re      = (const float*)d_in[0];
  const float* x_im      = (const float*)d_in[1];
  const float* dt        = (const float*)d_in[2];
  const float* ln_s_g    = (const float*)d_in[3];
  const float* ln_s_b    = (const float*)d_in[4];
  const float* conv_w    = (const float*)d_in[5];
  const float* conv_b    = (const float*)d_in[6];
  const float* mom_w     = (const float*)d_in[7];
  const float* mom_b     = (const float*)d_in[8];
  const float* adv_w     = (const float*)d_in[9];
  const float* enc_re    = (const float*)d_in[10];
  const float* enc_im    = (const float*)d_in[11];
  const float* dec_re    = (const float*)d_in[12];
  const float* dec_im    = (const float*)d_in[13];
  const float* flux_a_re = (const float*)d_in[14];
  const float* flux_a_im = (const float*)d_in[15];
  const float* fin_re    = (const float*)d_in[16];
  const float* fin_im    = (const float*)d_in[17];
  const float* fproj_re  = (const float*)d_in[18];
  const float* fproj_im  = (const float*)d_in[19];
  const float* gate_w    = (const float*)d_in[20];
  const float* gate_b    = (const float*)d_in[21];
  const float* lam_re    = (const float*)d_in[22];
  const float* lam_im    = (const float*)d_in[23];
  const float* noise_re  = (const float*)d_in[24];
  const float* noise_im  = (const float*)d_in[25];
  const float* e_scale   = (const float*)d_in[26];
  const float* ln_t_g    = (const float*)d_in[27];
  const float* ln_t_b    = (const float*)d_in[28];
  const float* router_w  = (const float*)d_in[29];
  const float* router_b  = (const float*)d_in[30];
  const float* w1        = (const float*)d_in[31];
  const float* b1        = (const float*)d_in[32];
  const float* w2        = (const float*)d_in[33];
  const float* b2        = (const float*)d_in[34];
  float* ws  = (float*)d_ws;
  float* out = (float*)d_out;

  k0_wprep<<<576, 256, 0, stream>>>(w1, w2, conv_w, enc_re, enc_im, dec_re, dec_im, ws);
  k2_transpose_ln<<<1024, 256, 0, stream>>>(x_re, x_im, ln_s_g, ln_s_b, ws);
  k1b_finish<<<16, 64, 0, stream>>>(ws);
  k2b_mom<<<16, 128, 0, stream>>>(mom_w, mom_b, adv_w, dt, ws);
  k3_conv<<<1024, 256, 0, stream>>>(conv_b, ws);
  k_cgemm<<<1024, 256, 0, stream>>>(ws, (long)W_ENCM,
      (long)W_XCL_RE, (long)W_XCL_IM, (long)W_EIG_RE, (long)W_EIG_IM,
      (long)W_XMP_RE, (long)W_XMP_IM, 1);
  k6_seq<<<1, 256, 0, stream>>>(fin_re, fin_im, fproj_re, fproj_im, flux_a_re, flux_a_im,
                                gate_w, gate_b, lam_re, lam_im, dt, ws);
  k7_scan<<<128, 256, 0, stream>>>(noise_re, noise_im, dt, ws);
  k_cgemm<<<1024, 256, 0, stream>>>(ws, (long)W_DECM,
      (long)W_EIG_RE, (long)W_EIG_IM, (long)W_EIG_RE, (long)W_EIG_IM,
      (long)W_EP_RE, (long)W_EP_IM, 2);
  k9b_scale<<<16, 64, 0, stream>>>(e_scale, ws);
  k11_moe<<<1024, 256, 0, stream>>>(router_w, router_b, b1, b2, ln_t_g, ln_t_b, ws, out);
}

// Round 8
// 278.622 us; speedup vs baseline: 6.8055x; 1.2188x over previous
//
#include <hip/hip_runtime.h>
#include <hip/hip_bf16.h>
#include <math.h>

// Problem constants: B=2,T=8,D=64,H=64,W=64,D2=128,E=4,HID=256
// token index = ((bt)*64 + h)*64 + w ; bt = b*8+t ; NTOK = 65536

// -------- workspace layout (float offsets) --------
#define W_XCL_RE 0u
#define W_XCL_IM 4194304u
#define W_C      8388608u     // xn BF16 [tok][128]; LIVE through k3_conv_enc (fused GEMM!)
#define W_CWT    12582912u    // bf16 conv weights, fragment order [9][8][4][64][8] -> [12582912,12656640)
#define W_W1T    14680064u    // bf16 w1 FRAGMENT order [4][16 nt][4 kt][64][8] -> [14680064,14745600)
#define W_W2T    14745600u    // bf16 w2 FRAGMENT order [4][8 nt][8 kt][64][8] -> [14745600,14811136)
#define W_ENCM   14811136u    // bf16 enc cat-matrix frag order, 16384 elems = 8192 floats
#define W_DECM   14819328u    // bf16 dec cat-matrix frag order -> ends 14827520
// partials moved OUT of xn space (xn live during fused k3):
#define W_XMP_RE 14827520u    // x_mean partials [1024 blk][64]
#define W_XMP_IM 14893056u
#define W_EP_RE  14958592u    // |x_out|^2 partials [4096 blk][64] (k7_dec, 512 blocks x 8 t)
#define W_EP_IM  15220736u    // ends 15482880 < W_EIG_RE
#define W_EIG_RE 16777216u    // x_eigen -> x_out (in place)
#define W_EIG_IM 20971520u
// k1 partials live in dead eig space (consumed by k1b BEFORE k3 writes eig); each 65536 floats
#define W_K1R    16777216u
#define W_K1I    16842752u
#define W_K1E    16908288u
#define W_SMALL  25165824u
#define W_TE     (W_SMALL+0u)
#define W_MOMRE  (W_SMALL+1024u)
#define W_MOMIM  (W_SMALL+2048u)
#define W_MTRE   (W_SMALL+3072u)
#define W_MTIM   (W_SMALL+4096u)
#define W_GATE   (W_SMALL+5120u)
#define W_SRCRE  (W_SMALL+6144u)
#define W_SRCIM  (W_SMALL+7168u)
#define W_OPFRE  (W_SMALL+8192u)
#define W_OPFIM  (W_SMALL+9216u)
#define W_OPDRE  (W_SMALL+10240u)
#define W_OPDIM  (W_SMALL+11264u)
#define W_SCALE  (W_SMALL+12288u)

typedef __attribute__((ext_vector_type(8))) short bf16x8;
typedef __attribute__((ext_vector_type(4))) float f32x4;

__device__ __forceinline__ unsigned short bfr(float x) {
  __hip_bfloat16 h = __float2bfloat16(x);
  return *(unsigned short*)&h;
}
__device__ __forceinline__ unsigned int pk2(float a, float b) {
  return ((unsigned int)bfr(b) << 16) | (unsigned int)bfr(a);
}

// K2: transpose (B,T,D,H,W)->(token,d) xcl; layernorm -> xn bf16; k1 partial reductions
__global__ __launch_bounds__(256) void k2_transpose_ln(
    const float* __restrict__ xre, const float* __restrict__ xim,
    const float* __restrict__ g, const float* __restrict__ bb_, float* ws) {
  int blk = blockIdx.x; int bt = blk >> 6, h = blk & 63;
  __shared__ float tre[64][65], tim[64][65];
  __shared__ float ps[4][64], pq[4][64], pe[4][64];
  __shared__ float mean_l[64], rstd_l[64];
  size_t inbase = (size_t)bt * 262144 + (size_t)h * 64; // + d*4096 + w
  for (int i = threadIdx.x; i < 1024; i += 256) {
    int d = i >> 4, w4 = (i & 15) * 4;
    float4 vr = *(const float4*)&xre[inbase + (size_t)d * 4096 + w4];
    float4 vi = *(const float4*)&xim[inbase + (size_t)d * 4096 + w4];
    tre[d][w4] = vr.x; tre[d][w4 + 1] = vr.y; tre[d][w4 + 2] = vr.z; tre[d][w4 + 3] = vr.w;
    tim[d][w4] = vi.x; tim[d][w4 + 1] = vi.y; tim[d][w4 + 2] = vi.z; tim[d][w4 + 3] = vi.w;
  }
  __syncthreads();
  {
    int w = threadIdx.x & 63, part = threadIdx.x >> 6;
    float s = 0.f, sq = 0.f;
    for (int dd = part * 16; dd < part * 16 + 16; dd++) {
      float vr = tre[dd][w], vi = tim[dd][w];
      s += vr + vi; sq += vr * vr + vi * vi;
    }
    ps[part][w] = s; pq[part][w] = sq;
  }
  __syncthreads();
  if (threadIdx.x < 64) {
    int w = threadIdx.x;
    float s  = ps[0][w] + ps[1][w] + ps[2][w] + ps[3][w];
    float sq = pq[0][w] + pq[1][w] + pq[2][w] + pq[3][w];
    float m = s / 128.f;
    float v = sq / 128.f - m * m;
    mean_l[w] = m; rstd_l[w] = rsqrtf(v + 1e-5f);
  }
  __syncthreads();
  // k1 partials: per d, sum over this block's w of re, im, |.|^2  (reuses ps/pq)
  {
    int d = threadIdx.x & 63, part = threadIdx.x >> 6;
    float sr = 0.f, si = 0.f, se = 0.f;
    for (int w = part * 16; w < part * 16 + 16; w++) {
      float vr = tre[d][w], vi = tim[d][w];
      sr += vr; si += vi; se += vr * vr + vi * vi;
    }
    ps[part][d] = sr; pq[part][d] = si; pe[part][d] = se;
  }
  __syncthreads();
  if (threadIdx.x < 64) {
    int d = threadIdx.x;
    int idx = h * 1024 + bt * 64 + d;
    ws[W_K1R + idx] = ps[0][d] + ps[1][d] + ps[2][d] + ps[3][d];
    ws[W_K1I + idx] = pq[0][d] + pq[1][d] + pq[2][d] + pq[3][d];
    ws[W_K1E + idx] = pe[0][d] + pe[1][d] + pe[2][d] + pe[3][d];
  }
  size_t tokbase = (size_t)blk * 64;
  for (int i = threadIdx.x; i < 1024; i += 256) {
    int w = i >> 4, d4 = (i & 15) * 4;
    float4 o, p;
    o.x = tre[d4][w]; o.y = tre[d4 + 1][w]; o.z = tre[d4 + 2][w]; o.w = tre[d4 + 3][w];
    p.x = tim[d4][w]; p.y = tim[d4 + 1][w]; p.z = tim[d4 + 2][w]; p.w = tim[d4 + 3][w];
    *(float4*)&ws[W_XCL_RE + tokbase * 64 + (size_t)w * 64 + d4] = o;
    *(float4*)&ws[W_XCL_IM + tokbase * 64 + (size_t)w * 64 + d4] = p;
  }
  // LN -> bf16 xn, packed u32 stores (2 channels/thread)
  __hip_bfloat16* xnb = (__hip_bfloat16*)(ws + W_C);
  int c0 = (threadIdx.x & 63) * 2, wg = threadIdx.x >> 6;
  float gc0 = g[c0], bc0 = bb_[c0], gc1 = g[c0 + 1], bc1 = bb_[c0 + 1];
  for (int pass = 0; pass < 16; pass++) {
    int w = pass * 4 + wg;
    float m = mean_l[w], rs = rstd_l[w];
    float v0 = (c0 < 64) ? tre[c0][w] : tim[c0 - 64][w];
    float v1 = (c0 + 1 < 64) ? tre[c0 + 1][w] : tim[c0 + 1 - 64][w];
    *(unsigned int*)&xnb[tokbase * 128 + (size_t)w * 128 + c0] =
        pk2((v0 - m) * rs * gc0 + bc0, (v1 - m) * rs * gc1 + bc1);
  }
}

// K1b: finalize k1 partials -> momentum / target_energy per (bt,d)
__global__ void k1b_finish(float* ws) {
  int bt = blockIdx.x, d = threadIdx.x; // 16 x 64
  float a = 0.f, b = 0.f, c = 0.f;
  for (int h = 0; h < 64; h++) {
    int idx = h * 1024 + bt * 64 + d;
    a += ws[W_K1R + idx]; b += ws[W_K1I + idx]; c += ws[W_K1E + idx];
  }
  ws[W_MOMRE + bt * 64 + d] = a / 4096.f;
  ws[W_MOMIM + bt * 64 + d] = b / 4096.f;
  ws[W_TE + bt * 64 + d]    = c / 4096.f;
}

// K2b: mom_cat @ mom_w + mom_b -> momentum advection term per (bt,d)
__global__ void k2b_mom(const float* __restrict__ mom_w, const float* __restrict__ mom_b,
                        const float* __restrict__ adv_w, const float* __restrict__ dt, float* ws) {
  int bt = blockIdx.x; int t = bt & 7;
  __shared__ float mc[128], outl[128];
  int tid = threadIdx.x; // 128 threads
  mc[tid] = (tid < 64) ? ws[W_MOMRE + bt * 64 + tid] : ws[W_MOMIM + bt * 64 + tid - 64];
  __syncthreads();
  float acc = mom_b[tid];
  for (int k = 0; k < 128; k++) acc += mc[k] * mom_w[k * 128 + tid];
  outl[tid] = acc;
  __syncthreads();
  if (tid < 64) {
    float f = adv_w[0] * dt[t];
    ws[W_MTRE + bt * 64 + tid] = outl[tid] * f;
    ws[W_MTIM + bt * 64 + tid] = outl[64 + tid] * f;
  }
}

// K0w: bf16 weight prep: MoE w1/w2 fragment order, conv frag-order, enc/dec cat-matrices
__global__ void k0_wprep(const float* __restrict__ w1, const float* __restrict__ w2,
                         const float* __restrict__ cw,
                         const float* __restrict__ enc_re, const float* __restrict__ enc_im,
                         const float* __restrict__ dec_re, const float* __restrict__ dec_im,
                         float* ws) {
  __hip_bfloat16* w1f = (__hip_bfloat16*)(ws + W_W1T);
  __hip_bfloat16* w2f = (__hip_bfloat16*)(ws + W_W2T);
  __hip_bfloat16* cwt = (__hip_bfloat16*)(ws + W_CWT);
  __hip_bfloat16* encM = (__hip_bfloat16*)(ws + W_ENCM);
  __hip_bfloat16* decM = (__hip_bfloat16*)(ws + W_DECM);
  int idx = blockIdx.x * 256 + threadIdx.x; // 0..147455
  if (idx < 131072) {
    {
      int j = idx & 7, lane = (idx >> 3) & 63, kt = (idx >> 9) & 3, nt = (idx >> 11) & 15, e = idx >> 15;
      int cout = nt * 16 + (lane & 15);
      int cin = kt * 32 + (lane >> 4) * 8 + j;
      w1f[idx] = __float2bfloat16(w1[((size_t)(e * 128 + cin)) * 256 + cout]);
    }
    {
      int j = idx & 7, lane = (idx >> 3) & 63, kt = (idx >> 9) & 7, nt = (idx >> 12) & 7, e = idx >> 15;
      int cout = nt * 16 + (lane & 15);
      int cin = kt * 32 + (lane >> 4) * 8 + j;
      w2f[idx] = __float2bfloat16(w2[((size_t)(e * 256 + cin)) * 128 + cout]);
    }
  }
  if (idx < 147456) {
    int j = idx & 7, lane = (idx >> 3) & 63, kt = (idx >> 9) & 3, r = idx >> 11;
    int nt = r & 7, tap = r >> 3;
    int cout = nt * 16 + (lane & 15);
    int cin = kt * 32 + (lane >> 4) * 8 + j;
    cwt[idx] = __float2bfloat16(cw[((size_t)(tap * 128 + cin)) * 128 + cout]);
  }
  if (idx < 16384) {
    int jj = idx & 7, lane = (idx >> 3) & 63, kt = (idx >> 9) & 3, nt = idx >> 11;
    int jc = nt * 16 + (lane & 15);
    int k = kt * 32 + (lane >> 4) * 8 + jj;
    float ve, vd;
    if (k < 64) {
      ve = (jc < 64) ? enc_re[k * 64 + jc] : enc_im[k * 64 + (jc - 64)];
      vd = (jc < 64) ? dec_re[k * 64 + jc] : dec_im[k * 64 + (jc - 64)];
    } else {
      int kk = k - 64;
      ve = (jc < 64) ? -enc_im[kk * 64 + jc] : enc_re[kk * 64 + (jc - 64)];
      vd = (jc < 64) ? -dec_im[kk * 64 + jc] : dec_re[kk * 64 + (jc - 64)];
    }
    encM[idx] = __float2bfloat16(ve);
    decM[idx] = __float2bfloat16(vd);
  }
}

// K3: 3x3 conv (bf16 MFMA) + xcl update + FUSED enc cgemm (x_eigen) + x_mean partials.
__global__ __launch_bounds__(256) void k3_conv_enc(const float* __restrict__ cb, float* ws) {
  int blk = blockIdx.x; int bt = blk >> 6, h = blk & 63;
  const __hip_bfloat16* xnb = (const __hip_bfloat16*)(ws + W_C);
  const __hip_bfloat16* cwt = (const __hip_bfloat16*)(ws + W_CWT);
  const __hip_bfloat16* encM = (const __hip_bfloat16*)(ws + W_ENCM);
  __shared__ __align__(16) char smem[3 * 66 * 136 * 2]; // xin; reused as A-tile after conv
  __hip_bfloat16 (*xin)[66][136] = (__hip_bfloat16(*)[66][136])smem;
  char* A = smem; // bf16 [64 rows][256B], XOR-swizzled
  int tid = threadIdx.x, lane = tid & 63, wv = tid >> 6;
  int arow = lane & 15, kgrp = (lane >> 4) * 8, rbase = (lane >> 4) * 4;

  for (int r = 0; r < 3; r++) {
    int hh = h + r - 1;
    if (hh < 0 || hh >= 64) {
      unsigned int* z = (unsigned int*)&xin[r][0][0];
      for (int i = tid; i < 4488; i += 256) z[i] = 0u;
    } else {
      if (tid < 68) *(unsigned int*)&xin[r][0][tid * 2] = 0u;
      else if (tid < 136) *(unsigned int*)&xin[r][65][(tid - 136 + 68) * 2] = 0u;
      const __hip_bfloat16* src = xnb + ((size_t)bt * 4096 + (size_t)hh * 64) * 128;
      for (int i = tid; i < 1024; i += 256) {
        int wp = (i >> 4) + 1, c8 = (i & 15) * 8;
        *(bf16x8*)&xin[r][wp][c8] = *(const bf16x8*)&src[(size_t)(wp - 1) * 128 + c8];
      }
    }
  }
  __syncthreads();

  f32x4 oacc[4][2];
  #pragma unroll
  for (int m = 0; m < 4; m++) {
    oacc[m][0] = (f32x4){0.f, 0.f, 0.f, 0.f};
    oacc[m][1] = (f32x4){0.f, 0.f, 0.f, 0.f};
  }

  for (int tap = 0; tap < 9; tap++) {
    int kh = tap / 3, kw = tap % 3;
    const __hip_bfloat16* wt0 = cwt + ((size_t)(tap * 8 + wv * 2) * 4) * 512 + lane * 8;
    #pragma unroll
    for (int kt = 0; kt < 4; kt++) {
      bf16x8 a[4];
      #pragma unroll
      for (int m = 0; m < 4; m++)
        a[m] = *(const bf16x8*)&xin[kh][m * 16 + arow + kw][kt * 32 + kgrp];
      bf16x8 b0 = *(const bf16x8*)&wt0[(size_t)kt * 512];
      bf16x8 b1 = *(const bf16x8*)&wt0[(size_t)(kt + 4) * 512];
      #pragma unroll
      for (int m = 0; m < 4; m++) {
        oacc[m][0] = __builtin_amdgcn_mfma_f32_16x16x32_bf16(a[m], b0, oacc[m][0], 0, 0, 0);
        oacc[m][1] = __builtin_amdgcn_mfma_f32_16x16x32_bf16(a[m], b1, oacc[m][1], 0, 0, 0);
      }
    }
  }
  __syncthreads(); // xin dead -> A-tile may overwrite

  // epilogue: xcl_new = old + conv + cb + mom; write f32 global + bf16 swizzled A-tile
  size_t rowtok = (size_t)blk * 64;
  #pragma unroll
  for (int n = 0; n < 2; n++) {
    int cout = (wv * 2 + n) * 16 + arow;
    bool isre = cout < 64;
    int d = cout & 63;
    float add = cb[cout] + ws[(isre ? W_MTRE : W_MTIM) + bt * 64 + d];
    float* xcl = ws + (isre ? W_XCL_RE : W_XCL_IM);
    #pragma unroll
    for (int m = 0; m < 4; m++)
      #pragma unroll
      for (int r = 0; r < 4; r++) {
        int w = m * 16 + rbase + r;
        float v = xcl[(rowtok + w) * 64 + d] + oacc[m][n][r] + add;
        xcl[(rowtok + w) * 64 + d] = v;
        *(__hip_bfloat16*)(A + w * 256 + ((cout * 2) ^ ((w & 7) << 4))) = __float2bfloat16(v);
      }
  }
  __syncthreads();

  // fused enc GEMM 64x128x128 -> eig, + x_mean partials
  f32x4 acc[4][2];
  #pragma unroll
  for (int m = 0; m < 4; m++) {
    acc[m][0] = (f32x4){0.f, 0.f, 0.f, 0.f};
    acc[m][1] = (f32x4){0.f, 0.f, 0.f, 0.f};
  }
  #pragma unroll
  for (int kt = 0; kt < 4; kt++) {
    bf16x8 a[4];
    #pragma unroll
    for (int m = 0; m < 4; m++)
      a[m] = *(const bf16x8*)(A + (m * 16 + arow) * 256 + (((kt * 32 + kgrp) * 2) ^ ((arow & 7) << 4)));
    bf16x8 b0 = *(const bf16x8*)&encM[(((size_t)(wv * 2 + 0) * 4 + kt) * 64 + lane) * 8];
    bf16x8 b1 = *(const bf16x8*)&encM[(((size_t)(wv * 2 + 1) * 4 + kt) * 64 + lane) * 8];
    #pragma unroll
    for (int m = 0; m < 4; m++) {
      acc[m][0] = __builtin_amdgcn_mfma_f32_16x16x32_bf16(a[m], b0, acc[m][0], 0, 0, 0);
      acc[m][1] = __builtin_amdgcn_mfma_f32_16x16x32_bf16(a[m], b1, acc[m][1], 0, 0, 0);
    }
  }
  float* orp = ws + W_EIG_RE;
  float* oip = ws + W_EIG_IM;
  #pragma unroll
  for (int n = 0; n < 2; n++) {
    int jc = (wv * 2 + n) * 16 + arow;
    float* dst = (jc < 64) ? orp : oip;
    int col = jc & 63;
    #pragma unroll
    for (int m = 0; m < 4; m++)
      #pragma unroll
      for (int r = 0; r < 4; r++)
        dst[(rowtok + m * 16 + rbase + r) * 64 + col] = acc[m][n][r];
    float s = 0.f;
    #pragma unroll
    for (int m = 0; m < 4; m++)
      #pragma unroll
      for (int r = 0; r < 4; r++) s += acc[m][n][r];
    s += __shfl_xor(s, 16);
    s += __shfl_xor(s, 32);
    if (lane < 16)
      ws[(jc < 64 ? W_XMP_RE : W_XMP_IM) + (size_t)blk * 64 + col] = s;
  }
}

__device__ __forceinline__ float softplusf(float x) {
  return (x > 20.f) ? x : log1pf(expf(x));
}

// K6: X_flux, flux scan, source, gate, op_decay/op_forcing — tiny (B,T,D) work
__global__ void k6_seq(const float* __restrict__ fin_re, const float* __restrict__ fin_im,
                       const float* __restrict__ fproj_re, const float* __restrict__ fproj_im,
                       const float* __restrict__ flux_a_re, const float* __restrict__ flux_a_im,
                       const float* __restrict__ gate_w, const float* __restrict__ gate_b,
                       const float* __restrict__ lam_re, const float* __restrict__ lam_im,
                       const float* __restrict__ dt, float* ws) {
  __shared__ float xmr[1024], xmi[1024], Xfr[1024], Xfi[1024], flr[1024], fli[1024];
  int tid = threadIdx.x;
  for (int i = tid; i < 1024; i += 256) {
    int bt = i >> 6, j = i & 63;
    float sr = 0.f, si = 0.f;
    for (int q = 0; q < 64; q++) {
      sr += ws[W_XMP_RE + (size_t)(bt * 64 + q) * 64 + j];
      si += ws[W_XMP_IM + (size_t)(bt * 64 + q) * 64 + j];
    }
    xmr[i] = sr / 4096.f; xmi[i] = si / 4096.f;
  }
  __syncthreads();
  for (int i = tid; i < 1024; i += 256) {
    int bt = i >> 6, j = i & 63;
    float ar = 0.f, ai = 0.f;
    for (int d = 0; d < 64; d++) {
      float xr = xmr[bt * 64 + d], xi = xmi[bt * 64 + d];
      float wr = fin_re[d * 64 + j], wi = fin_im[d * 64 + j];
      ar += xr * wr - xi * wi; ai += xr * wi + xi * wr;
    }
    Xfr[i] = ar; Xfi[i] = ai;
  }
  __syncthreads();
  if (tid < 128) {
    int b = tid >> 6, j = tid & 63;
    float mag = expf(-softplusf(flux_a_re[j]));
    float aar = mag * cosf(flux_a_im[j]), aai = mag * sinf(flux_a_im[j]);
    float sr = 0.f, si = 0.f;
    for (int t = 0; t < 8; t++) {
      int idx = (b * 8 + t) * 64 + j;
      float nr = aar * sr - aai * si + Xfr[idx];
      float ni = aar * si + aai * sr + Xfi[idx];
      sr = nr; si = ni;
      flr[idx] = sr; fli[idx] = si;
    }
  }
  __syncthreads();
  for (int i = tid; i < 1024; i += 256) {
    int bt = i >> 6, j = i & 63;
    float ar = 0.f, ai = 0.f, lg = 0.f;
    for (int d = 0; d < 64; d++) {
      float fr = flr[bt * 64 + d], fi = fli[bt * 64 + d];
      float wr = fproj_re[d * 64 + j], wi = fproj_im[d * 64 + j];
      ar += fr * wr - fi * wi; ai += fr * wi + fi * wr;
      lg += fr * gate_w[d * 64 + j] + fi * gate_w[(64 + d) * 64 + j];
    }
    ws[W_SRCRE + i] = ar; ws[W_SRCIM + i] = ai;
    ws[W_GATE + i] = 1.f / (1.f + expf(-(lg + gate_b[j])));
  }
  for (int i = tid; i < 1024; i += 256) {
    int bt = i >> 6, d = i & 63, t = bt & 7;
    float lr = -softplusf(lam_re[d]), li = lam_im[d];
    float dtv = dt[t];
    float mag = expf(lr * dtv);
    float dr = mag * cosf(li * dtv), di = mag * sinf(li * dtv);
    ws[W_OPDRE + i] = dr; ws[W_OPDIM + i] = di;
    float omr = dr - 1.f, omi = di;
    float den = lr * lr + li * li;
    ws[W_OPFRE + i] = (omr * lr + omi * li) / den;
    ws[W_OPFIM + i] = (omi * lr - omr * li) / den;
  }
}

// K7_DEC: fused time-scan + dec cgemm + |x_out|^2 partials.
// grid 512 = (b, h, wq): each block owns 16 tokens (w = wq*16 + wl) across all 8 t.
__global__ __launch_bounds__(256) void k7_dec(const float* __restrict__ nre,
                                              const float* __restrict__ nim,
                                              const float* __restrict__ dt, float* ws) {
  int blk = blockIdx.x;
  int b = blk >> 8, h = (blk >> 2) & 63, wq = blk & 3;
  const __hip_bfloat16* decM = (const __hip_bfloat16*)(ws + W_DECM);
  __shared__ float gl[8][64], srl[8][64], sil[8][64], ofr[8][64], ofi[8][64], odr[8][64], odi[8][64];
  __shared__ __align__(16) char A[4096]; // bf16 [16 rows][256B], XOR-swizzled
  __shared__ float dts[8];
  int tid = threadIdx.x, lane = tid & 63, wv = tid >> 6;
  int arow = lane & 15, kgrp = (lane >> 4) * 8, rbase = (lane >> 4) * 4;
  for (int i = tid; i < 512; i += 256) {
    int t = i >> 6, d = i & 63, idx = (b * 8 + t) * 64 + d;
    gl[t][d]  = ws[W_GATE + idx];
    srl[t][d] = ws[W_SRCRE + idx]; sil[t][d] = ws[W_SRCIM + idx];
    ofr[t][d] = ws[W_OPFRE + idx]; ofi[t][d] = ws[W_OPFIM + idx];
    odr[t][d] = ws[W_OPDRE + idx]; odi[t][d] = ws[W_OPDIM + idx];
  }
  if (tid < 8) dts[tid] = dt[tid];
  __syncthreads();

  int d = tid & 63, wbase = tid >> 6; // wl = wbase + 4k, k=0..3
  float ur[4], ui[4];
  #pragma unroll
  for (int k = 0; k < 4; k++) { ur[k] = 0.f; ui[k] = 0.f; }

  for (int t = 0; t < 8; t++) {
    float ns = 0.01f * sqrtf(dts[t]);
    size_t tokb = ((size_t)(b * 8 + t) * 64 + h) * 64 + (size_t)wq * 16; // token units
    // scan step for owned 4 elements -> bf16 A-tile
    #pragma unroll
    for (int k = 0; k < 4; k++) {
      int wl = wbase + 4 * k;
      size_t off = (tokb + wl) * 64 + d;
      float er_ = ws[W_EIG_RE + off], ei_ = ws[W_EIG_IM + off];
      float gg = gl[t][d];
      float fre = er_ * gg + srl[t][d] * (1.f - gg);
      float fim = ei_ * gg + sil[t][d] * (1.f - gg);
      float utr = fre * ofr[t][d] - fim * ofi[t][d];
      float uti = fre * ofi[t][d] + fim * ofr[t][d];
      float nur = odr[t][d] * ur[k] - odi[t][d] * ui[k] + utr;
      float nui = odr[t][d] * ui[k] + odi[t][d] * ur[k] + uti;
      ur[k] = nur; ui[k] = nui;
      float uor = nur + ns * nre[off];
      float uoi = nui + ns * nim[off];
      int sw = (wl & 7) << 4;
      *(__hip_bfloat16*)(A + wl * 256 + ((d * 2) ^ sw)) = __float2bfloat16(uor);
      *(__hip_bfloat16*)(A + wl * 256 + (((64 + d) * 2) ^ sw)) = __float2bfloat16(uoi);
    }
    __syncthreads();
    // dec GEMM 16x128x128 -> x_out (in place over eig) + |.|^2 partials
    f32x4 acc[2];
    acc[0] = (f32x4){0.f, 0.f, 0.f, 0.f};
    acc[1] = (f32x4){0.f, 0.f, 0.f, 0.f};
    #pragma unroll
    for (int kt = 0; kt < 4; kt++) {
      bf16x8 a0 = *(const bf16x8*)(A + arow * 256 + (((kt * 32 + kgrp) * 2) ^ ((arow & 7) << 4)));
      bf16x8 b0 = *(const bf16x8*)&decM[(((size_t)(wv * 2 + 0) * 4 + kt) * 64 + lane) * 8];
      bf16x8 b1 = *(const bf16x8*)&decM[(((size_t)(wv * 2 + 1) * 4 + kt) * 64 + lane) * 8];
      acc[0] = __builtin_amdgcn_mfma_f32_16x16x32_bf16(a0, b0, acc[0], 0, 0, 0);
      acc[1] = __builtin_amdgcn_mfma_f32_16x16x32_bf16(a0, b1, acc[1], 0, 0, 0);
    }
    float* orp = ws + W_EIG_RE;
    float* oip = ws + W_EIG_IM;
    #pragma unroll
    for (int n = 0; n < 2; n++) {
      int jc = (wv * 2 + n) * 16 + arow;
      float* dst = (jc < 64) ? orp : oip;
      int col = jc & 63;
      #pragma unroll
      for (int r = 0; r < 4; r++)
        dst[(tokb + rbase + r) * 64 + col] = acc[n][r];
      float s = acc[n][0] * acc[n][0] + acc[n][1] * acc[n][1]
              + acc[n][2] * acc[n][2] + acc[n][3] * acc[n][3];
      s += __shfl_xor(s, 16);
      s += __shfl_xor(s, 32);
      if (lane < 16)
        ws[(jc < 64 ? W_EP_RE : W_EP_IM)
           + (size_t)((b * 8 + t) * 256 + h * 4 + wq) * 64 + col] = s;
    }
    __syncthreads();
  }
}

// K9b: combine |x_out|^2 partials -> energy rescale factor per (bt,d)
__global__ void k9b_scale(const float* __restrict__ escale, float* ws) {
  int bt = blockIdx.x; int j = threadIdx.x; // 16 x 64
  float s = 0.f;
  for (int q = 0; q < 256; q++) {
    size_t idx = (size_t)(bt * 256 + q) * 64 + j;
    s += ws[W_EP_RE + idx] + ws[W_EP_IM + idx];
  }
  float cur = s / 4096.f;
  float te = ws[W_TE + bt * 64 + j];
  float ratio = te / (cur + 1e-8f);
  ratio = fminf(fmaxf(ratio, 0.5f), 2.0f);
  ws[W_SCALE + bt * 64 + j] = 1.f + escale[0] * (sqrtf(ratio) - 1.f);
}

// K11: reg-staged scale+LN -> bf16 ltok -> router -> MFMA MoE -> residuals -> out transpose
__global__ __launch_bounds__(256) void k11_moe(
    const float* __restrict__ rw, const float* __restrict__ rb,
    const float* __restrict__ b1, const float* __restrict__ b2,
    const float* __restrict__ g2, const float* __restrict__ b2_,
    float* __restrict__ ws, float* __restrict__ out) {
  int blk = blockIdx.x; int bt = blk >> 6, h = blk & 63;
  const __hip_bfloat16* w1f = (const __hip_bfloat16*)(ws + W_W1T);
  const __hip_bfloat16* w2f = (const __hip_bfloat16*)(ws + W_W2T);
  __shared__ __align__(16) char bufA[33024]; // hbuf bf16 64 rows x 512B | obuf f32[64][129]
  __shared__ __align__(16) char lt[16384];   // ltok bf16 64 rows x 256B, XOR-swizzled
  __shared__ float pl[64][4];
  __shared__ float sc[64];
  __shared__ float ps[4][64], pq[4][64], mean_l[64], rstd_l[64];
  char* hb = bufA;
  float (*obuf)[129] = (float(*)[129])bufA;
  int tid = threadIdx.x, lane = tid & 63, wv = tid >> 6;
  int arow = lane & 15, kgrp = (lane >> 4) * 8, rbase = (lane >> 4) * 4;
  size_t tokbase = (size_t)blk * 64;

  if (tid < 64) sc[tid] = ws[W_SCALE + bt * 64 + tid];
  __syncthreads();

  int w = tid >> 2, part = tid & 3;
  int c0 = part * 32, dbase = (part & 1) * 32;
  const float* rowp = ws + ((part < 2) ? W_EIG_RE : W_EIG_IM) + (tokbase + w) * 64 + dbase;
  float4 vv[8];
  {
    float s = 0.f, sq = 0.f;
    #pragma unroll
    for (int q = 0; q < 8; q++) {
      float4 t4 = *(const float4*)&rowp[q * 4];
      t4.x *= sc[dbase + q * 4 + 0];
      t4.y *= sc[dbase + q * 4 + 1];
      t4.z *= sc[dbase + q * 4 + 2];
      t4.w *= sc[dbase + q * 4 + 3];
      vv[q] = t4;
      s  += t4.x + t4.y + t4.z + t4.w;
      sq += t4.x * t4.x + t4.y * t4.y + t4.z * t4.z + t4.w * t4.w;
    }
    ps[part][w] = s; pq[part][w] = sq;
  }
  __syncthreads();
  if (tid < 64) {
    float s  = ps[0][tid] + ps[1][tid] + ps[2][tid] + ps[3][tid];
    float sq = pq[0][tid] + pq[1][tid] + pq[2][tid] + pq[3][tid];
    float m = s / 128.f, v = sq / 128.f - m * m;
    mean_l[tid] = m; rstd_l[tid] = rsqrtf(v + 1e-5f);
  }
  __syncthreads();
  {
    float m = mean_l[w], rs = rstd_l[w];
    int szw = (w & 7) << 4;
    #pragma unroll
    for (int q = 0; q < 8; q++) {
      int c = c0 + q * 4;
      float a0 = (vv[q].x - m) * rs * g2[c]     + b2_[c];
      float a1 = (vv[q].y - m) * rs * g2[c + 1] + b2_[c + 1];
      float a2 = (vv[q].z - m) * rs * g2[c + 2] + b2_[c + 2];
      float a3 = (vv[q].w - m) * rs * g2[c + 3] + b2_[c + 3];
      *(unsigned int*)(lt + w * 256 + ((c * 2) ^ szw)) = pk2(a0, a1);
      *(unsigned int*)(lt + w * 256 + (((c + 2) * 2) ^ szw)) = pk2(a2, a3);
    }
  }
  __syncthreads();
  {
    int l = tid >> 2, e = tid & 3;
    float acc = rb[e];
    const float* rwe = rw + e;
    int sz = (l & 7) << 4;
    for (int dd = 0; dd < 128; dd += 2) {
      unsigned int u = *(const unsigned int*)(lt + l * 256 + ((dd * 2) ^ sz));
      float x0 = __uint_as_float(u << 16);
      float x1 = __uint_as_float(u & 0xffff0000u);
      acc += x0 * rwe[dd * 4] + x1 * rwe[dd * 4 + 4];
    }
    pl[l][e] = acc;
  }
  __syncthreads();
  if (tid < 64) {
    float m = fmaxf(fmaxf(pl[tid][0], pl[tid][1]), fmaxf(pl[tid][2], pl[tid][3]));
    float e0 = expf(pl[tid][0] - m), e1 = expf(pl[tid][1] - m);
    float e2 = expf(pl[tid][2] - m), e3 = expf(pl[tid][3] - m);
    float s = e0 + e1 + e2 + e3;
    pl[tid][0] = e0 / s; pl[tid][1] = e1 / s; pl[tid][2] = e2 / s; pl[tid][3] = e3 / s;
  }

  f32x4 oacc[4][2];
  #pragma unroll
  for (int m = 0; m < 4; m++)
    #pragma unroll
    for (int n2 = 0; n2 < 2; n2++) {
      int col = (wv * 2 + n2) * 16 + arow;
      #pragma unroll
      for (int r = 0; r < 4; r++) {
        int row = m * 16 + rbase + r;
        oacc[m][n2][r] = __bfloat162float(
            *(const __hip_bfloat16*)(lt + row * 256 + ((col * 2) ^ ((row & 7) << 4))));
      }
    }
  __syncthreads();

  for (int e = 0; e < 4; e++) {
    #pragma unroll
    for (int hf = 0; hf < 2; hf++) {
      f32x4 acc1[4][2];
      #pragma unroll
      for (int m = 0; m < 4; m++) {
        acc1[m][0] = (f32x4){0.f, 0.f, 0.f, 0.f};
        acc1[m][1] = (f32x4){0.f, 0.f, 0.f, 0.f};
      }
      #pragma unroll
      for (int kt = 0; kt < 4; kt++) {
        bf16x8 a[4];
        #pragma unroll
        for (int m = 0; m < 4; m++) {
          int row = m * 16 + arow;
          a[m] = *(const bf16x8*)(lt + row * 256 + (((kt * 32 + kgrp) * 2) ^ ((arow & 7) << 4)));
        }
        bf16x8 b0 = *(const bf16x8*)&w1f[(((size_t)(e * 16 + wv * 4 + hf * 2 + 0) * 4 + kt) * 64 + lane) * 8];
        bf16x8 b1 = *(const bf16x8*)&w1f[(((size_t)(e * 16 + wv * 4 + hf * 2 + 1) * 4 + kt) * 64 + lane) * 8];
        #pragma unroll
        for (int m = 0; m < 4; m++) {
          acc1[m][0] = __builtin_amdgcn_mfma_f32_16x16x32_bf16(a[m], b0, acc1[m][0], 0, 0, 0);
          acc1[m][1] = __builtin_amdgcn_mfma_f32_16x16x32_bf16(a[m], b1, acc1[m][1], 0, 0, 0);
        }
      }
      if (hf == 0) __syncthreads();
      #pragma unroll
      for (int n = 0; n < 2; n++) {
        int col = (wv * 4 + hf * 2 + n) * 16 + arow;
        float bv = b1[e * 256 + col];
        #pragma unroll
        for (int m = 0; m < 4; m++)
          #pragma unroll
          for (int r = 0; r < 4; r++) {
            float hv = acc1[m][n][r] + bv;
            float z = 1.5957691216f * hv + 0.0713548162f * hv * hv * hv;
            float gelu = hv / (1.f + __expf(-z));
            int row = m * 16 + rbase + r;
            *(__hip_bfloat16*)(hb + row * 512 + ((col * 2) ^ ((row & 7) << 4))) =
                __float2bfloat16(gelu);
          }
      }
    }
    __syncthreads();
    f32x4 acc2[4][2];
    #pragma unroll
    for (int m = 0; m < 4; m++) {
      acc2[m][0] = (f32x4){0.f, 0.f, 0.f, 0.f};
      acc2[m][1] = (f32x4){0.f, 0.f, 0.f, 0.f};
    }
    #pragma unroll
    for (int kt = 0; kt < 8; kt++) {
      bf16x8 a2[4];
      #pragma unroll
      for (int m = 0; m < 4; m++) {
        int row = m * 16 + arow;
        a2[m] = *(const bf16x8*)(hb + row * 512 + (((kt * 32 + kgrp) * 2) ^ ((arow & 7) << 4)));
      }
      bf16x8 bb0 = *(const bf16x8*)&w2f[(((size_t)(e * 8 + wv * 2 + 0) * 8 + kt) * 64 + lane) * 8];
      bf16x8 bb1 = *(const bf16x8*)&w2f[(((size_t)(e * 8 + wv * 2 + 1) * 8 + kt) * 64 + lane) * 8];
      #pragma unroll
      for (int m = 0; m < 4; m++) {
        acc2[m][0] = __builtin_amdgcn_mfma_f32_16x16x32_bf16(a2[m], bb0, acc2[m][0], 0, 0, 0);
        acc2[m][1] = __builtin_amdgcn_mfma_f32_16x16x32_bf16(a2[m], bb1, acc2[m][1], 0, 0, 0);
      }
    }
    #pragma unroll
    for (int n = 0; n < 2; n++) {
      int col = (wv * 2 + n) * 16 + arow;
      float bv2 = b2[e * 128 + col];
      #pragma unroll
      for (int m = 0; m < 4; m++)
        #pragma unroll
        for (int r = 0; r < 4; r++)
          oacc[m][n][r] += pl[m * 16 + rbase + r][e] * (acc2[m][n][r] + bv2);
    }
  }

  __syncthreads();
  #pragma unroll
  for (int m = 0; m < 4; m++)
    #pragma unroll
    for (int n2 = 0; n2 < 2; n2++) {
      int col = (wv * 2 + n2) * 16 + arow;
      #pragma unroll
      for (int r = 0; r < 4; r++)
        obuf[m * 16 + rbase + r][col] = oacc[m][n2][r];
    }
  __syncthreads();

  {
    const float* xre = ws + W_XCL_RE;
    const float* xim = ws + W_XCL_IM;
    for (int i = tid; i < 8192; i += 256) {
      int wt = i >> 7, c = i & 127, dd = c & 63;
      float val = ((c < 64) ? xre : xim)[(tokbase + wt) * 64 + dd];
      obuf[wt][c] += val;
    }
  }
  __syncthreads();
  for (int i = tid; i < 8192; i += 256) {
    int d2 = i >> 6, wt = i & 63;
    out[(size_t)(d2 >> 6) * 4194304 + (size_t)bt * 262144 + (size_t)(d2 & 63) * 4096
        + (size_t)h * 64 + wt] = obuf[wt][d2];
  }
}

extern "C" void kernel_launch(void* const* d_in, const int* in_sizes, int n_in,
                              void* d_out, int out_size, void* d_ws, size_t ws_size,
                              hipStream_t stream) {
  const float* x_re      = (const float*)d_in[0];
  const float* x_im      = (const float*)d_in[1];
  const float* dt        = (const float*)d_in[2];
  const float* ln_s_g    = (const float*)d_in[3];
  const float* ln_s_b    = (const float*)d_in[4];
  const float* conv_w    = (const float*)d_in[5];
  const float* conv_b    = (const float*)d_in[6];
  const float* mom_w     = (const float*)d_in[7];
  const float* mom_b     = (const float*)d_in[8];
  const float* adv_w     = (const float*)d_in[9];
  const float* enc_re    = (const float*)d_in[10];
  const float* enc_im    = (const float*)d_in[11];
  const float* dec_re    = (const float*)d_in[12];
  const float* dec_im    = (const float*)d_in[13];
  const float* flux_a_re = (const float*)d_in[14];
  const float* flux_a_im = (const float*)d_in[15];
  const float* fin_re    = (const float*)d_in[16];
  const float* fin_im    = (const float*)d_in[17];
  const float* fproj_re  = (const float*)d_in[18];
  const float* fproj_im  = (const float*)d_in[19];
  const float* gate_w    = (const float*)d_in[20];
  const float* gate_b    = (const float*)d_in[21];
  const float* lam_re    = (const float*)d_in[22];
  const float* lam_im    = (const float*)d_in[23];
  const float* noise_re  = (const float*)d_in[24];
  const float* noise_im  = (const float*)d_in[25];
  const float* e_scale   = (const float*)d_in[26];
  const float* ln_t_g    = (const float*)d_in[27];
  const float* ln_t_b    = (const float*)d_in[28];
  const float* router_w  = (const float*)d_in[29];
  const float* router_b  = (const float*)d_in[30];
  const float* w1        = (const float*)d_in[31];
  const float* b1        = (const float*)d_in[32];
  const float* w2        = (const float*)d_in[33];
  const float* b2        = (const float*)d_in[34];
  float* ws  = (float*)d_ws;
  float* out = (float*)d_out;

  k0_wprep<<<576, 256, 0, stream>>>(w1, w2, conv_w, enc_re, enc_im, dec_re, dec_im, ws);
  k2_transpose_ln<<<1024, 256, 0, stream>>>(x_re, x_im, ln_s_g, ln_s_b, ws);
  k1b_finish<<<16, 64, 0, stream>>>(ws);
  k2b_mom<<<16, 128, 0, stream>>>(mom_w, mom_b, adv_w, dt, ws);
  k3_conv_enc<<<1024, 256, 0, stream>>>(conv_b, ws);
  k6_seq<<<1, 256, 0, stream>>>(fin_re, fin_im, fproj_re, fproj_im, flux_a_re, flux_a_im,
                                gate_w, gate_b, lam_re, lam_im, dt, ws);
  k7_dec<<<512, 256, 0, stream>>>(noise_re, noise_im, dt, ws);
  k9b_scale<<<16, 64, 0, stream>>>(e_scale, ws);
  k11_moe<<<1024, 256, 0, stream>>>(router_w, router_b, b1, b2, ln_t_g, ln_t_b, ws, out);
}